// Round 7
// baseline (259.022 us; speedup 1.0000x reference)
//
#include <hip/hip_runtime.h>
#include <hip/hip_bf16.h>
#include <math.h>

#define SEQ 2048
#define BATCH 4
#define HDIM 256
#define NHEAD 4
#define FFN_DIM 1024
#define MTOT (BATCH*SEQ)   // 8192

typedef __attribute__((ext_vector_type(8))) short bf16x8;
typedef __attribute__((ext_vector_type(4))) float f32x4;

__device__ __forceinline__ bf16x8 cvt8(const float* p)
{
    float4 a = *(const float4*)p;
    float4 b = *(const float4*)(p + 4);
    union { bf16x8 v; __hip_bfloat16 e[8]; } u;
    u.e[0] = __float2bfloat16(a.x); u.e[1] = __float2bfloat16(a.y);
    u.e[2] = __float2bfloat16(a.z); u.e[3] = __float2bfloat16(a.w);
    u.e[4] = __float2bfloat16(b.x); u.e[5] = __float2bfloat16(b.y);
    u.e[6] = __float2bfloat16(b.z); u.e[7] = __float2bfloat16(b.w);
    return u.v;
}

// ---------------------------------------------------------------------------
// Weights f32 -> bf16, re-laid out in MFMA-FRAGMENT TILES:
//   W[N][K] -> tiles [N/16][K/32][lane=0..63][8], where
//   lane = ((k>>3)&3)*16 + (row&15), elem = k&7.
// A fragment load is then ONE coalesced 1KB read: base + tile*512 + lane*8.
// ---------------------------------------------------------------------------
__global__ __launch_bounds__(256)
void cvt_all(const float* __restrict__ w_in, const float* __restrict__ w_out,
             const float* __restrict__ qkv_w, const float* __restrict__ out_w,
             const float* __restrict__ ff1_w, const float* __restrict__ ff2_w,
             __hip_bfloat16* __restrict__ wb)
{
    int i = blockIdx.x * 256 + threadIdx.x;   // grid 1216 -> exact (311296 thr)
    size_t e = (size_t)i * 8;

    const float* srcbase; size_t rbase; int kshift;  // K = 1<<kshift
    if (e < 720896) {
        if (e < 65536)       { srcbase = w_in;  rbase = 0;      kshift = 8; }
        else if (e < 131072) { srcbase = w_out; rbase = 65536;  kshift = 8; }
        else                 { srcbase = qkv_w; rbase = 131072; kshift = 8; }
    } else if (e < 917504)   { srcbase = out_w; rbase = 720896; kshift = 8; }
    else if (e < 1703936)    { srcbase = ff1_w; rbase = 917504; kshift = 8; }
    else                     { srcbase = ff2_w; rbase = 1703936; kshift = 10; }

    size_t local = e - rbase;
    int K = 1 << kshift;
    int row = (int)(local >> kshift);
    int k   = (int)(local & (K - 1));          // multiple of 8

    size_t dst = rbase
               + ((size_t)(row >> 4) * (K >> 5) + (k >> 5)) * 512
               + (size_t)((((k >> 3) & 3) << 4) | (row & 15)) * 8;

    *(bf16x8*)(wb + dst) = cvt8(srcbase + local);
}

// fragment-tile load helper: W swizzled with inner-dim K, n0 16-aligned
__device__ __forceinline__ bf16x8 fragW(const short* W, int n0, int k0, int K, int lane)
{
    return *(const bf16x8*)(W + ((size_t)(n0 >> 4) * (K >> 5) + (k0 >> 5)) * 512 + lane * 8);
}

// ---------------------------------------------------------------------------
// Embed: h = 16 * (x @ w_in^T) + PE.
// ---------------------------------------------------------------------------
__global__ __launch_bounds__(256)
void embed_pe(const float* __restrict__ X, const __hip_bfloat16* __restrict__ W,
              float* __restrict__ hbuf)
{
    int tid = threadIdx.x, wave = tid >> 6, lane = tid & 63;
    int wm = wave >> 1, wn = wave & 1;
    int rowBase = blockIdx.y * 64 + wm * 32;
    int colBase = blockIdx.x * 64 + wn * 32;
    int lr = lane & 15, hi = lane >> 4;

    const float* px0 = X + (size_t)(rowBase + lr) * HDIM + hi * 8;
    const float* px1 = px0 + (size_t)16 * HDIM;
    const short* Wb  = (const short*)W;

    f32x4 acc[2][2];
    acc[0][0] = (f32x4){0.f,0.f,0.f,0.f}; acc[0][1] = (f32x4){0.f,0.f,0.f,0.f};
    acc[1][0] = (f32x4){0.f,0.f,0.f,0.f}; acc[1][1] = (f32x4){0.f,0.f,0.f,0.f};

    #pragma unroll
    for (int k0 = 0; k0 < 256; k0 += 32) {
        bf16x8 a0 = cvt8(px0 + k0);
        bf16x8 a1 = cvt8(px1 + k0);
        bf16x8 b0 = fragW(Wb, colBase,      k0, 256, lane);
        bf16x8 b1 = fragW(Wb, colBase + 16, k0, 256, lane);
        acc[0][0] = __builtin_amdgcn_mfma_f32_16x16x32_bf16(a0, b0, acc[0][0], 0,0,0);
        acc[0][1] = __builtin_amdgcn_mfma_f32_16x16x32_bf16(a0, b1, acc[0][1], 0,0,0);
        acc[1][0] = __builtin_amdgcn_mfma_f32_16x16x32_bf16(a1, b0, acc[1][0], 0,0,0);
        acc[1][1] = __builtin_amdgcn_mfma_f32_16x16x32_bf16(a1, b1, acc[1][1], 0,0,0);
    }

    int cc = lane & 15, quad = lane >> 4;
    #pragma unroll
    for (int mt = 0; mt < 2; mt++)
        #pragma unroll
        for (int nt = 0; nt < 2; nt++) {
            int col = colBase + nt*16 + cc;
            int i2 = col & ~1;
            float freq = __expf((float)i2 * (-9.210340371976184f / 256.0f));
            #pragma unroll
            for (int r = 0; r < 4; r++) {
                int row = rowBase + mt*16 + quad*4 + r;
                float arg = (float)(row & (SEQ-1)) * freq;
                float pe = (col & 1) ? __cosf(arg) : __sinf(arg);
                hbuf[(size_t)row*HDIM + col] = 16.0f*acc[mt][nt][r] + pe;
            }
        }
}

// ---------------------------------------------------------------------------
// LN-fused GEMM, 64-row tile. Weights in fragment-tile layout.
// MODE 4: of32 = C + bias
// MODE 5: head-split qkv write; Q/K sections fragment-tiled over (seq, d);
//         V section fragment-tiled TRANSPOSED over (d, seq) so PV B-operand
//         fragments are single coalesced reads.
// ---------------------------------------------------------------------------
template<int MODE, int NT>
__global__ __launch_bounds__(256)
void gemm_ln(const float* __restrict__ h,
             const float* __restrict__ g, const float* __restrict__ bln,
             const __hip_bfloat16* __restrict__ W,
             const float* __restrict__ bias,
             __hip_bfloat16* __restrict__ obf, float* __restrict__ of32,
             int N, int ldw)
{
    constexpr int NTW = NT / 32;
    __shared__ __align__(16) short A_lds[64][264];

    int tid = threadIdx.x, wave = tid >> 6, lane = tid & 63;
    int wm = wave >> 1, wn = wave & 1;
    int rowBase = blockIdx.y * 64;
    int colBase = blockIdx.x * NT + wn * (NT / 2);

    {
        float4 gv = *(const float4*)(g + lane * 4);
        float4 bv = *(const float4*)(bln + lane * 4);
        #pragma unroll
        for (int rr = 0; rr < 16; rr += 4) {
            float4 xv[4];
            #pragma unroll
            for (int u = 0; u < 4; u++)
                xv[u] = *(const float4*)(h + (size_t)(rowBase + wave*16 + rr + u)*HDIM + lane*4);
            #pragma unroll
            for (int u = 0; u < 4; u++) {
                float s = xv[u].x + xv[u].y + xv[u].z + xv[u].w;
                #pragma unroll
                for (int off = 32; off >= 1; off >>= 1) s += __shfl_xor(s, off);
                float mu = s * (1.0f/256.0f);
                float d0 = xv[u].x-mu, d1 = xv[u].y-mu, d2 = xv[u].z-mu, d3 = xv[u].w-mu;
                float v = d0*d0 + d1*d1 + d2*d2 + d3*d3;
                #pragma unroll
                for (int off = 32; off >= 1; off >>= 1) v += __shfl_xor(v, off);
                float rstd = rsqrtf(v * (1.0f/256.0f) + 1e-5f);
                union { short e[4]; uint2 w2; } o;
                o.e[0] = (short)__bfloat16_as_ushort(__float2bfloat16(d0*rstd*gv.x + bv.x));
                o.e[1] = (short)__bfloat16_as_ushort(__float2bfloat16(d1*rstd*gv.y + bv.y));
                o.e[2] = (short)__bfloat16_as_ushort(__float2bfloat16(d2*rstd*gv.z + bv.z));
                o.e[3] = (short)__bfloat16_as_ushort(__float2bfloat16(d3*rstd*gv.w + bv.w));
                *(uint2*)&A_lds[wave*16 + rr + u][lane*4] = o.w2;
            }
        }
    }
    __syncthreads();

    int lr = lane & 15, hi = lane >> 4;
    f32x4 acc[2][NTW];
    #pragma unroll
    for (int mt = 0; mt < 2; mt++)
        #pragma unroll
        for (int nt = 0; nt < NTW; nt++)
            acc[mt][nt] = (f32x4){0.f,0.f,0.f,0.f};

    const short* Ws = (const short*)W;
    #pragma unroll
    for (int k0 = 0; k0 < 256; k0 += 32) {
        bf16x8 af[2], bfr[NTW];
        #pragma unroll
        for (int mt = 0; mt < 2; mt++)
            af[mt] = *(const bf16x8*)&A_lds[wm*32 + mt*16 + lr][k0 + hi*8];
        #pragma unroll
        for (int nt = 0; nt < NTW; nt++)
            bfr[nt] = fragW(Ws, colBase + nt*16, k0, 256, lane);
        #pragma unroll
        for (int mt = 0; mt < 2; mt++)
            #pragma unroll
            for (int nt = 0; nt < NTW; nt++)
                acc[mt][nt] = __builtin_amdgcn_mfma_f32_16x16x32_bf16(af[mt], bfr[nt], acc[mt][nt], 0,0,0);
    }

    int cc = lane & 15, quad = lane >> 4;
    #pragma unroll
    for (int mt = 0; mt < 2; mt++)
        #pragma unroll
        for (int nt = 0; nt < NTW; nt++) {
            int col = colBase + nt*16 + cc;
            float bv = bias[col];
            #pragma unroll
            for (int r = 0; r < 4; r++) {
                int row = rowBase + wm*32 + mt*16 + quad*4 + r;
                float c = acc[mt][nt][r] + bv;
                if (MODE == 4) { of32[(size_t)row*N + col] = c; }
                else { // MODE 5
                    int sec = col >> 8, hd = (col >> 6) & 3, d = col & 63;
                    int srow = row & (SEQ - 1);
                    size_t base = (size_t)sec * 2097152
                                + (size_t)(((row >> 11) << 2) | hd) * 131072;
                    size_t idx;
                    if (sec < 2)   // Q/K: tiles [s/16][d/32]
                        idx = base + (size_t)(srow >> 4) * 1024 + (size_t)(d >> 5) * 512
                            + (size_t)((((d >> 3) & 3) << 4) | (srow & 15)) * 8 + (d & 7);
                    else           // V^T: tiles [d/16][s/32]
                        idx = base + ((size_t)(d >> 4) * 64 + (srow >> 5)) * 512
                            + (size_t)((((srow >> 3) & 3) << 4) | (d & 15)) * 8 + (srow & 7);
                    obf[idx] = __float2bfloat16(c);
                }
            }
        }
}

// ---------------------------------------------------------------------------
// FULLY FUSED layer tail, 1024 threads / 16 waves. ALL matrix operands
// (Q, K, V^T, ow, W1, W2) are single coalesced 1KB fragment reads.
// V never touches LDS (global V^T fragment tiles).
// ---------------------------------------------------------------------------
struct AttnLDS {
    __align__(16) __hip_bfloat16 Pl[32][104];   // stride 104: 2-way banks
    float sm[2][32], ss[2][32];
};

__global__ __launch_bounds__(1024)
void attn_ffn(const __hip_bfloat16* __restrict__ qkvd,
              const __hip_bfloat16* __restrict__ ow,   // fragment-tiled [256][256]
              const float* __restrict__ ob,
              float* __restrict__ h,
              const float* __restrict__ g, const float* __restrict__ bln,
              const __hip_bfloat16* __restrict__ W1, const float* __restrict__ b1,
              const __hip_bfloat16* __restrict__ W2, const float* __restrict__ b2)
{
    __shared__ union SMem {
        AttnLDS asl[4];                                   // ~28 KB (attention)
        struct {
            __align__(16) short A[32][264];               // LN2 out (bf16)
            __align__(16) short Z[2][32][264];            // FFN hidden, dbuf
        } f;                                              // ~51 KB (FFN)
    } U;
    __shared__ __align__(16) short att_lds[32][264];
    __shared__ __align__(16) float H_lds[32][260];

    int tid  = threadIdx.x;
    int wave = tid >> 6, lane = tid & 63;
    int grp  = wave >> 2, w4 = wave & 3;
    int b    = blockIdx.y, i0 = blockIdx.x * 32;
    int klo  = i0 - 32;

    int lr = lane & 15, hi = lane >> 4;
    int cc = lane & 15, quad = lane >> 4;

    int hd = grp;
    AttnLDS& S = U.asl[grp];
    const short* Qd = (const short*)qkvd + (size_t)(b * 4 + hd) * 131072;
    const short* Kd = Qd + 2097152;
    const short* Vd = Qd + 4194304;
    int qh = w4 & 1, seg = w4 >> 1;
    int qoff = qh * 16 + quad * 4;

    // ======== ENTRY PREFETCH (all coalesced fragment loads) ========
    // Q fragments
    bf16x8 qf[2];
    #pragma unroll
    for (int ds = 0; ds < 2; ds++)
        qf[ds] = *(const bf16x8*)(Qd + (size_t)((i0 >> 4) + qh) * 1024 + ds * 512 + lane * 8);
    // K fragments
    bf16x8 kf[3][2];
    #pragma unroll
    for (int t = 0; t < 3; t++) {
        int jt = (klo + seg * 48 + t * 16) >> 4;
        jt = jt < 0 ? 0 : (jt > 127 ? 127 : jt);
        kf[t][0] = *(const bf16x8*)(Kd + (size_t)jt * 1024 + lane * 8);
        kf[t][1] = *(const bf16x8*)(Kd + (size_t)jt * 1024 + 512 + lane * 8);
    }
    // V^T fragments (tiles [d/16][s/32]; clamped tiles pair with P==0 exactly)
    bf16x8 vf[3][2];
    #pragma unroll
    for (int ks = 0; ks < 3; ks++) {
        int s0 = klo + ks * 32;
        s0 = s0 < 0 ? 0 : (s0 > SEQ - 32 ? SEQ - 32 : s0);
        #pragma unroll
        for (int dt = 0; dt < 2; dt++) {
            int d0 = seg*32 + dt*16;
            vf[ks][dt] = *(const bf16x8*)(Vd + ((size_t)(d0 >> 4) * 64 + (s0 >> 5)) * 512 + lane * 8);
        }
    }
    // residual h_old
    float hold[2][4];
    {
        const float* hp = h + (size_t)(b * SEQ + i0) * HDIM + wave * 16 + cc;
        #pragma unroll
        for (int mt = 0; mt < 2; mt++)
            #pragma unroll
            for (int r = 0; r < 4; r++)
                hold[mt][r] = hp[(size_t)(mt*16 + quad*4 + r) * HDIM];
    }

    // ======== phase 1: attention ========
    f32x4 sacc[3];
    #pragma unroll
    for (int t = 0; t < 3; t++) {
        f32x4 a = (f32x4){0.f,0.f,0.f,0.f};
        a = __builtin_amdgcn_mfma_f32_16x16x32_bf16(qf[0], kf[t][0], a, 0,0,0);
        a = __builtin_amdgcn_mfma_f32_16x16x32_bf16(qf[1], kf[t][1], a, 0,0,0);
        sacc[t] = a;
    }

    float s[3][4];
    #pragma unroll
    for (int t = 0; t < 3; t++) {
        int koff = seg * 48 + t * 16 + cc;
        int jj = klo + koff;
        #pragma unroll
        for (int r = 0; r < 4; r++) {
            int rel = koff - (qoff + r);
            bool ok = (jj >= 0) && (jj < SEQ) && (rel >= 0) && (rel <= 64);
            s[t][r] = ok ? sacc[t][r] * 0.125f : -1e30f;
        }
    }

    float mrow[4], srow[4];
    #pragma unroll
    for (int r = 0; r < 4; r++)
        mrow[r] = fmaxf(fmaxf(s[0][r], s[1][r]), s[2][r]);
    #pragma unroll
    for (int off = 8; off >= 1; off >>= 1)
        #pragma unroll
        for (int r = 0; r < 4; r++)
            mrow[r] = fmaxf(mrow[r], __shfl_xor(mrow[r], off));
    #pragma unroll
    for (int r = 0; r < 4; r++)
        srow[r] = __expf(s[0][r]-mrow[r]) + __expf(s[1][r]-mrow[r]) + __expf(s[2][r]-mrow[r]);
    #pragma unroll
    for (int off = 8; off >= 1; off >>= 1)
        #pragma unroll
        for (int r = 0; r < 4; r++)
            srow[r] += __shfl_xor(srow[r], off);
    if (cc == 0) {
        #pragma unroll
        for (int r = 0; r < 4; r++) { S.sm[seg][qoff+r] = mrow[r]; S.ss[seg][qoff+r] = srow[r]; }
    }
    __syncthreads();

    float Mr[4], inv[4];
    #pragma unroll
    for (int r = 0; r < 4; r++) {
        float m0 = S.sm[0][qoff+r], m1 = S.sm[1][qoff+r];
        float M = fmaxf(m0, m1);
        float dn = S.ss[0][qoff+r] * __expf(m0 - M) + S.ss[1][qoff+r] * __expf(m1 - M);
        Mr[r] = M; inv[r] = 1.0f / dn;
    }
    #pragma unroll
    for (int t = 0; t < 3; t++)
        #pragma unroll
        for (int r = 0; r < 4; r++)
            S.Pl[qoff+r][seg*48 + t*16 + cc] = __float2bfloat16(__expf(s[t][r]-Mr[r]) * inv[r]);
    __syncthreads();

    // prefetch proj weight fragments (coalesced; hidden under PV)
    bf16x8 owf[8];
    {
        const short* op = (const short*)ow + (size_t)wave * 8 * 512 + lane * 8;
        #pragma unroll
        for (int i = 0; i < 8; i++)
            owf[i] = *(const bf16x8*)(op + i * 512);
    }

    // O = P @ V -> att_lds (V already in registers)
    {
        f32x4 oacc[2];
        oacc[0] = (f32x4){0.f,0.f,0.f,0.f}; oacc[1] = (f32x4){0.f,0.f,0.f,0.f};
        #pragma unroll
        for (int ks = 0; ks < 3; ks++) {
            bf16x8 pf = *(const bf16x8*)&S.Pl[qh*16 + lr][ks*32 + hi*8];
            #pragma unroll
            for (int dt = 0; dt < 2; dt++)
                oacc[dt] = __builtin_amdgcn_mfma_f32_16x16x32_bf16(pf, vf[ks][dt], oacc[dt], 0,0,0);
        }
        #pragma unroll
        for (int dt = 0; dt < 2; dt++) {
            int col = hd*64 + seg*32 + dt*16 + cc;
            #pragma unroll
            for (int r = 0; r < 4; r++)
                att_lds[qoff + r][col] =
                    (short)__bfloat16_as_ushort(__float2bfloat16(oacc[dt][r]));
        }
    }
    __syncthreads();

    // ======== phase 2: proj + residual -> H_lds (wave owns 16 cols) ========
    {
        f32x4 acc[2];
        acc[0] = (f32x4){0.f,0.f,0.f,0.f}; acc[1] = (f32x4){0.f,0.f,0.f,0.f};
        #pragma unroll
        for (int i = 0; i < 8; i++) {
            bf16x8 a0 = *(const bf16x8*)&att_lds[lr][i*32 + hi*8];
            bf16x8 a1 = *(const bf16x8*)&att_lds[16 + lr][i*32 + hi*8];
            acc[0] = __builtin_amdgcn_mfma_f32_16x16x32_bf16(a0, owf[i], acc[0], 0,0,0);
            acc[1] = __builtin_amdgcn_mfma_f32_16x16x32_bf16(a1, owf[i], acc[1], 0,0,0);
        }
        float bv = ob[wave*16 + cc];
        #pragma unroll
        for (int mt = 0; mt < 2; mt++)
            #pragma unroll
            for (int r = 0; r < 4; r++)
                H_lds[mt*16 + quad*4 + r][wave*16 + cc] = hold[mt][r] + acc[mt][r] + bv;
    }

    // prologue: prefetch W1 chunk 0 (coalesced; hidden under barrier + LN2)
    const short* W1s = (const short*)W1;
    const short* W2s = (const short*)W2;
    bf16x8 w1f[8];
    {
        const short* wp = W1s + (size_t)wave * 8 * 512 + lane * 8;
        #pragma unroll
        for (int i = 0; i < 8; i++)
            w1f[i] = *(const bf16x8*)(wp + i * 512);
    }
    __syncthreads();

    // ======== phase 3: LN2(H_lds) -> A bf16 (each wave: 2 rows) ========
    {
        float4 gv = *(const float4*)(g + lane * 4);
        float4 bv = *(const float4*)(bln + lane * 4);
        #pragma unroll
        for (int u = 0; u < 2; u++) {
            float4 xv = *(const float4*)&H_lds[wave*2 + u][lane*4];
            float ss2 = xv.x + xv.y + xv.z + xv.w;
            #pragma unroll
            for (int off = 32; off >= 1; off >>= 1) ss2 += __shfl_xor(ss2, off);
            float mu = ss2 * (1.0f/256.0f);
            float d0 = xv.x-mu, d1 = xv.y-mu, d2 = xv.z-mu, d3 = xv.w-mu;
            float v = d0*d0 + d1*d1 + d2*d2 + d3*d3;
            #pragma unroll
            for (int off = 32; off >= 1; off >>= 1) v += __shfl_xor(v, off);
            float rstd = rsqrtf(v * (1.0f/256.0f) + 1e-5f);
            union { short e[4]; uint2 w2; } o;
            o.e[0] = (short)__bfloat16_as_ushort(__float2bfloat16(d0*rstd*gv.x + bv.x));
            o.e[1] = (short)__bfloat16_as_ushort(__float2bfloat16(d1*rstd*gv.y + bv.y));
            o.e[2] = (short)__bfloat16_as_ushort(__float2bfloat16(d2*rstd*gv.z + bv.z));
            o.e[3] = (short)__bfloat16_as_ushort(__float2bfloat16(d3*rstd*gv.w + bv.w));
            *(uint2*)&U.f.A[wave*2 + u][lane*4] = o.w2;
        }
    }
    __syncthreads();

    // ======== phase 4: FFN, Z dbuf, weights software-pipelined ========
    f32x4 acc2[2];
    acc2[0] = (f32x4){0.f,0.f,0.f,0.f}; acc2[1] = (f32x4){0.f,0.f,0.f,0.f};

    #pragma unroll 1
    for (int kk = 0; kk < 4; kk++) {
        // prefetch W2[kk] fragments (coalesced)
        bf16x8 w2f[8];
        {
            const short* wp = W2s + (size_t)(wave * 32 + kk * 8) * 512 + lane * 8;
            #pragma unroll
            for (int i = 0; i < 8; i++)
                w2f[i] = *(const bf16x8*)(wp + i * 512);
        }

        // FF1 chunk
        f32x4 acc1[2];
        acc1[0] = (f32x4){0.f,0.f,0.f,0.f}; acc1[1] = (f32x4){0.f,0.f,0.f,0.f};
        #pragma unroll
        for (int i = 0; i < 8; i++) {
            bf16x8 af0 = *(const bf16x8*)&U.f.A[lr][i*32 + hi*8];
            bf16x8 af1 = *(const bf16x8*)&U.f.A[16 + lr][i*32 + hi*8];
            acc1[0] = __builtin_amdgcn_mfma_f32_16x16x32_bf16(af0, w1f[i], acc1[0], 0,0,0);
            acc1[1] = __builtin_amdgcn_mfma_f32_16x16x32_bf16(af1, w1f[i], acc1[1], 0,0,0);
        }

        // relu + bias -> Z[kk&1]
        {
            int col = wave*16 + cc;
            float bb = b1[kk*256 + col];
            #pragma unroll
            for (int mt = 0; mt < 2; mt++)
                #pragma unroll
                for (int r = 0; r < 4; r++) {
                    float z = fmaxf(acc1[mt][r] + bb, 0.f);
                    U.f.Z[kk & 1][mt*16 + quad*4 + r][col] =
                        (short)__bfloat16_as_ushort(__float2bfloat16(z));
                }
        }
        __syncthreads();

        // prefetch W1[kk+1] fragments (covered by FF2)
        {
            int nk = (kk < 3) ? kk + 1 : 3;
            const short* wp = W1s + (size_t)(nk * 16 + wave) * 8 * 512 + lane * 8;
            #pragma unroll
            for (int i = 0; i < 8; i++)
                w1f[i] = *(const bf16x8*)(wp + i * 512);
        }

        // FF2 partial
        #pragma unroll
        for (int i = 0; i < 8; i++) {
            bf16x8 zf0 = *(const bf16x8*)&U.f.Z[kk & 1][lr][i*32 + hi*8];
            bf16x8 zf1 = *(const bf16x8*)&U.f.Z[kk & 1][16 + lr][i*32 + hi*8];
            acc2[0] = __builtin_amdgcn_mfma_f32_16x16x32_bf16(zf0, w2f[i], acc2[0], 0,0,0);
            acc2[1] = __builtin_amdgcn_mfma_f32_16x16x32_bf16(zf1, w2f[i], acc2[1], 0,0,0);
        }
        // Z[kk&1] overwritten only at kk+2, after the kk+1 barrier.
    }

    // ======== phase 5: h = H_lds + FF2 + b2 ========
    {
        int col = wave*16 + cc;
        float bb = b2[col];
        #pragma unroll
        for (int mt = 0; mt < 2; mt++)
            #pragma unroll
            for (int r = 0; r < 4; r++) {
                int rowl = mt*16 + quad*4 + r;
                int row = b * SEQ + i0 + rowl;
                h[(size_t)row * HDIM + col] = H_lds[rowl][col] + acc2[mt][r] + bb;
            }
    }
}

// ---------------------------------------------------------------------------
extern "C" void kernel_launch(void* const* d_in, const int* in_sizes, int n_in,
                              void* d_out, int out_size, void* d_ws, size_t ws_size,
                              hipStream_t stream)
{
    const float* x     = (const float*)d_in[0];
    const float* w_in  = (const float*)d_in[1];
    const float* w_out = (const float*)d_in[2];
    const float* b_out = (const float*)d_in[3];
    const float* qkv_w = (const float*)d_in[4];
    const float* qkv_b = (const float*)d_in[5];
    const float* out_w = (const float*)d_in[6];
    const float* out_b = (const float*)d_in[7];
    const float* ln1_g = (const float*)d_in[8];
    const float* ln1_b = (const float*)d_in[9];
    const float* ln2_g = (const float*)d_in[10];
    const float* ln2_b = (const float*)d_in[11];
    const float* ff1_w = (const float*)d_in[12];
    const float* ff1_b = (const float*)d_in[13];
    const float* ff2_w = (const float*)d_in[14];
    const float* ff2_b = (const float*)d_in[15];
    const float* lnf_g = (const float*)d_in[16];
    const float* lnf_b = (const float*)d_in[17];

    char* ws = (char*)d_ws;
    float*          h    = (float*)ws;                        // [0, 8M)
    __hip_bfloat16* qkvd = (__hip_bfloat16*)(ws + 8388608);   // [8M, ~21M)
    __hip_bfloat16* wb   = (__hip_bfloat16*)(ws + 25165824);  // weights bf16 (~5 MB)

    __hip_bfloat16* w_in_b  = wb;
    __hip_bfloat16* w_out_b = wb + 65536;
    __hip_bfloat16* qkv_w_b = wb + 131072;
    __hip_bfloat16* out_w_b = wb + 720896;
    __hip_bfloat16* ff1_w_b = wb + 917504;
    __hip_bfloat16* ff2_w_b = wb + 1703936;

    dim3 blk(256);

    cvt_all<<<1216, blk, 0, stream>>>(w_in, w_out, qkv_w, out_w, ff1_w, ff2_w, wb);

    // h = 16 * (x @ w_in^T) + PE
    embed_pe<<<dim3(4, 128), blk, 0, stream>>>(x, w_in_b, h);

    for (int l = 0; l < 3; l++) {
        // qkv = LN1(h) @ qkv_w^T + qkv_b; NT=256 -> h re-read 3x (was 6x)
        gemm_ln<5, 256><<<dim3(3, 128), blk, 0, stream>>>(
            h, ln1_g + l*HDIM, ln1_b + l*HDIM,
            qkv_w_b + (size_t)l*768*HDIM, qkv_b + l*768, qkvd, nullptr, 768, HDIM);
        // attention + proj + residual + LN2 + FFN + residual (single kernel)
        attn_ffn<<<dim3(SEQ/32, BATCH), dim3(1024), 0, stream>>>(
            qkvd, out_w_b + (size_t)l*HDIM*HDIM, out_b + l*HDIM, h,
            ln2_g + l*HDIM, ln2_b + l*HDIM,
            ff1_w_b + (size_t)l*FFN_DIM*HDIM, ff1_b + l*FFN_DIM,
            ff2_w_b + (size_t)l*HDIM*FFN_DIM, ff2_b + l*HDIM);
    }

    // out = LNf(h) @ w_out^T + b_out   (fp32)
    gemm_ln<4, 64><<<dim3(4, 128), blk, 0, stream>>>(
        h, lnf_g, lnf_b, w_out_b, b_out, nullptr, (float*)d_out, HDIM, HDIM);
}

// Round 8
// 257.259 us; speedup vs baseline: 1.0069x; 1.0069x over previous
//
#include <hip/hip_runtime.h>
#include <hip/hip_bf16.h>
#include <math.h>

#define SEQ 2048
#define BATCH 4
#define HDIM 256
#define NHEAD 4
#define FFN_DIM 1024
#define MTOT (BATCH*SEQ)   // 8192

typedef __attribute__((ext_vector_type(8))) short bf16x8;
typedef __attribute__((ext_vector_type(4))) float f32x4;

__device__ __forceinline__ bf16x8 cvt8(const float* p)
{
    float4 a = *(const float4*)p;
    float4 b = *(const float4*)(p + 4);
    union { bf16x8 v; __hip_bfloat16 e[8]; } u;
    u.e[0] = __float2bfloat16(a.x); u.e[1] = __float2bfloat16(a.y);
    u.e[2] = __float2bfloat16(a.z); u.e[3] = __float2bfloat16(a.w);
    u.e[4] = __float2bfloat16(b.x); u.e[5] = __float2bfloat16(b.y);
    u.e[6] = __float2bfloat16(b.z); u.e[7] = __float2bfloat16(b.w);
    return u.v;
}

// ---------------------------------------------------------------------------
// Weights f32 -> bf16, re-laid out in MFMA-FRAGMENT TILES:
//   W[N][K] -> tiles [N/16][K/32][lane=0..63][8], where
//   lane = ((k>>3)&3)*16 + (row&15), elem = k&7.
// A fragment load is then ONE coalesced 1KB read: base + tile*512 + lane*8.
// ---------------------------------------------------------------------------
__global__ __launch_bounds__(256)
void cvt_all(const float* __restrict__ w_in, const float* __restrict__ w_out,
             const float* __restrict__ qkv_w, const float* __restrict__ out_w,
             const float* __restrict__ ff1_w, const float* __restrict__ ff2_w,
             __hip_bfloat16* __restrict__ wb)
{
    int i = blockIdx.x * 256 + threadIdx.x;   // grid 1216 -> exact (311296 thr)
    size_t e = (size_t)i * 8;

    const float* srcbase; size_t rbase; int kshift;  // K = 1<<kshift
    if (e < 720896) {
        if (e < 65536)       { srcbase = w_in;  rbase = 0;      kshift = 8; }
        else if (e < 131072) { srcbase = w_out; rbase = 65536;  kshift = 8; }
        else                 { srcbase = qkv_w; rbase = 131072; kshift = 8; }
    } else if (e < 917504)   { srcbase = out_w; rbase = 720896; kshift = 8; }
    else if (e < 1703936)    { srcbase = ff1_w; rbase = 917504; kshift = 8; }
    else                     { srcbase = ff2_w; rbase = 1703936; kshift = 10; }

    size_t local = e - rbase;
    int K = 1 << kshift;
    int row = (int)(local >> kshift);
    int k   = (int)(local & (K - 1));          // multiple of 8

    size_t dst = rbase
               + ((size_t)(row >> 4) * (K >> 5) + (k >> 5)) * 512
               + (size_t)((((k >> 3) & 3) << 4) | (row & 15)) * 8;

    *(bf16x8*)(wb + dst) = cvt8(srcbase + local);
}

// fragment-tile load helper: W swizzled with inner-dim K, n0 16-aligned
__device__ __forceinline__ bf16x8 fragW(const short* W, int n0, int k0, int K, int lane)
{
    return *(const bf16x8*)(W + ((size_t)(n0 >> 4) * (K >> 5) + (k0 >> 5)) * 512 + lane * 8);
}

// ---------------------------------------------------------------------------
// Embed: h = 16 * (x @ w_in^T) + PE.
// ---------------------------------------------------------------------------
__global__ __launch_bounds__(256)
void embed_pe(const float* __restrict__ X, const __hip_bfloat16* __restrict__ W,
              float* __restrict__ hbuf)
{
    int tid = threadIdx.x, wave = tid >> 6, lane = tid & 63;
    int wm = wave >> 1, wn = wave & 1;
    int rowBase = blockIdx.y * 64 + wm * 32;
    int colBase = blockIdx.x * 64 + wn * 32;
    int lr = lane & 15, hi = lane >> 4;

    const float* px0 = X + (size_t)(rowBase + lr) * HDIM + hi * 8;
    const float* px1 = px0 + (size_t)16 * HDIM;
    const short* Wb  = (const short*)W;

    f32x4 acc[2][2];
    acc[0][0] = (f32x4){0.f,0.f,0.f,0.f}; acc[0][1] = (f32x4){0.f,0.f,0.f,0.f};
    acc[1][0] = (f32x4){0.f,0.f,0.f,0.f}; acc[1][1] = (f32x4){0.f,0.f,0.f,0.f};

    #pragma unroll
    for (int k0 = 0; k0 < 256; k0 += 32) {
        bf16x8 a0 = cvt8(px0 + k0);
        bf16x8 a1 = cvt8(px1 + k0);
        bf16x8 b0 = fragW(Wb, colBase,      k0, 256, lane);
        bf16x8 b1 = fragW(Wb, colBase + 16, k0, 256, lane);
        acc[0][0] = __builtin_amdgcn_mfma_f32_16x16x32_bf16(a0, b0, acc[0][0], 0,0,0);
        acc[0][1] = __builtin_amdgcn_mfma_f32_16x16x32_bf16(a0, b1, acc[0][1], 0,0,0);
        acc[1][0] = __builtin_amdgcn_mfma_f32_16x16x32_bf16(a1, b0, acc[1][0], 0,0,0);
        acc[1][1] = __builtin_amdgcn_mfma_f32_16x16x32_bf16(a1, b1, acc[1][1], 0,0,0);
    }

    int cc = lane & 15, quad = lane >> 4;
    #pragma unroll
    for (int mt = 0; mt < 2; mt++)
        #pragma unroll
        for (int nt = 0; nt < 2; nt++) {
            int col = colBase + nt*16 + cc;
            int i2 = col & ~1;
            float freq = __expf((float)i2 * (-9.210340371976184f / 256.0f));
            #pragma unroll
            for (int r = 0; r < 4; r++) {
                int row = rowBase + mt*16 + quad*4 + r;
                float arg = (float)(row & (SEQ-1)) * freq;
                float pe = (col & 1) ? __cosf(arg) : __sinf(arg);
                hbuf[(size_t)row*HDIM + col] = 16.0f*acc[mt][nt][r] + pe;
            }
        }
}

// ---------------------------------------------------------------------------
// LN-fused GEMM, 64-row tile. Weights in fragment-tile layout.
// MODE 4: of32 = C + bias
// MODE 5: head-split qkv write; Q/K sections fragment-tiled over (seq, d);
//         V section fragment-tiled TRANSPOSED over (d, seq).
// ---------------------------------------------------------------------------
template<int MODE, int NT>
__global__ __launch_bounds__(256)
void gemm_ln(const float* __restrict__ h,
             const float* __restrict__ g, const float* __restrict__ bln,
             const __hip_bfloat16* __restrict__ W,
             const float* __restrict__ bias,
             __hip_bfloat16* __restrict__ obf, float* __restrict__ of32,
             int N, int ldw)
{
    constexpr int NTW = NT / 32;
    __shared__ __align__(16) short A_lds[64][264];

    int tid = threadIdx.x, wave = tid >> 6, lane = tid & 63;
    int wm = wave >> 1, wn = wave & 1;
    int rowBase = blockIdx.y * 64;
    int colBase = blockIdx.x * NT + wn * (NT / 2);

    {
        float4 gv = *(const float4*)(g + lane * 4);
        float4 bv = *(const float4*)(bln + lane * 4);
        #pragma unroll
        for (int rr = 0; rr < 16; rr += 4) {
            float4 xv[4];
            #pragma unroll
            for (int u = 0; u < 4; u++)
                xv[u] = *(const float4*)(h + (size_t)(rowBase + wave*16 + rr + u)*HDIM + lane*4);
            #pragma unroll
            for (int u = 0; u < 4; u++) {
                float s = xv[u].x + xv[u].y + xv[u].z + xv[u].w;
                #pragma unroll
                for (int off = 32; off >= 1; off >>= 1) s += __shfl_xor(s, off);
                float mu = s * (1.0f/256.0f);
                float d0 = xv[u].x-mu, d1 = xv[u].y-mu, d2 = xv[u].z-mu, d3 = xv[u].w-mu;
                float v = d0*d0 + d1*d1 + d2*d2 + d3*d3;
                #pragma unroll
                for (int off = 32; off >= 1; off >>= 1) v += __shfl_xor(v, off);
                float rstd = rsqrtf(v * (1.0f/256.0f) + 1e-5f);
                union { short e[4]; uint2 w2; } o;
                o.e[0] = (short)__bfloat16_as_ushort(__float2bfloat16(d0*rstd*gv.x + bv.x));
                o.e[1] = (short)__bfloat16_as_ushort(__float2bfloat16(d1*rstd*gv.y + bv.y));
                o.e[2] = (short)__bfloat16_as_ushort(__float2bfloat16(d2*rstd*gv.z + bv.z));
                o.e[3] = (short)__bfloat16_as_ushort(__float2bfloat16(d3*rstd*gv.w + bv.w));
                *(uint2*)&A_lds[wave*16 + rr + u][lane*4] = o.w2;
            }
        }
    }
    __syncthreads();

    int lr = lane & 15, hi = lane >> 4;
    f32x4 acc[2][NTW];
    #pragma unroll
    for (int mt = 0; mt < 2; mt++)
        #pragma unroll
        for (int nt = 0; nt < NTW; nt++)
            acc[mt][nt] = (f32x4){0.f,0.f,0.f,0.f};

    const short* Ws = (const short*)W;
    #pragma unroll
    for (int k0 = 0; k0 < 256; k0 += 32) {
        bf16x8 af[2], bfr[NTW];
        #pragma unroll
        for (int mt = 0; mt < 2; mt++)
            af[mt] = *(const bf16x8*)&A_lds[wm*32 + mt*16 + lr][k0 + hi*8];
        #pragma unroll
        for (int nt = 0; nt < NTW; nt++)
            bfr[nt] = fragW(Ws, colBase + nt*16, k0, 256, lane);
        #pragma unroll
        for (int mt = 0; mt < 2; mt++)
            #pragma unroll
            for (int nt = 0; nt < NTW; nt++)
                acc[mt][nt] = __builtin_amdgcn_mfma_f32_16x16x32_bf16(af[mt], bfr[nt], acc[mt][nt], 0,0,0);
    }

    int cc = lane & 15, quad = lane >> 4;
    #pragma unroll
    for (int mt = 0; mt < 2; mt++)
        #pragma unroll
        for (int nt = 0; nt < NTW; nt++) {
            int col = colBase + nt*16 + cc;
            float bv = bias[col];
            #pragma unroll
            for (int r = 0; r < 4; r++) {
                int row = rowBase + wm*32 + mt*16 + quad*4 + r;
                float c = acc[mt][nt][r] + bv;
                if (MODE == 4) { of32[(size_t)row*N + col] = c; }
                else { // MODE 5
                    int sec = col >> 8, hd = (col >> 6) & 3, d = col & 63;
                    int srow = row & (SEQ - 1);
                    size_t base = (size_t)sec * 2097152
                                + (size_t)(((row >> 11) << 2) | hd) * 131072;
                    size_t idx;
                    if (sec < 2)   // Q/K: tiles [s/16][d/32]
                        idx = base + (size_t)(srow >> 4) * 1024 + (size_t)(d >> 5) * 512
                            + (size_t)((((d >> 3) & 3) << 4) | (srow & 15)) * 8 + (d & 7);
                    else           // V^T: tiles [d/16][s/32]
                        idx = base + ((size_t)(d >> 4) * 64 + (srow >> 5)) * 512
                            + (size_t)((((srow >> 3) & 3) << 4) | (d & 15)) * 8 + (srow & 7);
                    obf[idx] = __float2bfloat16(c);
                }
            }
        }
}

// ---------------------------------------------------------------------------
// FULLY FUSED layer tail, 1024 threads / 16 waves. ALL matrix operands
// (Q, K, V^T, ow, W1, W2) are single coalesced 1KB fragment reads.
// V never touches LDS (global V^T fragment tiles).
// ---------------------------------------------------------------------------
struct AttnLDS {
    __align__(16) __hip_bfloat16 Pl[32][104];   // stride 104: 2-way banks
    float sm[2][32], ss[2][32];
};

__global__ __launch_bounds__(1024)
void attn_ffn(const __hip_bfloat16* __restrict__ qkvd,
              const __hip_bfloat16* __restrict__ ow,   // fragment-tiled [256][256]
              const float* __restrict__ ob,
              float* __restrict__ h,
              const float* __restrict__ g, const float* __restrict__ bln,
              const __hip_bfloat16* __restrict__ W1, const float* __restrict__ b1,
              const __hip_bfloat16* __restrict__ W2, const float* __restrict__ b2)
{
    __shared__ union SMem {
        AttnLDS asl[4];                                   // ~28 KB (attention)
        struct {
            __align__(16) short A[32][264];               // LN2 out (bf16)
            __align__(16) short Z[2][32][264];            // FFN hidden, dbuf
        } f;                                              // ~51 KB (FFN)
    } U;
    __shared__ __align__(16) short att_lds[32][264];
    __shared__ __align__(16) float H_lds[32][260];

    int tid  = threadIdx.x;
    int wave = tid >> 6, lane = tid & 63;
    int grp  = wave >> 2, w4 = wave & 3;
    int b    = blockIdx.y, i0 = blockIdx.x * 32;
    int klo  = i0 - 32;

    int lr = lane & 15, hi = lane >> 4;
    int cc = lane & 15, quad = lane >> 4;

    int hd = grp;
    AttnLDS& S = U.asl[grp];
    const short* Qd = (const short*)qkvd + (size_t)(b * 4 + hd) * 131072;
    const short* Kd = Qd + 2097152;
    const short* Vd = Qd + 4194304;
    int qh = w4 & 1, seg = w4 >> 1;
    int qoff = qh * 16 + quad * 4;

    // ======== ENTRY PREFETCH (all coalesced fragment loads) ========
    // Q fragments
    bf16x8 qf[2];
    #pragma unroll
    for (int ds = 0; ds < 2; ds++)
        qf[ds] = *(const bf16x8*)(Qd + (size_t)((i0 >> 4) + qh) * 1024 + ds * 512 + lane * 8);
    // K fragments
    bf16x8 kf[3][2];
    #pragma unroll
    for (int t = 0; t < 3; t++) {
        int jt = (klo + seg * 48 + t * 16) >> 4;
        jt = jt < 0 ? 0 : (jt > 127 ? 127 : jt);
        kf[t][0] = *(const bf16x8*)(Kd + (size_t)jt * 1024 + lane * 8);
        kf[t][1] = *(const bf16x8*)(Kd + (size_t)jt * 1024 + 512 + lane * 8);
    }
    // V^T fragments (tiles [d/16][s/32]; clamped tiles pair with P==0 exactly)
    bf16x8 vf[3][2];
    #pragma unroll
    for (int ks = 0; ks < 3; ks++) {
        int s0 = klo + ks * 32;
        s0 = s0 < 0 ? 0 : (s0 > SEQ - 32 ? SEQ - 32 : s0);
        #pragma unroll
        for (int dt = 0; dt < 2; dt++) {
            int d0 = seg*32 + dt*16;
            vf[ks][dt] = *(const bf16x8*)(Vd + ((size_t)(d0 >> 4) * 64 + (s0 >> 5)) * 512 + lane * 8);
        }
    }
    // residual h_old
    float hold[2][4];
    {
        const float* hp = h + (size_t)(b * SEQ + i0) * HDIM + wave * 16 + cc;
        #pragma unroll
        for (int mt = 0; mt < 2; mt++)
            #pragma unroll
            for (int r = 0; r < 4; r++)
                hold[mt][r] = hp[(size_t)(mt*16 + quad*4 + r) * HDIM];
    }

    // ======== phase 1: attention ========
    f32x4 sacc[3];
    #pragma unroll
    for (int t = 0; t < 3; t++) {
        f32x4 a = (f32x4){0.f,0.f,0.f,0.f};
        a = __builtin_amdgcn_mfma_f32_16x16x32_bf16(qf[0], kf[t][0], a, 0,0,0);
        a = __builtin_amdgcn_mfma_f32_16x16x32_bf16(qf[1], kf[t][1], a, 0,0,0);
        sacc[t] = a;
    }

    float s[3][4];
    #pragma unroll
    for (int t = 0; t < 3; t++) {
        int koff = seg * 48 + t * 16 + cc;
        int jj = klo + koff;
        #pragma unroll
        for (int r = 0; r < 4; r++) {
            int rel = koff - (qoff + r);
            bool ok = (jj >= 0) && (jj < SEQ) && (rel >= 0) && (rel <= 64);
            s[t][r] = ok ? sacc[t][r] * 0.125f : -1e30f;
        }
    }

    float mrow[4], srow[4];
    #pragma unroll
    for (int r = 0; r < 4; r++)
        mrow[r] = fmaxf(fmaxf(s[0][r], s[1][r]), s[2][r]);
    #pragma unroll
    for (int off = 8; off >= 1; off >>= 1)
        #pragma unroll
        for (int r = 0; r < 4; r++)
            mrow[r] = fmaxf(mrow[r], __shfl_xor(mrow[r], off));
    #pragma unroll
    for (int r = 0; r < 4; r++)
        srow[r] = __expf(s[0][r]-mrow[r]) + __expf(s[1][r]-mrow[r]) + __expf(s[2][r]-mrow[r]);
    #pragma unroll
    for (int off = 8; off >= 1; off >>= 1)
        #pragma unroll
        for (int r = 0; r < 4; r++)
            srow[r] += __shfl_xor(srow[r], off);
    if (cc == 0) {
        #pragma unroll
        for (int r = 0; r < 4; r++) { S.sm[seg][qoff+r] = mrow[r]; S.ss[seg][qoff+r] = srow[r]; }
    }
    __syncthreads();

    float Mr[4], inv[4];
    #pragma unroll
    for (int r = 0; r < 4; r++) {
        float m0 = S.sm[0][qoff+r], m1 = S.sm[1][qoff+r];
        float M = fmaxf(m0, m1);
        float dn = S.ss[0][qoff+r] * __expf(m0 - M) + S.ss[1][qoff+r] * __expf(m1 - M);
        Mr[r] = M; inv[r] = 1.0f / dn;
    }
    #pragma unroll
    for (int t = 0; t < 3; t++)
        #pragma unroll
        for (int r = 0; r < 4; r++)
            S.Pl[qoff+r][seg*48 + t*16 + cc] = __float2bfloat16(__expf(s[t][r]-Mr[r]) * inv[r]);
    __syncthreads();

    // prefetch proj weight fragments (coalesced; hidden under PV)
    bf16x8 owf[8];
    {
        const short* op = (const short*)ow + (size_t)wave * 8 * 512 + lane * 8;
        #pragma unroll
        for (int i = 0; i < 8; i++)
            owf[i] = *(const bf16x8*)(op + i * 512);
    }

    // O = P @ V -> att_lds (V already in registers)
    {
        f32x4 oacc[2];
        oacc[0] = (f32x4){0.f,0.f,0.f,0.f}; oacc[1] = (f32x4){0.f,0.f,0.f,0.f};
        #pragma unroll
        for (int ks = 0; ks < 3; ks++) {
            bf16x8 pf = *(const bf16x8*)&S.Pl[qh*16 + lr][ks*32 + hi*8];
            #pragma unroll
            for (int dt = 0; dt < 2; dt++)
                oacc[dt] = __builtin_amdgcn_mfma_f32_16x16x32_bf16(pf, vf[ks][dt], oacc[dt], 0,0,0);
        }
        #pragma unroll
        for (int dt = 0; dt < 2; dt++) {
            int col = hd*64 + seg*32 + dt*16 + cc;
            #pragma unroll
            for (int r = 0; r < 4; r++)
                att_lds[qoff + r][col] =
                    (short)__bfloat16_as_ushort(__float2bfloat16(oacc[dt][r]));
        }
    }
    __syncthreads();

    // ======== phase 2: proj + residual -> H_lds (wave owns 16 cols) ========
    {
        f32x4 acc[2];
        acc[0] = (f32x4){0.f,0.f,0.f,0.f}; acc[1] = (f32x4){0.f,0.f,0.f,0.f};
        #pragma unroll
        for (int i = 0; i < 8; i++) {
            bf16x8 a0 = *(const bf16x8*)&att_lds[lr][i*32 + hi*8];
            bf16x8 a1 = *(const bf16x8*)&att_lds[16 + lr][i*32 + hi*8];
            acc[0] = __builtin_amdgcn_mfma_f32_16x16x32_bf16(a0, owf[i], acc[0], 0,0,0);
            acc[1] = __builtin_amdgcn_mfma_f32_16x16x32_bf16(a1, owf[i], acc[1], 0,0,0);
        }
        float bv = ob[wave*16 + cc];
        #pragma unroll
        for (int mt = 0; mt < 2; mt++)
            #pragma unroll
            for (int r = 0; r < 4; r++)
                H_lds[mt*16 + quad*4 + r][wave*16 + cc] = hold[mt][r] + acc[mt][r] + bv;
    }

    // prologue: prefetch W1 chunk 0 (coalesced; hidden under barrier + LN2)
    const short* W1s = (const short*)W1;
    const short* W2s = (const short*)W2;
    bf16x8 w1f[8];
    {
        const short* wp = W1s + (size_t)wave * 8 * 512 + lane * 8;
        #pragma unroll
        for (int i = 0; i < 8; i++)
            w1f[i] = *(const bf16x8*)(wp + i * 512);
    }
    __syncthreads();

    // ======== phase 3: LN2(H_lds) -> A bf16 (each wave: 2 rows) ========
    {
        float4 gv = *(const float4*)(g + lane * 4);
        float4 bv = *(const float4*)(bln + lane * 4);
        #pragma unroll
        for (int u = 0; u < 2; u++) {
            float4 xv = *(const float4*)&H_lds[wave*2 + u][lane*4];
            float ss2 = xv.x + xv.y + xv.z + xv.w;
            #pragma unroll
            for (int off = 32; off >= 1; off >>= 1) ss2 += __shfl_xor(ss2, off);
            float mu = ss2 * (1.0f/256.0f);
            float d0 = xv.x-mu, d1 = xv.y-mu, d2 = xv.z-mu, d3 = xv.w-mu;
            float v = d0*d0 + d1*d1 + d2*d2 + d3*d3;
            #pragma unroll
            for (int off = 32; off >= 1; off >>= 1) v += __shfl_xor(v, off);
            float rstd = rsqrtf(v * (1.0f/256.0f) + 1e-5f);
            union { short e[4]; uint2 w2; } o;
            o.e[0] = (short)__bfloat16_as_ushort(__float2bfloat16(d0*rstd*gv.x + bv.x));
            o.e[1] = (short)__bfloat16_as_ushort(__float2bfloat16(d1*rstd*gv.y + bv.y));
            o.e[2] = (short)__bfloat16_as_ushort(__float2bfloat16(d2*rstd*gv.z + bv.z));
            o.e[3] = (short)__bfloat16_as_ushort(__float2bfloat16(d3*rstd*gv.w + bv.w));
            *(uint2*)&U.f.A[wave*2 + u][lane*4] = o.w2;
        }
    }
    __syncthreads();

    // ======== phase 4: FFN, Z dbuf, weights software-pipelined ========
    f32x4 acc2[2];
    acc2[0] = (f32x4){0.f,0.f,0.f,0.f}; acc2[1] = (f32x4){0.f,0.f,0.f,0.f};

    #pragma unroll 1
    for (int kk = 0; kk < 4; kk++) {
        // prefetch W2[kk] fragments (coalesced)
        bf16x8 w2f[8];
        {
            const short* wp = W2s + (size_t)(wave * 32 + kk * 8) * 512 + lane * 8;
            #pragma unroll
            for (int i = 0; i < 8; i++)
                w2f[i] = *(const bf16x8*)(wp + i * 512);
        }

        // FF1 chunk
        f32x4 acc1[2];
        acc1[0] = (f32x4){0.f,0.f,0.f,0.f}; acc1[1] = (f32x4){0.f,0.f,0.f,0.f};
        #pragma unroll
        for (int i = 0; i < 8; i++) {
            bf16x8 af0 = *(const bf16x8*)&U.f.A[lr][i*32 + hi*8];
            bf16x8 af1 = *(const bf16x8*)&U.f.A[16 + lr][i*32 + hi*8];
            acc1[0] = __builtin_amdgcn_mfma_f32_16x16x32_bf16(af0, w1f[i], acc1[0], 0,0,0);
            acc1[1] = __builtin_amdgcn_mfma_f32_16x16x32_bf16(af1, w1f[i], acc1[1], 0,0,0);
        }

        // relu + bias -> Z[kk&1]
        {
            int col = wave*16 + cc;
            float bb = b1[kk*256 + col];
            #pragma unroll
            for (int mt = 0; mt < 2; mt++)
                #pragma unroll
                for (int r = 0; r < 4; r++) {
                    float z = fmaxf(acc1[mt][r] + bb, 0.f);
                    U.f.Z[kk & 1][mt*16 + quad*4 + r][col] =
                        (short)__bfloat16_as_ushort(__float2bfloat16(z));
                }
        }
        __syncthreads();

        // prefetch W1[kk+1] fragments (covered by FF2)
        {
            int nk = (kk < 3) ? kk + 1 : 3;
            const short* wp = W1s + (size_t)(nk * 16 + wave) * 8 * 512 + lane * 8;
            #pragma unroll
            for (int i = 0; i < 8; i++)
                w1f[i] = *(const bf16x8*)(wp + i * 512);
        }

        // FF2 partial
        #pragma unroll
        for (int i = 0; i < 8; i++) {
            bf16x8 zf0 = *(const bf16x8*)&U.f.Z[kk & 1][lr][i*32 + hi*8];
            bf16x8 zf1 = *(const bf16x8*)&U.f.Z[kk & 1][16 + lr][i*32 + hi*8];
            acc2[0] = __builtin_amdgcn_mfma_f32_16x16x32_bf16(zf0, w2f[i], acc2[0], 0,0,0);
            acc2[1] = __builtin_amdgcn_mfma_f32_16x16x32_bf16(zf1, w2f[i], acc2[1], 0,0,0);
        }
        // Z[kk&1] overwritten only at kk+2, after the kk+1 barrier.
    }

    // ======== phase 5: h = H_lds + FF2 + b2 ========
    {
        int col = wave*16 + cc;
        float bb = b2[col];
        #pragma unroll
        for (int mt = 0; mt < 2; mt++)
            #pragma unroll
            for (int r = 0; r < 4; r++) {
                int rowl = mt*16 + quad*4 + r;
                int row = b * SEQ + i0 + rowl;
                h[(size_t)row * HDIM + col] = H_lds[rowl][col] + acc2[mt][r] + bb;
            }
    }
}

// ---------------------------------------------------------------------------
extern "C" void kernel_launch(void* const* d_in, const int* in_sizes, int n_in,
                              void* d_out, int out_size, void* d_ws, size_t ws_size,
                              hipStream_t stream)
{
    const float* x     = (const float*)d_in[0];
    const float* w_in  = (const float*)d_in[1];
    const float* w_out = (const float*)d_in[2];
    const float* b_out = (const float*)d_in[3];
    const float* qkv_w = (const float*)d_in[4];
    const float* qkv_b = (const float*)d_in[5];
    const float* out_w = (const float*)d_in[6];
    const float* out_b = (const float*)d_in[7];
    const float* ln1_g = (const float*)d_in[8];
    const float* ln1_b = (const float*)d_in[9];
    const float* ln2_g = (const float*)d_in[10];
    const float* ln2_b = (const float*)d_in[11];
    const float* ff1_w = (const float*)d_in[12];
    const float* ff1_b = (const float*)d_in[13];
    const float* ff2_w = (const float*)d_in[14];
    const float* ff2_b = (const float*)d_in[15];
    const float* lnf_g = (const float*)d_in[16];
    const float* lnf_b = (const float*)d_in[17];

    char* ws = (char*)d_ws;
    float*          h    = (float*)ws;                        // [0, 8M)
    __hip_bfloat16* qkvd = (__hip_bfloat16*)(ws + 8388608);   // [8M, ~21M)
    __hip_bfloat16* wb   = (__hip_bfloat16*)(ws + 25165824);  // weights bf16 (~5 MB)

    __hip_bfloat16* w_in_b  = wb;
    __hip_bfloat16* w_out_b = wb + 65536;
    __hip_bfloat16* qkv_w_b = wb + 131072;
    __hip_bfloat16* out_w_b = wb + 720896;
    __hip_bfloat16* ff1_w_b = wb + 917504;
    __hip_bfloat16* ff2_w_b = wb + 1703936;

    dim3 blk(256);

    cvt_all<<<1216, blk, 0, stream>>>(w_in, w_out, qkv_w, out_w, ff1_w, ff2_w, wb);

    // h = 16 * (x @ w_in^T) + PE
    embed_pe<<<dim3(4, 128), blk, 0, stream>>>(x, w_in_b, h);

    for (int l = 0; l < 3; l++) {
        // qkv = LN1(h) @ qkv_w^T + qkv_b; NT=192 -> grid 512 = 2 blocks/CU, balanced
        gemm_ln<5, 192><<<dim3(4, 128), blk, 0, stream>>>(
            h, ln1_g + l*HDIM, ln1_b + l*HDIM,
            qkv_w_b + (size_t)l*768*HDIM, qkv_b + l*768, qkvd, nullptr, 768, HDIM);
        // attention + proj + residual + LN2 + FFN + residual (single kernel)
        attn_ffn<<<dim3(SEQ/32, BATCH), dim3(1024), 0, stream>>>(
            qkvd, out_w_b + (size_t)l*HDIM*HDIM, out_b + l*HDIM, h,
            ln2_g + l*HDIM, ln2_b + l*HDIM,
            ff1_w_b + (size_t)l*FFN_DIM*HDIM, ff1_b + l*FFN_DIM,
            ff2_w_b + (size_t)l*HDIM*FFN_DIM, ff2_b + l*HDIM);
    }

    // out = LNf(h) @ w_out^T + b_out   (fp32)
    gemm_ln<4, 64><<<dim3(4, 128), blk, 0, stream>>>(
        h, lnf_g, lnf_b, w_out_b, b_out, nullptr, (float*)d_out, HDIM, HDIM);
}

// Round 9
// 256.774 us; speedup vs baseline: 1.0088x; 1.0019x over previous
//
#include <hip/hip_runtime.h>
#include <hip/hip_bf16.h>
#include <math.h>

#define SEQ 2048
#define BATCH 4
#define HDIM 256
#define NHEAD 4
#define FFN_DIM 1024
#define MTOT (BATCH*SEQ)   // 8192

typedef __attribute__((ext_vector_type(8))) short bf16x8;
typedef __attribute__((ext_vector_type(4))) float f32x4;

__device__ __forceinline__ bf16x8 cvt8(const float* p)
{
    float4 a = *(const float4*)p;
    float4 b = *(const float4*)(p + 4);
    union { bf16x8 v; __hip_bfloat16 e[8]; } u;
    u.e[0] = __float2bfloat16(a.x); u.e[1] = __float2bfloat16(a.y);
    u.e[2] = __float2bfloat16(a.z); u.e[3] = __float2bfloat16(a.w);
    u.e[4] = __float2bfloat16(b.x); u.e[5] = __float2bfloat16(b.y);
    u.e[6] = __float2bfloat16(b.z); u.e[7] = __float2bfloat16(b.w);
    return u.v;
}

// ---------------------------------------------------------------------------
// Weights f32 -> bf16, re-laid out in MFMA-FRAGMENT TILES:
//   W[N][K] -> tiles [N/16][K/32][lane=0..63][8], where
//   lane = ((k>>3)&3)*16 + (row&15), elem = k&7.
// A fragment load is then ONE coalesced 1KB read: base + tile*512 + lane*8.
// ---------------------------------------------------------------------------
__global__ __launch_bounds__(256)
void cvt_all(const float* __restrict__ w_in, const float* __restrict__ w_out,
             const float* __restrict__ qkv_w, const float* __restrict__ out_w,
             const float* __restrict__ ff1_w, const float* __restrict__ ff2_w,
             __hip_bfloat16* __restrict__ wb)
{
    int i = blockIdx.x * 256 + threadIdx.x;   // grid 1216 -> exact (311296 thr)
    size_t e = (size_t)i * 8;

    const float* srcbase; size_t rbase; int kshift;  // K = 1<<kshift
    if (e < 720896) {
        if (e < 65536)       { srcbase = w_in;  rbase = 0;      kshift = 8; }
        else if (e < 131072) { srcbase = w_out; rbase = 65536;  kshift = 8; }
        else                 { srcbase = qkv_w; rbase = 131072; kshift = 8; }
    } else if (e < 917504)   { srcbase = out_w; rbase = 720896; kshift = 8; }
    else if (e < 1703936)    { srcbase = ff1_w; rbase = 917504; kshift = 8; }
    else                     { srcbase = ff2_w; rbase = 1703936; kshift = 10; }

    size_t local = e - rbase;
    int K = 1 << kshift;
    int row = (int)(local >> kshift);
    int k   = (int)(local & (K - 1));          // multiple of 8

    size_t dst = rbase
               + ((size_t)(row >> 4) * (K >> 5) + (k >> 5)) * 512
               + (size_t)((((k >> 3) & 3) << 4) | (row & 15)) * 8;

    *(bf16x8*)(wb + dst) = cvt8(srcbase + local);
}

// fragment-tile load helper: W swizzled with inner-dim K, n0 16-aligned
__device__ __forceinline__ bf16x8 fragW(const short* W, int n0, int k0, int K, int lane)
{
    return *(const bf16x8*)(W + ((size_t)(n0 >> 4) * (K >> 5) + (k0 >> 5)) * 512 + lane * 8);
}

// ---------------------------------------------------------------------------
// Embed: h = 16 * (x @ w_in^T) + PE.
// ---------------------------------------------------------------------------
__global__ __launch_bounds__(256)
void embed_pe(const float* __restrict__ X, const __hip_bfloat16* __restrict__ W,
              float* __restrict__ hbuf)
{
    int tid = threadIdx.x, wave = tid >> 6, lane = tid & 63;
    int wm = wave >> 1, wn = wave & 1;
    int rowBase = blockIdx.y * 64 + wm * 32;
    int colBase = blockIdx.x * 64 + wn * 32;
    int lr = lane & 15, hi = lane >> 4;

    const float* px0 = X + (size_t)(rowBase + lr) * HDIM + hi * 8;
    const float* px1 = px0 + (size_t)16 * HDIM;
    const short* Wb  = (const short*)W;

    f32x4 acc[2][2];
    acc[0][0] = (f32x4){0.f,0.f,0.f,0.f}; acc[0][1] = (f32x4){0.f,0.f,0.f,0.f};
    acc[1][0] = (f32x4){0.f,0.f,0.f,0.f}; acc[1][1] = (f32x4){0.f,0.f,0.f,0.f};

    #pragma unroll
    for (int k0 = 0; k0 < 256; k0 += 32) {
        bf16x8 a0 = cvt8(px0 + k0);
        bf16x8 a1 = cvt8(px1 + k0);
        bf16x8 b0 = fragW(Wb, colBase,      k0, 256, lane);
        bf16x8 b1 = fragW(Wb, colBase + 16, k0, 256, lane);
        acc[0][0] = __builtin_amdgcn_mfma_f32_16x16x32_bf16(a0, b0, acc[0][0], 0,0,0);
        acc[0][1] = __builtin_amdgcn_mfma_f32_16x16x32_bf16(a0, b1, acc[0][1], 0,0,0);
        acc[1][0] = __builtin_amdgcn_mfma_f32_16x16x32_bf16(a1, b0, acc[1][0], 0,0,0);
        acc[1][1] = __builtin_amdgcn_mfma_f32_16x16x32_bf16(a1, b1, acc[1][1], 0,0,0);
    }

    int cc = lane & 15, quad = lane >> 4;
    #pragma unroll
    for (int mt = 0; mt < 2; mt++)
        #pragma unroll
        for (int nt = 0; nt < 2; nt++) {
            int col = colBase + nt*16 + cc;
            int i2 = col & ~1;
            float freq = __expf((float)i2 * (-9.210340371976184f / 256.0f));
            #pragma unroll
            for (int r = 0; r < 4; r++) {
                int row = rowBase + mt*16 + quad*4 + r;
                float arg = (float)(row & (SEQ-1)) * freq;
                float pe = (col & 1) ? __cosf(arg) : __sinf(arg);
                hbuf[(size_t)row*HDIM + col] = 16.0f*acc[mt][nt][r] + pe;
            }
        }
}

// ---------------------------------------------------------------------------
// LN-fused GEMM, 64-row tile. Weights in fragment-tile layout.
// MODE 4: of32 = C + bias
// MODE 5: head-split dense qkv write; Q/K sections fragment-tiled, V dense.
// ---------------------------------------------------------------------------
template<int MODE, int NT>
__global__ __launch_bounds__(256)
void gemm_ln(const float* __restrict__ h,
             const float* __restrict__ g, const float* __restrict__ bln,
             const __hip_bfloat16* __restrict__ W,
             const float* __restrict__ bias,
             __hip_bfloat16* __restrict__ obf, float* __restrict__ of32,
             int N, int ldw)
{
    constexpr int NTW = NT / 32;
    __shared__ __align__(16) short A_lds[64][264];

    int tid = threadIdx.x, wave = tid >> 6, lane = tid & 63;
    int wm = wave >> 1, wn = wave & 1;
    int rowBase = blockIdx.y * 64;
    int colBase = blockIdx.x * NT + wn * (NT / 2);

    {
        float4 gv = *(const float4*)(g + lane * 4);
        float4 bv = *(const float4*)(bln + lane * 4);
        #pragma unroll
        for (int rr = 0; rr < 16; rr += 4) {
            float4 xv[4];
            #pragma unroll
            for (int u = 0; u < 4; u++)
                xv[u] = *(const float4*)(h + (size_t)(rowBase + wave*16 + rr + u)*HDIM + lane*4);
            #pragma unroll
            for (int u = 0; u < 4; u++) {
                float s = xv[u].x + xv[u].y + xv[u].z + xv[u].w;
                #pragma unroll
                for (int off = 32; off >= 1; off >>= 1) s += __shfl_xor(s, off);
                float mu = s * (1.0f/256.0f);
                float d0 = xv[u].x-mu, d1 = xv[u].y-mu, d2 = xv[u].z-mu, d3 = xv[u].w-mu;
                float v = d0*d0 + d1*d1 + d2*d2 + d3*d3;
                #pragma unroll
                for (int off = 32; off >= 1; off >>= 1) v += __shfl_xor(v, off);
                float rstd = rsqrtf(v * (1.0f/256.0f) + 1e-5f);
                union { short e[4]; uint2 w2; } o;
                o.e[0] = (short)__bfloat16_as_ushort(__float2bfloat16(d0*rstd*gv.x + bv.x));
                o.e[1] = (short)__bfloat16_as_ushort(__float2bfloat16(d1*rstd*gv.y + bv.y));
                o.e[2] = (short)__bfloat16_as_ushort(__float2bfloat16(d2*rstd*gv.z + bv.z));
                o.e[3] = (short)__bfloat16_as_ushort(__float2bfloat16(d3*rstd*gv.w + bv.w));
                *(uint2*)&A_lds[wave*16 + rr + u][lane*4] = o.w2;
            }
        }
    }
    __syncthreads();

    int lr = lane & 15, hi = lane >> 4;
    f32x4 acc[2][NTW];
    #pragma unroll
    for (int mt = 0; mt < 2; mt++)
        #pragma unroll
        for (int nt = 0; nt < NTW; nt++)
            acc[mt][nt] = (f32x4){0.f,0.f,0.f,0.f};

    const short* Ws = (const short*)W;
    #pragma unroll
    for (int k0 = 0; k0 < 256; k0 += 32) {
        bf16x8 af[2], bfr[NTW];
        #pragma unroll
        for (int mt = 0; mt < 2; mt++)
            af[mt] = *(const bf16x8*)&A_lds[wm*32 + mt*16 + lr][k0 + hi*8];
        #pragma unroll
        for (int nt = 0; nt < NTW; nt++)
            bfr[nt] = fragW(Ws, colBase + nt*16, k0, 256, lane);
        #pragma unroll
        for (int mt = 0; mt < 2; mt++)
            #pragma unroll
            for (int nt = 0; nt < NTW; nt++)
                acc[mt][nt] = __builtin_amdgcn_mfma_f32_16x16x32_bf16(af[mt], bfr[nt], acc[mt][nt], 0,0,0);
    }

    int cc = lane & 15, quad = lane >> 4;
    #pragma unroll
    for (int mt = 0; mt < 2; mt++)
        #pragma unroll
        for (int nt = 0; nt < NTW; nt++) {
            int col = colBase + nt*16 + cc;
            float bv = bias[col];
            #pragma unroll
            for (int r = 0; r < 4; r++) {
                int row = rowBase + wm*32 + mt*16 + quad*4 + r;
                float c = acc[mt][nt][r] + bv;
                if (MODE == 4) { of32[(size_t)row*N + col] = c; }
                else { // MODE 5
                    int sec = col >> 8, hd = (col >> 6) & 3, d = col & 63;
                    int srow = row & (SEQ - 1);
                    size_t base = (size_t)sec * 2097152
                                + (size_t)(((row >> 11) << 2) | hd) * 131072;
                    size_t idx;
                    if (sec < 2)   // Q/K: tiles [s/16][d/32]
                        idx = base + (size_t)(srow >> 4) * 1024 + (size_t)(d >> 5) * 512
                            + (size_t)((((d >> 3) & 3) << 4) | (srow & 15)) * 8 + (d & 7);
                    else           // V: dense row-major [s][64]
                        idx = base + (size_t)srow * 64 + d;
                    obf[idx] = __float2bfloat16(c);
                }
            }
        }
}

// ---------------------------------------------------------------------------
// FULLY FUSED layer tail, 1024 threads / 16 waves (round-6 form: V staged
// through LDS Vt with swizzled scatter; Q/K/weights fragment-tiled).
// ---------------------------------------------------------------------------
struct AttnLDS {
    __align__(16) __hip_bfloat16 Vt[64][128];
    __align__(16) __hip_bfloat16 Pl[32][96];
    float sm[2][32], ss[2][32];
};

__global__ __launch_bounds__(1024)
void attn_ffn(const __hip_bfloat16* __restrict__ qkvd,
              const __hip_bfloat16* __restrict__ ow,   // fragment-tiled [256][256]
              const float* __restrict__ ob,
              float* __restrict__ h,
              const float* __restrict__ g, const float* __restrict__ bln,
              const __hip_bfloat16* __restrict__ W1, const float* __restrict__ b1,
              const __hip_bfloat16* __restrict__ W2, const float* __restrict__ b2)
{
    __shared__ union SMem {
        AttnLDS asl[4];                                   // 92160 B (attention)
        struct {
            __align__(16) short A[32][264];               // LN2 out (bf16)
            __align__(16) short Z[2][32][264];            // FFN hidden, dbuf
        } f;                                              // 50688 B (FFN)
    } U;
    __shared__ __align__(16) short att_lds[32][264];
    __shared__ __align__(16) float H_lds[32][260];

    int tid  = threadIdx.x;
    int wave = tid >> 6, lane = tid & 63;
    int grp  = wave >> 2, w4 = wave & 3, ltid = tid & 255;
    int b    = blockIdx.y, i0 = blockIdx.x * 32;
    int klo  = i0 - 32;

    int lr = lane & 15, hi = lane >> 4;
    int cc = lane & 15, quad = lane >> 4;

    int hd = grp;
    AttnLDS& S = U.asl[grp];
    const short* Qd = (const short*)qkvd + (size_t)(b * 4 + hd) * 131072;
    const short* Kd = Qd + 2097152;
    const short* Vd = Qd + 4194304;
    int qh = w4 & 1, seg = w4 >> 1;
    int qoff = qh * 16 + quad * 4;

    // ======== ENTRY PREFETCH ========
    // V rows (issued FIRST -> waited first; later loads stay in flight)
    int vm = ltid & 7, vrl = ltid >> 3, vdp = vm * 8;
    bf16x8 vr[3];
    #pragma unroll
    for (int rr = 0; rr < 3; rr++) {
        int j = klo + rr * 32 + vrl;
        j = j < 0 ? 0 : (j > SEQ - 1 ? SEQ - 1 : j);
        vr[rr] = *(const bf16x8*)(Vd + (size_t)j * 64 + vdp);
    }
    // Q fragments (coalesced tile loads)
    bf16x8 qf[2];
    #pragma unroll
    for (int ds = 0; ds < 2; ds++)
        qf[ds] = *(const bf16x8*)(Qd + (size_t)((i0 >> 4) + qh) * 1024 + ds * 512 + lane * 8);
    // K fragments (coalesced tile loads; tiles fully valid or fully masked)
    bf16x8 kf[3][2];
    #pragma unroll
    for (int t = 0; t < 3; t++) {
        int jt = (klo + seg * 48 + t * 16) >> 4;
        jt = jt < 0 ? 0 : (jt > 127 ? 127 : jt);
        kf[t][0] = *(const bf16x8*)(Kd + (size_t)jt * 1024 + lane * 8);
        kf[t][1] = *(const bf16x8*)(Kd + (size_t)jt * 1024 + 512 + lane * 8);
    }
    float hold[2][4];
    {
        const float* hp = h + (size_t)(b * SEQ + i0) * HDIM + wave * 16 + cc;
        #pragma unroll
        for (int mt = 0; mt < 2; mt++)
            #pragma unroll
            for (int r = 0; r < 4; r++)
                hold[mt][r] = hp[(size_t)(mt*16 + quad*4 + r) * HDIM];
    }

    // ======== phase 1: attention ========
    { // scatter V^T (waits only on vr; Q/K/h_old remain outstanding)
        union { bf16x8 v; short e[8]; } u;
        #pragma unroll
        for (int rr = 0; rr < 3; rr++) {
            int row = rr * 32 + vrl;
            int colp = row ^ (vm << 3);
            u.v = vr[rr];
            #pragma unroll
            for (int jj = 0; jj < 8; jj++)
                *(short*)&S.Vt[vdp + jj][colp] = u.e[jj];
        }
    }

    f32x4 sacc[3];
    #pragma unroll
    for (int t = 0; t < 3; t++) {
        f32x4 a = (f32x4){0.f,0.f,0.f,0.f};
        a = __builtin_amdgcn_mfma_f32_16x16x32_bf16(qf[0], kf[t][0], a, 0,0,0);
        a = __builtin_amdgcn_mfma_f32_16x16x32_bf16(qf[1], kf[t][1], a, 0,0,0);
        sacc[t] = a;
    }

    float s[3][4];
    #pragma unroll
    for (int t = 0; t < 3; t++) {
        int koff = seg * 48 + t * 16 + cc;
        int jj = klo + koff;
        #pragma unroll
        for (int r = 0; r < 4; r++) {
            int rel = koff - (qoff + r);
            bool ok = (jj >= 0) && (jj < SEQ) && (rel >= 0) && (rel <= 64);
            s[t][r] = ok ? sacc[t][r] * 0.125f : -1e30f;
        }
    }

    float mrow[4], srow[4];
    #pragma unroll
    for (int r = 0; r < 4; r++)
        mrow[r] = fmaxf(fmaxf(s[0][r], s[1][r]), s[2][r]);
    #pragma unroll
    for (int off = 8; off >= 1; off >>= 1)
        #pragma unroll
        for (int r = 0; r < 4; r++)
            mrow[r] = fmaxf(mrow[r], __shfl_xor(mrow[r], off));
    #pragma unroll
    for (int r = 0; r < 4; r++)
        srow[r] = __expf(s[0][r]-mrow[r]) + __expf(s[1][r]-mrow[r]) + __expf(s[2][r]-mrow[r]);
    #pragma unroll
    for (int off = 8; off >= 1; off >>= 1)
        #pragma unroll
        for (int r = 0; r < 4; r++)
            srow[r] += __shfl_xor(srow[r], off);
    if (cc == 0) {
        #pragma unroll
        for (int r = 0; r < 4; r++) { S.sm[seg][qoff+r] = mrow[r]; S.ss[seg][qoff+r] = srow[r]; }
    }
    __syncthreads();

    float Mr[4], inv[4];
    #pragma unroll
    for (int r = 0; r < 4; r++) {
        float m0 = S.sm[0][qoff+r], m1 = S.sm[1][qoff+r];
        float M = fmaxf(m0, m1);
        float dn = S.ss[0][qoff+r] * __expf(m0 - M) + S.ss[1][qoff+r] * __expf(m1 - M);
        Mr[r] = M; inv[r] = 1.0f / dn;
    }
    #pragma unroll
    for (int t = 0; t < 3; t++)
        #pragma unroll
        for (int r = 0; r < 4; r++)
            S.Pl[qoff+r][seg*48 + t*16 + cc] = __float2bfloat16(__expf(s[t][r]-Mr[r]) * inv[r]);
    __syncthreads();

    // prefetch proj weight fragments (coalesced; hidden under PV)
    bf16x8 owf[8];
    {
        const short* op = (const short*)ow + (size_t)wave * 8 * 512 + lane * 8;
        #pragma unroll
        for (int i = 0; i < 8; i++)
            owf[i] = *(const bf16x8*)(op + i * 512);
    }

    // O = P @ V -> att_lds
    {
        f32x4 oacc[2];
        oacc[0] = (f32x4){0.f,0.f,0.f,0.f}; oacc[1] = (f32x4){0.f,0.f,0.f,0.f};
        #pragma unroll
        for (int ks = 0; ks < 3; ks++) {
            int kk = ks * 32;
            bf16x8 pf = *(const bf16x8*)&S.Pl[qh*16 + lr][kk + hi*8];
            #pragma unroll
            for (int dt = 0; dt < 2; dt++) {
                int d = seg*32 + dt*16 + lr;
                int colb = (kk + hi*8) ^ (((d >> 3) & 7) << 3);
                bf16x8 vf = *(const bf16x8*)&S.Vt[d][colb];
                oacc[dt] = __builtin_amdgcn_mfma_f32_16x16x32_bf16(pf, vf, oacc[dt], 0,0,0);
            }
        }
        #pragma unroll
        for (int dt = 0; dt < 2; dt++) {
            int col = hd*64 + seg*32 + dt*16 + cc;
            #pragma unroll
            for (int r = 0; r < 4; r++)
                att_lds[qoff + r][col] =
                    (short)__bfloat16_as_ushort(__float2bfloat16(oacc[dt][r]));
        }
    }
    __syncthreads();

    // ======== phase 2: proj + residual -> H_lds (wave owns 16 cols) ========
    {
        f32x4 acc[2];
        acc[0] = (f32x4){0.f,0.f,0.f,0.f}; acc[1] = (f32x4){0.f,0.f,0.f,0.f};
        #pragma unroll
        for (int i = 0; i < 8; i++) {
            bf16x8 a0 = *(const bf16x8*)&att_lds[lr][i*32 + hi*8];
            bf16x8 a1 = *(const bf16x8*)&att_lds[16 + lr][i*32 + hi*8];
            acc[0] = __builtin_amdgcn_mfma_f32_16x16x32_bf16(a0, owf[i], acc[0], 0,0,0);
            acc[1] = __builtin_amdgcn_mfma_f32_16x16x32_bf16(a1, owf[i], acc[1], 0,0,0);
        }
        float bv = ob[wave*16 + cc];
        #pragma unroll
        for (int mt = 0; mt < 2; mt++)
            #pragma unroll
            for (int r = 0; r < 4; r++)
                H_lds[mt*16 + quad*4 + r][wave*16 + cc] = hold[mt][r] + acc[mt][r] + bv;
    }

    // prologue: prefetch W1 chunk 0 (coalesced; hidden under barrier + LN2)
    const short* W1s = (const short*)W1;
    const short* W2s = (const short*)W2;
    bf16x8 w1f[8];
    {
        const short* wp = W1s + (size_t)wave * 8 * 512 + lane * 8;
        #pragma unroll
        for (int i = 0; i < 8; i++)
            w1f[i] = *(const bf16x8*)(wp + i * 512);
    }
    __syncthreads();

    // ======== phase 3: LN2(H_lds) -> A bf16 (each wave: 2 rows) ========
    {
        float4 gv = *(const float4*)(g + lane * 4);
        float4 bv = *(const float4*)(bln + lane * 4);
        #pragma unroll
        for (int u = 0; u < 2; u++) {
            float4 xv = *(const float4*)&H_lds[wave*2 + u][lane*4];
            float ss2 = xv.x + xv.y + xv.z + xv.w;
            #pragma unroll
            for (int off = 32; off >= 1; off >>= 1) ss2 += __shfl_xor(ss2, off);
            float mu = ss2 * (1.0f/256.0f);
            float d0 = xv.x-mu, d1 = xv.y-mu, d2 = xv.z-mu, d3 = xv.w-mu;
            float v = d0*d0 + d1*d1 + d2*d2 + d3*d3;
            #pragma unroll
            for (int off = 32; off >= 1; off >>= 1) v += __shfl_xor(v, off);
            float rstd = rsqrtf(v * (1.0f/256.0f) + 1e-5f);
            union { short e[4]; uint2 w2; } o;
            o.e[0] = (short)__bfloat16_as_ushort(__float2bfloat16(d0*rstd*gv.x + bv.x));
            o.e[1] = (short)__bfloat16_as_ushort(__float2bfloat16(d1*rstd*gv.y + bv.y));
            o.e[2] = (short)__bfloat16_as_ushort(__float2bfloat16(d2*rstd*gv.z + bv.z));
            o.e[3] = (short)__bfloat16_as_ushort(__float2bfloat16(d3*rstd*gv.w + bv.w));
            *(uint2*)&U.f.A[wave*2 + u][lane*4] = o.w2;
        }
    }
    __syncthreads();

    // ======== phase 4: FFN, Z dbuf, weights software-pipelined ========
    f32x4 acc2[2];
    acc2[0] = (f32x4){0.f,0.f,0.f,0.f}; acc2[1] = (f32x4){0.f,0.f,0.f,0.f};

    #pragma unroll 1
    for (int kk = 0; kk < 4; kk++) {
        // prefetch W2[kk] fragments (coalesced)
        bf16x8 w2f[8];
        {
            const short* wp = W2s + (size_t)(wave * 32 + kk * 8) * 512 + lane * 8;
            #pragma unroll
            for (int i = 0; i < 8; i++)
                w2f[i] = *(const bf16x8*)(wp + i * 512);
        }

        // FF1 chunk
        f32x4 acc1[2];
        acc1[0] = (f32x4){0.f,0.f,0.f,0.f}; acc1[1] = (f32x4){0.f,0.f,0.f,0.f};
        #pragma unroll
        for (int i = 0; i < 8; i++) {
            bf16x8 af0 = *(const bf16x8*)&U.f.A[lr][i*32 + hi*8];
            bf16x8 af1 = *(const bf16x8*)&U.f.A[16 + lr][i*32 + hi*8];
            acc1[0] = __builtin_amdgcn_mfma_f32_16x16x32_bf16(af0, w1f[i], acc1[0], 0,0,0);
            acc1[1] = __builtin_amdgcn_mfma_f32_16x16x32_bf16(af1, w1f[i], acc1[1], 0,0,0);
        }

        // relu + bias -> Z[kk&1]
        {
            int col = wave*16 + cc;
            float bb = b1[kk*256 + col];
            #pragma unroll
            for (int mt = 0; mt < 2; mt++)
                #pragma unroll
                for (int r = 0; r < 4; r++) {
                    float z = fmaxf(acc1[mt][r] + bb, 0.f);
                    U.f.Z[kk & 1][mt*16 + quad*4 + r][col] =
                        (short)__bfloat16_as_ushort(__float2bfloat16(z));
                }
        }
        __syncthreads();

        // prefetch W1[kk+1] fragments (covered by FF2)
        {
            int nk = (kk < 3) ? kk + 1 : 3;
            const short* wp = W1s + (size_t)(nk * 16 + wave) * 8 * 512 + lane * 8;
            #pragma unroll
            for (int i = 0; i < 8; i++)
                w1f[i] = *(const bf16x8*)(wp + i * 512);
        }

        // FF2 partial
        #pragma unroll
        for (int i = 0; i < 8; i++) {
            bf16x8 zf0 = *(const bf16x8*)&U.f.Z[kk & 1][lr][i*32 + hi*8];
            bf16x8 zf1 = *(const bf16x8*)&U.f.Z[kk & 1][16 + lr][i*32 + hi*8];
            acc2[0] = __builtin_amdgcn_mfma_f32_16x16x32_bf16(zf0, w2f[i], acc2[0], 0,0,0);
            acc2[1] = __builtin_amdgcn_mfma_f32_16x16x32_bf16(zf1, w2f[i], acc2[1], 0,0,0);
        }
        // Z[kk&1] overwritten only at kk+2, after the kk+1 barrier.
    }

    // ======== phase 5: h = H_lds + FF2 + b2 ========
    {
        int col = wave*16 + cc;
        float bb = b2[col];
        #pragma unroll
        for (int mt = 0; mt < 2; mt++)
            #pragma unroll
            for (int r = 0; r < 4; r++) {
                int rowl = mt*16 + quad*4 + r;
                int row = b * SEQ + i0 + rowl;
                h[(size_t)row * HDIM + col] = H_lds[rowl][col] + acc2[mt][r] + bb;
            }
    }
}

// ---------------------------------------------------------------------------
extern "C" void kernel_launch(void* const* d_in, const int* in_sizes, int n_in,
                              void* d_out, int out_size, void* d_ws, size_t ws_size,
                              hipStream_t stream)
{
    const float* x     = (const float*)d_in[0];
    const float* w_in  = (const float*)d_in[1];
    const float* w_out = (const float*)d_in[2];
    const float* b_out = (const float*)d_in[3];
    const float* qkv_w = (const float*)d_in[4];
    const float* qkv_b = (const float*)d_in[5];
    const float* out_w = (const float*)d_in[6];
    const float* out_b = (const float*)d_in[7];
    const float* ln1_g = (const float*)d_in[8];
    const float* ln1_b = (const float*)d_in[9];
    const float* ln2_g = (const float*)d_in[10];
    const float* ln2_b = (const float*)d_in[11];
    const float* ff1_w = (const float*)d_in[12];
    const float* ff1_b = (const float*)d_in[13];
    const float* ff2_w = (const float*)d_in[14];
    const float* ff2_b = (const float*)d_in[15];
    const float* lnf_g = (const float*)d_in[16];
    const float* lnf_b = (const float*)d_in[17];

    char* ws = (char*)d_ws;
    float*          h    = (float*)ws;                        // [0, 8M)
    __hip_bfloat16* qkvd = (__hip_bfloat16*)(ws + 8388608);   // [8M, ~21M)
    __hip_bfloat16* wb   = (__hip_bfloat16*)(ws + 25165824);  // weights bf16 (~5 MB)

    __hip_bfloat16* w_in_b  = wb;
    __hip_bfloat16* w_out_b = wb + 65536;
    __hip_bfloat16* qkv_w_b = wb + 131072;
    __hip_bfloat16* out_w_b = wb + 720896;
    __hip_bfloat16* ff1_w_b = wb + 917504;
    __hip_bfloat16* ff2_w_b = wb + 1703936;

    dim3 blk(256);

    cvt_all<<<1216, blk, 0, stream>>>(w_in, w_out, qkv_w, out_w, ff1_w, ff2_w, wb);

    // h = 16 * (x @ w_in^T) + PE
    embed_pe<<<dim3(4, 128), blk, 0, stream>>>(x, w_in_b, h);

    for (int l = 0; l < 3; l++) {
        // qkv = LN1(h) @ qkv_w^T + qkv_b; NT=192 -> 512 blocks = 2/CU, balanced
        gemm_ln<5, 192><<<dim3(4, 128), blk, 0, stream>>>(
            h, ln1_g + l*HDIM, ln1_b + l*HDIM,
            qkv_w_b + (size_t)l*768*HDIM, qkv_b + l*768, qkvd, nullptr, 768, HDIM);
        // attention + proj + residual + LN2 + FFN + residual (single kernel)
        attn_ffn<<<dim3(SEQ/32, BATCH), dim3(1024), 0, stream>>>(
            qkvd, out_w_b + (size_t)l*HDIM*HDIM, out_b + l*HDIM, h,
            ln2_g + l*HDIM, ln2_b + l*HDIM,
            ff1_w_b + (size_t)l*FFN_DIM*HDIM, ff1_b + l*FFN_DIM,
            ff2_w_b + (size_t)l*HDIM*FFN_DIM, ff2_b + l*HDIM);
    }

    // out = LNf(h) @ w_out^T + b_out   (fp32)
    gemm_ln<4, 64><<<dim3(4, 128), blk, 0, stream>>>(
        h, lnf_g, lnf_b, w_out_b, b_out, nullptr, (float*)d_out, HDIM, HDIM);
}

// Round 10
// 252.532 us; speedup vs baseline: 1.0257x; 1.0168x over previous
//
#include <hip/hip_runtime.h>
#include <hip/hip_bf16.h>
#include <math.h>

#define SEQ 2048
#define BATCH 4
#define HDIM 256
#define NHEAD 4
#define FFN_DIM 1024
#define MTOT (BATCH*SEQ)   // 8192

typedef __attribute__((ext_vector_type(8))) short bf16x8;
typedef __attribute__((ext_vector_type(4))) float f32x4;

__device__ __forceinline__ bf16x8 cvt8(const float* p)
{
    float4 a = *(const float4*)p;
    float4 b = *(const float4*)(p + 4);
    union { bf16x8 v; __hip_bfloat16 e[8]; } u;
    u.e[0] = __float2bfloat16(a.x); u.e[1] = __float2bfloat16(a.y);
    u.e[2] = __float2bfloat16(a.z); u.e[3] = __float2bfloat16(a.w);
    u.e[4] = __float2bfloat16(b.x); u.e[5] = __float2bfloat16(b.y);
    u.e[6] = __float2bfloat16(b.z); u.e[7] = __float2bfloat16(b.w);
    return u.v;
}

// ---------------------------------------------------------------------------
// Weights f32 -> bf16, re-laid out in MFMA-FRAGMENT TILES:
//   W[N][K] -> tiles [N/16][K/32][lane=0..63][8], where
//   lane = ((k>>3)&3)*16 + (row&15), elem = k&7.
// A fragment load is then ONE coalesced 1KB read: base + tile*512 + lane*8.
// ---------------------------------------------------------------------------
__global__ __launch_bounds__(256)
void cvt_all(const float* __restrict__ w_in, const float* __restrict__ w_out,
             const float* __restrict__ qkv_w, const float* __restrict__ out_w,
             const float* __restrict__ ff1_w, const float* __restrict__ ff2_w,
             __hip_bfloat16* __restrict__ wb)
{
    int i = blockIdx.x * 256 + threadIdx.x;   // grid 1216 -> exact (311296 thr)
    size_t e = (size_t)i * 8;

    const float* srcbase; size_t rbase; int kshift;  // K = 1<<kshift
    if (e < 720896) {
        if (e < 65536)       { srcbase = w_in;  rbase = 0;      kshift = 8; }
        else if (e < 131072) { srcbase = w_out; rbase = 65536;  kshift = 8; }
        else                 { srcbase = qkv_w; rbase = 131072; kshift = 8; }
    } else if (e < 917504)   { srcbase = out_w; rbase = 720896; kshift = 8; }
    else if (e < 1703936)    { srcbase = ff1_w; rbase = 917504; kshift = 8; }
    else                     { srcbase = ff2_w; rbase = 1703936; kshift = 10; }

    size_t local = e - rbase;
    int K = 1 << kshift;
    int row = (int)(local >> kshift);
    int k   = (int)(local & (K - 1));          // multiple of 8

    size_t dst = rbase
               + ((size_t)(row >> 4) * (K >> 5) + (k >> 5)) * 512
               + (size_t)((((k >> 3) & 3) << 4) | (row & 15)) * 8;

    *(bf16x8*)(wb + dst) = cvt8(srcbase + local);
}

// fragment-tile load helper: W swizzled with inner-dim K, n0 16-aligned
__device__ __forceinline__ bf16x8 fragW(const short* W, int n0, int k0, int K, int lane)
{
    return *(const bf16x8*)(W + ((size_t)(n0 >> 4) * (K >> 5) + (k0 >> 5)) * 512 + lane * 8);
}

// ---------------------------------------------------------------------------
// Embed: h = 16 * (x @ w_in^T) + PE.
// ---------------------------------------------------------------------------
__global__ __launch_bounds__(256)
void embed_pe(const float* __restrict__ X, const __hip_bfloat16* __restrict__ W,
              float* __restrict__ hbuf)
{
    int tid = threadIdx.x, wave = tid >> 6, lane = tid & 63;
    int wm = wave >> 1, wn = wave & 1;
    int rowBase = blockIdx.y * 64 + wm * 32;
    int colBase = blockIdx.x * 64 + wn * 32;
    int lr = lane & 15, hi = lane >> 4;

    const float* px0 = X + (size_t)(rowBase + lr) * HDIM + hi * 8;
    const float* px1 = px0 + (size_t)16 * HDIM;
    const short* Wb  = (const short*)W;

    f32x4 acc[2][2];
    acc[0][0] = (f32x4){0.f,0.f,0.f,0.f}; acc[0][1] = (f32x4){0.f,0.f,0.f,0.f};
    acc[1][0] = (f32x4){0.f,0.f,0.f,0.f}; acc[1][1] = (f32x4){0.f,0.f,0.f,0.f};

    #pragma unroll
    for (int k0 = 0; k0 < 256; k0 += 32) {
        bf16x8 a0 = cvt8(px0 + k0);
        bf16x8 a1 = cvt8(px1 + k0);
        bf16x8 b0 = fragW(Wb, colBase,      k0, 256, lane);
        bf16x8 b1 = fragW(Wb, colBase + 16, k0, 256, lane);
        acc[0][0] = __builtin_amdgcn_mfma_f32_16x16x32_bf16(a0, b0, acc[0][0], 0,0,0);
        acc[0][1] = __builtin_amdgcn_mfma_f32_16x16x32_bf16(a0, b1, acc[0][1], 0,0,0);
        acc[1][0] = __builtin_amdgcn_mfma_f32_16x16x32_bf16(a1, b0, acc[1][0], 0,0,0);
        acc[1][1] = __builtin_amdgcn_mfma_f32_16x16x32_bf16(a1, b1, acc[1][1], 0,0,0);
    }

    int cc = lane & 15, quad = lane >> 4;
    #pragma unroll
    for (int mt = 0; mt < 2; mt++)
        #pragma unroll
        for (int nt = 0; nt < 2; nt++) {
            int col = colBase + nt*16 + cc;
            int i2 = col & ~1;
            float freq = __expf((float)i2 * (-9.210340371976184f / 256.0f));
            #pragma unroll
            for (int r = 0; r < 4; r++) {
                int row = rowBase + mt*16 + quad*4 + r;
                float arg = (float)(row & (SEQ-1)) * freq;
                float pe = (col & 1) ? __cosf(arg) : __sinf(arg);
                hbuf[(size_t)row*HDIM + col] = 16.0f*acc[mt][nt][r] + pe;
            }
        }
}

// ---------------------------------------------------------------------------
// LN-fused GEMM, 64-row tile. Weights in fragment-tile layout.
// MODE 4: of32 = C + bias
// MODE 5: head-split dense qkv write; Q/K sections fragment-tiled, V dense.
// ---------------------------------------------------------------------------
template<int MODE, int NT>
__global__ __launch_bounds__(256)
void gemm_ln(const float* __restrict__ h,
             const float* __restrict__ g, const float* __restrict__ bln,
             const __hip_bfloat16* __restrict__ W,
             const float* __restrict__ bias,
             __hip_bfloat16* __restrict__ obf, float* __restrict__ of32,
             int N, int ldw)
{
    constexpr int NTW = NT / 32;
    __shared__ __align__(16) short A_lds[64][264];

    int tid = threadIdx.x, wave = tid >> 6, lane = tid & 63;
    int wm = wave >> 1, wn = wave & 1;
    int rowBase = blockIdx.y * 64;
    int colBase = blockIdx.x * NT + wn * (NT / 2);

    {
        float4 gv = *(const float4*)(g + lane * 4);
        float4 bv = *(const float4*)(bln + lane * 4);
        #pragma unroll
        for (int rr = 0; rr < 16; rr += 4) {
            float4 xv[4];
            #pragma unroll
            for (int u = 0; u < 4; u++)
                xv[u] = *(const float4*)(h + (size_t)(rowBase + wave*16 + rr + u)*HDIM + lane*4);
            #pragma unroll
            for (int u = 0; u < 4; u++) {
                float s = xv[u].x + xv[u].y + xv[u].z + xv[u].w;
                #pragma unroll
                for (int off = 32; off >= 1; off >>= 1) s += __shfl_xor(s, off);
                float mu = s * (1.0f/256.0f);
                float d0 = xv[u].x-mu, d1 = xv[u].y-mu, d2 = xv[u].z-mu, d3 = xv[u].w-mu;
                float v = d0*d0 + d1*d1 + d2*d2 + d3*d3;
                #pragma unroll
                for (int off = 32; off >= 1; off >>= 1) v += __shfl_xor(v, off);
                float rstd = rsqrtf(v * (1.0f/256.0f) + 1e-5f);
                union { short e[4]; uint2 w2; } o;
                o.e[0] = (short)__bfloat16_as_ushort(__float2bfloat16(d0*rstd*gv.x + bv.x));
                o.e[1] = (short)__bfloat16_as_ushort(__float2bfloat16(d1*rstd*gv.y + bv.y));
                o.e[2] = (short)__bfloat16_as_ushort(__float2bfloat16(d2*rstd*gv.z + bv.z));
                o.e[3] = (short)__bfloat16_as_ushort(__float2bfloat16(d3*rstd*gv.w + bv.w));
                *(uint2*)&A_lds[wave*16 + rr + u][lane*4] = o.w2;
            }
        }
    }
    __syncthreads();

    int lr = lane & 15, hi = lane >> 4;
    f32x4 acc[2][NTW];
    #pragma unroll
    for (int mt = 0; mt < 2; mt++)
        #pragma unroll
        for (int nt = 0; nt < NTW; nt++)
            acc[mt][nt] = (f32x4){0.f,0.f,0.f,0.f};

    const short* Ws = (const short*)W;
    #pragma unroll
    for (int k0 = 0; k0 < 256; k0 += 32) {
        bf16x8 af[2], bfr[NTW];
        #pragma unroll
        for (int mt = 0; mt < 2; mt++)
            af[mt] = *(const bf16x8*)&A_lds[wm*32 + mt*16 + lr][k0 + hi*8];
        #pragma unroll
        for (int nt = 0; nt < NTW; nt++)
            bfr[nt] = fragW(Ws, colBase + nt*16, k0, 256, lane);
        #pragma unroll
        for (int mt = 0; mt < 2; mt++)
            #pragma unroll
            for (int nt = 0; nt < NTW; nt++)
                acc[mt][nt] = __builtin_amdgcn_mfma_f32_16x16x32_bf16(af[mt], bfr[nt], acc[mt][nt], 0,0,0);
    }

    int cc = lane & 15, quad = lane >> 4;
    #pragma unroll
    for (int mt = 0; mt < 2; mt++)
        #pragma unroll
        for (int nt = 0; nt < NTW; nt++) {
            int col = colBase + nt*16 + cc;
            float bv = bias[col];
            #pragma unroll
            for (int r = 0; r < 4; r++) {
                int row = rowBase + wm*32 + mt*16 + quad*4 + r;
                float c = acc[mt][nt][r] + bv;
                if (MODE == 4) { of32[(size_t)row*N + col] = c; }
                else { // MODE 5
                    int sec = col >> 8, hd = (col >> 6) & 3, d = col & 63;
                    int srow = row & (SEQ - 1);
                    size_t base = (size_t)sec * 2097152
                                + (size_t)(((row >> 11) << 2) | hd) * 131072;
                    size_t idx;
                    if (sec < 2)   // Q/K: tiles [s/16][d/32]
                        idx = base + (size_t)(srow >> 4) * 1024 + (size_t)(d >> 5) * 512
                            + (size_t)((((d >> 3) & 3) << 4) | (srow & 15)) * 8 + (d & 7);
                    else           // V: dense row-major [s][64]
                        idx = base + (size_t)srow * 64 + d;
                    obf[idx] = __float2bfloat16(c);
                }
            }
        }
}

// ---------------------------------------------------------------------------
// FULLY FUSED layer tail, 1024 threads / 16 waves (round-6 form: V staged
// through LDS Vt with swizzled scatter; Q/K/weights fragment-tiled).
// ---------------------------------------------------------------------------
struct AttnLDS {
    __align__(16) __hip_bfloat16 Vt[64][128];
    __align__(16) __hip_bfloat16 Pl[32][96];
    float sm[2][32], ss[2][32];
};

__global__ __launch_bounds__(1024)
void attn_ffn(const __hip_bfloat16* __restrict__ qkvd,
              const __hip_bfloat16* __restrict__ ow,   // fragment-tiled [256][256]
              const float* __restrict__ ob,
              float* __restrict__ h,
              const float* __restrict__ g, const float* __restrict__ bln,
              const __hip_bfloat16* __restrict__ W1, const float* __restrict__ b1,
              const __hip_bfloat16* __restrict__ W2, const float* __restrict__ b2)
{
    __shared__ union SMem {
        AttnLDS asl[4];                                   // 92160 B (attention)
        struct {
            __align__(16) short A[32][264];               // LN2 out (bf16)
            __align__(16) short Z[2][32][264];            // FFN hidden, dbuf
        } f;                                              // 50688 B (FFN)
    } U;
    __shared__ __align__(16) short att_lds[32][264];
    __shared__ __align__(16) float H_lds[32][260];

    int tid  = threadIdx.x;
    int wave = tid >> 6, lane = tid & 63;
    int grp  = wave >> 2, w4 = wave & 3, ltid = tid & 255;
    int b    = blockIdx.y, i0 = blockIdx.x * 32;
    int klo  = i0 - 32;

    int lr = lane & 15, hi = lane >> 4;
    int cc = lane & 15, quad = lane >> 4;

    int hd = grp;
    AttnLDS& S = U.asl[grp];
    const short* Qd = (const short*)qkvd + (size_t)(b * 4 + hd) * 131072;
    const short* Kd = Qd + 2097152;
    const short* Vd = Qd + 4194304;
    int qh = w4 & 1, seg = w4 >> 1;
    int qoff = qh * 16 + quad * 4;

    // ======== ENTRY PREFETCH ========
    // V rows (issued FIRST -> waited first; later loads stay in flight)
    int vm = ltid & 7, vrl = ltid >> 3, vdp = vm * 8;
    bf16x8 vr[3];
    #pragma unroll
    for (int rr = 0; rr < 3; rr++) {
        int j = klo + rr * 32 + vrl;
        j = j < 0 ? 0 : (j > SEQ - 1 ? SEQ - 1 : j);
        vr[rr] = *(const bf16x8*)(Vd + (size_t)j * 64 + vdp);
    }
    // Q fragments (coalesced tile loads)
    bf16x8 qf[2];
    #pragma unroll
    for (int ds = 0; ds < 2; ds++)
        qf[ds] = *(const bf16x8*)(Qd + (size_t)((i0 >> 4) + qh) * 1024 + ds * 512 + lane * 8);
    // K fragments (coalesced tile loads; tiles fully valid or fully masked)
    bf16x8 kf[3][2];
    #pragma unroll
    for (int t = 0; t < 3; t++) {
        int jt = (klo + seg * 48 + t * 16) >> 4;
        jt = jt < 0 ? 0 : (jt > 127 ? 127 : jt);
        kf[t][0] = *(const bf16x8*)(Kd + (size_t)jt * 1024 + lane * 8);
        kf[t][1] = *(const bf16x8*)(Kd + (size_t)jt * 1024 + 512 + lane * 8);
    }
    float hold[2][4];
    {
        const float* hp = h + (size_t)(b * SEQ + i0) * HDIM + wave * 16 + cc;
        #pragma unroll
        for (int mt = 0; mt < 2; mt++)
            #pragma unroll
            for (int r = 0; r < 4; r++)
                hold[mt][r] = hp[(size_t)(mt*16 + quad*4 + r) * HDIM];
    }

    // ======== phase 1: attention ========
    { // scatter V^T (waits only on vr; Q/K/h_old remain outstanding)
        union { bf16x8 v; short e[8]; } u;
        #pragma unroll
        for (int rr = 0; rr < 3; rr++) {
            int row = rr * 32 + vrl;
            int colp = row ^ (vm << 3);
            u.v = vr[rr];
            #pragma unroll
            for (int jj = 0; jj < 8; jj++)
                *(short*)&S.Vt[vdp + jj][colp] = u.e[jj];
        }
    }

    f32x4 sacc[3];
    #pragma unroll
    for (int t = 0; t < 3; t++) {
        f32x4 a = (f32x4){0.f,0.f,0.f,0.f};
        a = __builtin_amdgcn_mfma_f32_16x16x32_bf16(qf[0], kf[t][0], a, 0,0,0);
        a = __builtin_amdgcn_mfma_f32_16x16x32_bf16(qf[1], kf[t][1], a, 0,0,0);
        sacc[t] = a;
    }

    float s[3][4];
    #pragma unroll
    for (int t = 0; t < 3; t++) {
        int koff = seg * 48 + t * 16 + cc;
        int jj = klo + koff;
        #pragma unroll
        for (int r = 0; r < 4; r++) {
            int rel = koff - (qoff + r);
            bool ok = (jj >= 0) && (jj < SEQ) && (rel >= 0) && (rel <= 64);
            s[t][r] = ok ? sacc[t][r] * 0.125f : -1e30f;
        }
    }

    float mrow[4], srow[4];
    #pragma unroll
    for (int r = 0; r < 4; r++)
        mrow[r] = fmaxf(fmaxf(s[0][r], s[1][r]), s[2][r]);
    #pragma unroll
    for (int off = 8; off >= 1; off >>= 1)
        #pragma unroll
        for (int r = 0; r < 4; r++)
            mrow[r] = fmaxf(mrow[r], __shfl_xor(mrow[r], off));
    #pragma unroll
    for (int r = 0; r < 4; r++)
        srow[r] = __expf(s[0][r]-mrow[r]) + __expf(s[1][r]-mrow[r]) + __expf(s[2][r]-mrow[r]);
    #pragma unroll
    for (int off = 8; off >= 1; off >>= 1)
        #pragma unroll
        for (int r = 0; r < 4; r++)
            srow[r] += __shfl_xor(srow[r], off);
    if (cc == 0) {
        #pragma unroll
        for (int r = 0; r < 4; r++) { S.sm[seg][qoff+r] = mrow[r]; S.ss[seg][qoff+r] = srow[r]; }
    }
    __syncthreads();

    float Mr[4], inv[4];
    #pragma unroll
    for (int r = 0; r < 4; r++) {
        float m0 = S.sm[0][qoff+r], m1 = S.sm[1][qoff+r];
        float M = fmaxf(m0, m1);
        float dn = S.ss[0][qoff+r] * __expf(m0 - M) + S.ss[1][qoff+r] * __expf(m1 - M);
        Mr[r] = M; inv[r] = 1.0f / dn;
    }
    #pragma unroll
    for (int t = 0; t < 3; t++)
        #pragma unroll
        for (int r = 0; r < 4; r++)
            S.Pl[qoff+r][seg*48 + t*16 + cc] = __float2bfloat16(__expf(s[t][r]-Mr[r]) * inv[r]);
    __syncthreads();

    // prefetch proj weight fragments (coalesced; hidden under PV)
    bf16x8 owf[8];
    {
        const short* op = (const short*)ow + (size_t)wave * 8 * 512 + lane * 8;
        #pragma unroll
        for (int i = 0; i < 8; i++)
            owf[i] = *(const bf16x8*)(op + i * 512);
    }

    // O = P @ V -> att_lds
    {
        f32x4 oacc[2];
        oacc[0] = (f32x4){0.f,0.f,0.f,0.f}; oacc[1] = (f32x4){0.f,0.f,0.f,0.f};
        #pragma unroll
        for (int ks = 0; ks < 3; ks++) {
            int kk = ks * 32;
            bf16x8 pf = *(const bf16x8*)&S.Pl[qh*16 + lr][kk + hi*8];
            #pragma unroll
            for (int dt = 0; dt < 2; dt++) {
                int d = seg*32 + dt*16 + lr;
                int colb = (kk + hi*8) ^ (((d >> 3) & 7) << 3);
                bf16x8 vf = *(const bf16x8*)&S.Vt[d][colb];
                oacc[dt] = __builtin_amdgcn_mfma_f32_16x16x32_bf16(pf, vf, oacc[dt], 0,0,0);
            }
        }
        #pragma unroll
        for (int dt = 0; dt < 2; dt++) {
            int col = hd*64 + seg*32 + dt*16 + cc;
            #pragma unroll
            for (int r = 0; r < 4; r++)
                att_lds[qoff + r][col] =
                    (short)__bfloat16_as_ushort(__float2bfloat16(oacc[dt][r]));
        }
    }
    __syncthreads();

    // ======== phase 2: proj + residual -> H_lds (wave owns 16 cols) ========
    {
        f32x4 acc[2];
        acc[0] = (f32x4){0.f,0.f,0.f,0.f}; acc[1] = (f32x4){0.f,0.f,0.f,0.f};
        #pragma unroll
        for (int i = 0; i < 8; i++) {
            bf16x8 a0 = *(const bf16x8*)&att_lds[lr][i*32 + hi*8];
            bf16x8 a1 = *(const bf16x8*)&att_lds[16 + lr][i*32 + hi*8];
            acc[0] = __builtin_amdgcn_mfma_f32_16x16x32_bf16(a0, owf[i], acc[0], 0,0,0);
            acc[1] = __builtin_amdgcn_mfma_f32_16x16x32_bf16(a1, owf[i], acc[1], 0,0,0);
        }
        float bv = ob[wave*16 + cc];
        #pragma unroll
        for (int mt = 0; mt < 2; mt++)
            #pragma unroll
            for (int r = 0; r < 4; r++)
                H_lds[mt*16 + quad*4 + r][wave*16 + cc] = hold[mt][r] + acc[mt][r] + bv;
    }

    // prologue: prefetch W1 chunk 0 (coalesced; hidden under barrier + LN2)
    const short* W1s = (const short*)W1;
    const short* W2s = (const short*)W2;
    bf16x8 w1f[8];
    {
        const short* wp = W1s + (size_t)wave * 8 * 512 + lane * 8;
        #pragma unroll
        for (int i = 0; i < 8; i++)
            w1f[i] = *(const bf16x8*)(wp + i * 512);
    }
    __syncthreads();

    // ======== phase 3: LN2(H_lds) -> A bf16 (each wave: 2 rows) ========
    {
        float4 gv = *(const float4*)(g + lane * 4);
        float4 bv = *(const float4*)(bln + lane * 4);
        #pragma unroll
        for (int u = 0; u < 2; u++) {
            float4 xv = *(const float4*)&H_lds[wave*2 + u][lane*4];
            float ss2 = xv.x + xv.y + xv.z + xv.w;
            #pragma unroll
            for (int off = 32; off >= 1; off >>= 1) ss2 += __shfl_xor(ss2, off);
            float mu = ss2 * (1.0f/256.0f);
            float d0 = xv.x-mu, d1 = xv.y-mu, d2 = xv.z-mu, d3 = xv.w-mu;
            float v = d0*d0 + d1*d1 + d2*d2 + d3*d3;
            #pragma unroll
            for (int off = 32; off >= 1; off >>= 1) v += __shfl_xor(v, off);
            float rstd = rsqrtf(v * (1.0f/256.0f) + 1e-5f);
            union { short e[4]; uint2 w2; } o;
            o.e[0] = (short)__bfloat16_as_ushort(__float2bfloat16(d0*rstd*gv.x + bv.x));
            o.e[1] = (short)__bfloat16_as_ushort(__float2bfloat16(d1*rstd*gv.y + bv.y));
            o.e[2] = (short)__bfloat16_as_ushort(__float2bfloat16(d2*rstd*gv.z + bv.z));
            o.e[3] = (short)__bfloat16_as_ushort(__float2bfloat16(d3*rstd*gv.w + bv.w));
            *(uint2*)&U.f.A[wave*2 + u][lane*4] = o.w2;
        }
    }
    __syncthreads();

    // ======== phase 4: FFN, Z dbuf, weights software-pipelined ========
    f32x4 acc2[2];
    acc2[0] = (f32x4){0.f,0.f,0.f,0.f}; acc2[1] = (f32x4){0.f,0.f,0.f,0.f};

    #pragma unroll 1
    for (int kk = 0; kk < 4; kk++) {
        // prefetch W2[kk] fragments (coalesced)
        bf16x8 w2f[8];
        {
            const short* wp = W2s + (size_t)(wave * 32 + kk * 8) * 512 + lane * 8;
            #pragma unroll
            for (int i = 0; i < 8; i++)
                w2f[i] = *(const bf16x8*)(wp + i * 512);
        }

        // FF1 chunk
        f32x4 acc1[2];
        acc1[0] = (f32x4){0.f,0.f,0.f,0.f}; acc1[1] = (f32x4){0.f,0.f,0.f,0.f};
        #pragma unroll
        for (int i = 0; i < 8; i++) {
            bf16x8 af0 = *(const bf16x8*)&U.f.A[lr][i*32 + hi*8];
            bf16x8 af1 = *(const bf16x8*)&U.f.A[16 + lr][i*32 + hi*8];
            acc1[0] = __builtin_amdgcn_mfma_f32_16x16x32_bf16(af0, w1f[i], acc1[0], 0,0,0);
            acc1[1] = __builtin_amdgcn_mfma_f32_16x16x32_bf16(af1, w1f[i], acc1[1], 0,0,0);
        }

        // relu + bias -> Z[kk&1]
        {
            int col = wave*16 + cc;
            float bb = b1[kk*256 + col];
            #pragma unroll
            for (int mt = 0; mt < 2; mt++)
                #pragma unroll
                for (int r = 0; r < 4; r++) {
                    float z = fmaxf(acc1[mt][r] + bb, 0.f);
                    U.f.Z[kk & 1][mt*16 + quad*4 + r][col] =
                        (short)__bfloat16_as_ushort(__float2bfloat16(z));
                }
        }
        __syncthreads();

        // prefetch W1[kk+1] fragments (covered by FF2)
        {
            int nk = (kk < 3) ? kk + 1 : 3;
            const short* wp = W1s + (size_t)(nk * 16 + wave) * 8 * 512 + lane * 8;
            #pragma unroll
            for (int i = 0; i < 8; i++)
                w1f[i] = *(const bf16x8*)(wp + i * 512);
        }

        // FF2 partial
        #pragma unroll
        for (int i = 0; i < 8; i++) {
            bf16x8 zf0 = *(const bf16x8*)&U.f.Z[kk & 1][lr][i*32 + hi*8];
            bf16x8 zf1 = *(const bf16x8*)&U.f.Z[kk & 1][16 + lr][i*32 + hi*8];
            acc2[0] = __builtin_amdgcn_mfma_f32_16x16x32_bf16(zf0, w2f[i], acc2[0], 0,0,0);
            acc2[1] = __builtin_amdgcn_mfma_f32_16x16x32_bf16(zf1, w2f[i], acc2[1], 0,0,0);
        }
        // Z[kk&1] overwritten only at kk+2, after the kk+1 barrier.
    }

    // ======== phase 5: h = H_lds + FF2 + b2 ========
    {
        int col = wave*16 + cc;
        float bb = b2[col];
        #pragma unroll
        for (int mt = 0; mt < 2; mt++)
            #pragma unroll
            for (int r = 0; r < 4; r++) {
                int rowl = mt*16 + quad*4 + r;
                int row = b * SEQ + i0 + rowl;
                h[(size_t)row * HDIM + col] = H_lds[rowl][col] + acc2[mt][r] + bb;
            }
    }
}

// ---------------------------------------------------------------------------
extern "C" void kernel_launch(void* const* d_in, const int* in_sizes, int n_in,
                              void* d_out, int out_size, void* d_ws, size_t ws_size,
                              hipStream_t stream)
{
    const float* x     = (const float*)d_in[0];
    const float* w_in  = (const float*)d_in[1];
    const float* w_out = (const float*)d_in[2];
    const float* b_out = (const float*)d_in[3];
    const float* qkv_w = (const float*)d_in[4];
    const float* qkv_b = (const float*)d_in[5];
    const float* out_w = (const float*)d_in[6];
    const float* out_b = (const float*)d_in[7];
    const float* ln1_g = (const float*)d_in[8];
    const float* ln1_b = (const float*)d_in[9];
    const float* ln2_g = (const float*)d_in[10];
    const float* ln2_b = (const float*)d_in[11];
    const float* ff1_w = (const float*)d_in[12];
    const float* ff1_b = (const float*)d_in[13];
    const float* ff2_w = (const float*)d_in[14];
    const float* ff2_b = (const float*)d_in[15];
    const float* lnf_g = (const float*)d_in[16];
    const float* lnf_b = (const float*)d_in[17];

    char* ws = (char*)d_ws;
    float*          h    = (float*)ws;                        // [0, 8M)
    __hip_bfloat16* qkvd = (__hip_bfloat16*)(ws + 8388608);   // [8M, ~21M)
    __hip_bfloat16* wb   = (__hip_bfloat16*)(ws + 25165824);  // weights bf16 (~5 MB)

    __hip_bfloat16* w_in_b  = wb;
    __hip_bfloat16* w_out_b = wb + 65536;
    __hip_bfloat16* qkv_w_b = wb + 131072;
    __hip_bfloat16* out_w_b = wb + 720896;
    __hip_bfloat16* ff1_w_b = wb + 917504;
    __hip_bfloat16* ff2_w_b = wb + 1703936;

    dim3 blk(256);

    cvt_all<<<1216, blk, 0, stream>>>(w_in, w_out, qkv_w, out_w, ff1_w, ff2_w, wb);

    // h = 16 * (x @ w_in^T) + PE
    embed_pe<<<dim3(4, 128), blk, 0, stream>>>(x, w_in_b, h);

    for (int l = 0; l < 3; l++) {
        // qkv = LN1(h) @ qkv_w^T + qkv_b; NT=96 -> 1024 blocks = 4/CU, balanced
        gemm_ln<5, 96><<<dim3(8, 128), blk, 0, stream>>>(
            h, ln1_g + l*HDIM, ln1_b + l*HDIM,
            qkv_w_b + (size_t)l*768*HDIM, qkv_b + l*768, qkvd, nullptr, 768, HDIM);
        // attention + proj + residual + LN2 + FFN + residual (single kernel)
        attn_ffn<<<dim3(SEQ/32, BATCH), dim3(1024), 0, stream>>>(
            qkvd, out_w_b + (size_t)l*HDIM*HDIM, out_b + l*HDIM, h,
            ln2_g + l*HDIM, ln2_b + l*HDIM,
            ff1_w_b + (size_t)l*FFN_DIM*HDIM, ff1_b + l*FFN_DIM,
            ff2_w_b + (size_t)l*HDIM*FFN_DIM, ff2_b + l*HDIM);
    }

    // out = LNf(h) @ w_out^T + b_out   (fp32)
    gemm_ln<4, 64><<<dim3(4, 128), blk, 0, stream>>>(
        h, lnf_g, lnf_b, w_out_b, b_out, nullptr, (float*)d_out, HDIM, HDIM);
}

// Round 11
// 244.300 us; speedup vs baseline: 1.0603x; 1.0337x over previous
//
#include <hip/hip_runtime.h>
#include <hip/hip_bf16.h>
#include <math.h>

#define SEQ 2048
#define BATCH 4
#define HDIM 256
#define NHEAD 4
#define FFN_DIM 1024
#define MTOT (BATCH*SEQ)   // 8192

typedef __attribute__((ext_vector_type(8))) short bf16x8;
typedef __attribute__((ext_vector_type(4))) float f32x4;

__device__ __forceinline__ bf16x8 cvt8(const float* p)
{
    float4 a = *(const float4*)p;
    float4 b = *(const float4*)(p + 4);
    union { bf16x8 v; __hip_bfloat16 e[8]; } u;
    u.e[0] = __float2bfloat16(a.x); u.e[1] = __float2bfloat16(a.y);
    u.e[2] = __float2bfloat16(a.z); u.e[3] = __float2bfloat16(a.w);
    u.e[4] = __float2bfloat16(b.x); u.e[5] = __float2bfloat16(b.y);
    u.e[6] = __float2bfloat16(b.z); u.e[7] = __float2bfloat16(b.w);
    return u.v;
}

// ---------------------------------------------------------------------------
// Weights f32 -> bf16, re-laid out in MFMA-FRAGMENT TILES:
//   W[N][K] -> tiles [N/16][K/32][lane=0..63][8], where
//   lane = ((k>>3)&3)*16 + (row&15), elem = k&7.
// A fragment load is then ONE coalesced 1KB read: base + tile*512 + lane*8.
// ---------------------------------------------------------------------------
__global__ __launch_bounds__(256)
void cvt_all(const float* __restrict__ w_in, const float* __restrict__ w_out,
             const float* __restrict__ qkv_w, const float* __restrict__ out_w,
             const float* __restrict__ ff1_w, const float* __restrict__ ff2_w,
             __hip_bfloat16* __restrict__ wb)
{
    int i = blockIdx.x * 256 + threadIdx.x;   // grid 1216 -> exact (311296 thr)
    size_t e = (size_t)i * 8;

    const float* srcbase; size_t rbase; int kshift;  // K = 1<<kshift
    if (e < 720896) {
        if (e < 65536)       { srcbase = w_in;  rbase = 0;      kshift = 8; }
        else if (e < 131072) { srcbase = w_out; rbase = 65536;  kshift = 8; }
        else                 { srcbase = qkv_w; rbase = 131072; kshift = 8; }
    } else if (e < 917504)   { srcbase = out_w; rbase = 720896; kshift = 8; }
    else if (e < 1703936)    { srcbase = ff1_w; rbase = 917504; kshift = 8; }
    else                     { srcbase = ff2_w; rbase = 1703936; kshift = 10; }

    size_t local = e - rbase;
    int K = 1 << kshift;
    int row = (int)(local >> kshift);
    int k   = (int)(local & (K - 1));          // multiple of 8

    size_t dst = rbase
               + ((size_t)(row >> 4) * (K >> 5) + (k >> 5)) * 512
               + (size_t)((((k >> 3) & 3) << 4) | (row & 15)) * 8;

    *(bf16x8*)(wb + dst) = cvt8(srcbase + local);
}

// fragment-tile load helper: W swizzled with inner-dim K, n0 16-aligned
__device__ __forceinline__ bf16x8 fragW(const short* W, int n0, int k0, int K, int lane)
{
    return *(const bf16x8*)(W + ((size_t)(n0 >> 4) * (K >> 5) + (k0 >> 5)) * 512 + lane * 8);
}

// ---------------------------------------------------------------------------
// Embed: h = 16 * (x @ w_in^T) + PE.
// ---------------------------------------------------------------------------
__global__ __launch_bounds__(256)
void embed_pe(const float* __restrict__ X, const __hip_bfloat16* __restrict__ W,
              float* __restrict__ hbuf)
{
    int tid = threadIdx.x, wave = tid >> 6, lane = tid & 63;
    int wm = wave >> 1, wn = wave & 1;
    int rowBase = blockIdx.y * 64 + wm * 32;
    int colBase = blockIdx.x * 64 + wn * 32;
    int lr = lane & 15, hi = lane >> 4;

    const float* px0 = X + (size_t)(rowBase + lr) * HDIM + hi * 8;
    const float* px1 = px0 + (size_t)16 * HDIM;
    const short* Wb  = (const short*)W;

    f32x4 acc[2][2];
    acc[0][0] = (f32x4){0.f,0.f,0.f,0.f}; acc[0][1] = (f32x4){0.f,0.f,0.f,0.f};
    acc[1][0] = (f32x4){0.f,0.f,0.f,0.f}; acc[1][1] = (f32x4){0.f,0.f,0.f,0.f};

    #pragma unroll
    for (int k0 = 0; k0 < 256; k0 += 32) {
        bf16x8 a0 = cvt8(px0 + k0);
        bf16x8 a1 = cvt8(px1 + k0);
        bf16x8 b0 = fragW(Wb, colBase,      k0, 256, lane);
        bf16x8 b1 = fragW(Wb, colBase + 16, k0, 256, lane);
        acc[0][0] = __builtin_amdgcn_mfma_f32_16x16x32_bf16(a0, b0, acc[0][0], 0,0,0);
        acc[0][1] = __builtin_amdgcn_mfma_f32_16x16x32_bf16(a0, b1, acc[0][1], 0,0,0);
        acc[1][0] = __builtin_amdgcn_mfma_f32_16x16x32_bf16(a1, b0, acc[1][0], 0,0,0);
        acc[1][1] = __builtin_amdgcn_mfma_f32_16x16x32_bf16(a1, b1, acc[1][1], 0,0,0);
    }

    int cc = lane & 15, quad = lane >> 4;
    #pragma unroll
    for (int mt = 0; mt < 2; mt++)
        #pragma unroll
        for (int nt = 0; nt < 2; nt++) {
            int col = colBase + nt*16 + cc;
            int i2 = col & ~1;
            float freq = __expf((float)i2 * (-9.210340371976184f / 256.0f));
            #pragma unroll
            for (int r = 0; r < 4; r++) {
                int row = rowBase + mt*16 + quad*4 + r;
                float arg = (float)(row & (SEQ-1)) * freq;
                float pe = (col & 1) ? __cosf(arg) : __sinf(arg);
                hbuf[(size_t)row*HDIM + col] = 16.0f*acc[mt][nt][r] + pe;
            }
        }
}

// ---------------------------------------------------------------------------
// LN-fused GEMM, 64-row tile. Weights in fragment-tile layout.
// MODE 4: of32 = C + bias
// MODE 5: head-split dense qkv write; Q/K sections fragment-tiled, V dense.
// ---------------------------------------------------------------------------
template<int MODE, int NT>
__global__ __launch_bounds__(256)
void gemm_ln(const float* __restrict__ h,
             const float* __restrict__ g, const float* __restrict__ bln,
             const __hip_bfloat16* __restrict__ W,
             const float* __restrict__ bias,
             __hip_bfloat16* __restrict__ obf, float* __restrict__ of32,
             int N, int ldw)
{
    constexpr int NTW = NT / 32;
    __shared__ __align__(16) short A_lds[64][264];

    int tid = threadIdx.x, wave = tid >> 6, lane = tid & 63;
    int wm = wave >> 1, wn = wave & 1;
    int rowBase = blockIdx.y * 64;
    int colBase = blockIdx.x * NT + wn * (NT / 2);

    {
        float4 gv = *(const float4*)(g + lane * 4);
        float4 bv = *(const float4*)(bln + lane * 4);
        #pragma unroll
        for (int rr = 0; rr < 16; rr += 4) {
            float4 xv[4];
            #pragma unroll
            for (int u = 0; u < 4; u++)
                xv[u] = *(const float4*)(h + (size_t)(rowBase + wave*16 + rr + u)*HDIM + lane*4);
            #pragma unroll
            for (int u = 0; u < 4; u++) {
                float s = xv[u].x + xv[u].y + xv[u].z + xv[u].w;
                #pragma unroll
                for (int off = 32; off >= 1; off >>= 1) s += __shfl_xor(s, off);
                float mu = s * (1.0f/256.0f);
                float d0 = xv[u].x-mu, d1 = xv[u].y-mu, d2 = xv[u].z-mu, d3 = xv[u].w-mu;
                float v = d0*d0 + d1*d1 + d2*d2 + d3*d3;
                #pragma unroll
                for (int off = 32; off >= 1; off >>= 1) v += __shfl_xor(v, off);
                float rstd = rsqrtf(v * (1.0f/256.0f) + 1e-5f);
                union { short e[4]; uint2 w2; } o;
                o.e[0] = (short)__bfloat16_as_ushort(__float2bfloat16(d0*rstd*gv.x + bv.x));
                o.e[1] = (short)__bfloat16_as_ushort(__float2bfloat16(d1*rstd*gv.y + bv.y));
                o.e[2] = (short)__bfloat16_as_ushort(__float2bfloat16(d2*rstd*gv.z + bv.z));
                o.e[3] = (short)__bfloat16_as_ushort(__float2bfloat16(d3*rstd*gv.w + bv.w));
                *(uint2*)&A_lds[wave*16 + rr + u][lane*4] = o.w2;
            }
        }
    }
    __syncthreads();

    int lr = lane & 15, hi = lane >> 4;
    f32x4 acc[2][NTW];
    #pragma unroll
    for (int mt = 0; mt < 2; mt++)
        #pragma unroll
        for (int nt = 0; nt < NTW; nt++)
            acc[mt][nt] = (f32x4){0.f,0.f,0.f,0.f};

    const short* Ws = (const short*)W;
    #pragma unroll
    for (int k0 = 0; k0 < 256; k0 += 32) {
        bf16x8 af[2], bfr[NTW];
        #pragma unroll
        for (int mt = 0; mt < 2; mt++)
            af[mt] = *(const bf16x8*)&A_lds[wm*32 + mt*16 + lr][k0 + hi*8];
        #pragma unroll
        for (int nt = 0; nt < NTW; nt++)
            bfr[nt] = fragW(Ws, colBase + nt*16, k0, 256, lane);
        #pragma unroll
        for (int mt = 0; mt < 2; mt++)
            #pragma unroll
            for (int nt = 0; nt < NTW; nt++)
                acc[mt][nt] = __builtin_amdgcn_mfma_f32_16x16x32_bf16(af[mt], bfr[nt], acc[mt][nt], 0,0,0);
    }

    int cc = lane & 15, quad = lane >> 4;
    #pragma unroll
    for (int mt = 0; mt < 2; mt++)
        #pragma unroll
        for (int nt = 0; nt < NTW; nt++) {
            int col = colBase + nt*16 + cc;
            float bv = bias[col];
            #pragma unroll
            for (int r = 0; r < 4; r++) {
                int row = rowBase + wm*32 + mt*16 + quad*4 + r;
                float c = acc[mt][nt][r] + bv;
                if (MODE == 4) { of32[(size_t)row*N + col] = c; }
                else { // MODE 5
                    int sec = col >> 8, hd = (col >> 6) & 3, d = col & 63;
                    int srow = row & (SEQ - 1);
                    size_t base = (size_t)sec * 2097152
                                + (size_t)(((row >> 11) << 2) | hd) * 131072;
                    size_t idx;
                    if (sec < 2)   // Q/K: tiles [s/16][d/32]
                        idx = base + (size_t)(srow >> 4) * 1024 + (size_t)(d >> 5) * 512
                            + (size_t)((((d >> 3) & 3) << 4) | (srow & 15)) * 8 + (d & 7);
                    else           // V: dense row-major [s][64]
                        idx = base + (size_t)srow * 64 + d;
                    obf[idx] = __float2bfloat16(c);
                }
            }
        }
}

// ---------------------------------------------------------------------------
// FULLY FUSED layer tail, 1024 threads / 16 waves (round-6 form: V staged
// through LDS Vt with swizzled scatter; Q/K/weights fragment-tiled).
// Pl stride 104 (was 96): PV ds_read_b128 bank conflict 8-way -> 2-way.
// ---------------------------------------------------------------------------
struct AttnLDS {
    __align__(16) __hip_bfloat16 Vt[64][128];
    __align__(16) __hip_bfloat16 Pl[32][104];
    float sm[2][32], ss[2][32];
};

__global__ __launch_bounds__(1024)
void attn_ffn(const __hip_bfloat16* __restrict__ qkvd,
              const __hip_bfloat16* __restrict__ ow,   // fragment-tiled [256][256]
              const float* __restrict__ ob,
              float* __restrict__ h,
              const float* __restrict__ g, const float* __restrict__ bln,
              const __hip_bfloat16* __restrict__ W1, const float* __restrict__ b1,
              const __hip_bfloat16* __restrict__ W2, const float* __restrict__ b2)
{
    __shared__ union SMem {
        AttnLDS asl[4];                                   // ~94 KB (attention)
        struct {
            __align__(16) short A[32][264];               // LN2 out (bf16)
            __align__(16) short Z[2][32][264];            // FFN hidden, dbuf
        } f;                                              // 50688 B (FFN)
    } U;
    __shared__ __align__(16) short att_lds[32][264];
    __shared__ __align__(16) float H_lds[32][260];

    int tid  = threadIdx.x;
    int wave = tid >> 6, lane = tid & 63;
    int grp  = wave >> 2, w4 = wave & 3, ltid = tid & 255;
    int b    = blockIdx.y, i0 = blockIdx.x * 32;
    int klo  = i0 - 32;

    int lr = lane & 15, hi = lane >> 4;
    int cc = lane & 15, quad = lane >> 4;

    int hd = grp;
    AttnLDS& S = U.asl[grp];
    const short* Qd = (const short*)qkvd + (size_t)(b * 4 + hd) * 131072;
    const short* Kd = Qd + 2097152;
    const short* Vd = Qd + 4194304;
    int qh = w4 & 1, seg = w4 >> 1;
    int qoff = qh * 16 + quad * 4;

    // ======== ENTRY PREFETCH ========
    // V rows (issued FIRST -> waited first; later loads stay in flight)
    int vm = ltid & 7, vrl = ltid >> 3, vdp = vm * 8;
    bf16x8 vr[3];
    #pragma unroll
    for (int rr = 0; rr < 3; rr++) {
        int j = klo + rr * 32 + vrl;
        j = j < 0 ? 0 : (j > SEQ - 1 ? SEQ - 1 : j);
        vr[rr] = *(const bf16x8*)(Vd + (size_t)j * 64 + vdp);
    }
    // Q fragments (coalesced tile loads)
    bf16x8 qf[2];
    #pragma unroll
    for (int ds = 0; ds < 2; ds++)
        qf[ds] = *(const bf16x8*)(Qd + (size_t)((i0 >> 4) + qh) * 1024 + ds * 512 + lane * 8);
    // K fragments (coalesced tile loads; tiles fully valid or fully masked)
    bf16x8 kf[3][2];
    #pragma unroll
    for (int t = 0; t < 3; t++) {
        int jt = (klo + seg * 48 + t * 16) >> 4;
        jt = jt < 0 ? 0 : (jt > 127 ? 127 : jt);
        kf[t][0] = *(const bf16x8*)(Kd + (size_t)jt * 1024 + lane * 8);
        kf[t][1] = *(const bf16x8*)(Kd + (size_t)jt * 1024 + 512 + lane * 8);
    }
    float hold[2][4];
    {
        const float* hp = h + (size_t)(b * SEQ + i0) * HDIM + wave * 16 + cc;
        #pragma unroll
        for (int mt = 0; mt < 2; mt++)
            #pragma unroll
            for (int r = 0; r < 4; r++)
                hold[mt][r] = hp[(size_t)(mt*16 + quad*4 + r) * HDIM];
    }

    // ======== phase 1: attention ========
    { // scatter V^T (waits only on vr; Q/K/h_old remain outstanding)
        union { bf16x8 v; short e[8]; } u;
        #pragma unroll
        for (int rr = 0; rr < 3; rr++) {
            int row = rr * 32 + vrl;
            int colp = row ^ (vm << 3);
            u.v = vr[rr];
            #pragma unroll
            for (int jj = 0; jj < 8; jj++)
                *(short*)&S.Vt[vdp + jj][colp] = u.e[jj];
        }
    }

    f32x4 sacc[3];
    #pragma unroll
    for (int t = 0; t < 3; t++) {
        f32x4 a = (f32x4){0.f,0.f,0.f,0.f};
        a = __builtin_amdgcn_mfma_f32_16x16x32_bf16(qf[0], kf[t][0], a, 0,0,0);
        a = __builtin_amdgcn_mfma_f32_16x16x32_bf16(qf[1], kf[t][1], a, 0,0,0);
        sacc[t] = a;
    }

    float s[3][4];
    #pragma unroll
    for (int t = 0; t < 3; t++) {
        int koff = seg * 48 + t * 16 + cc;
        int jj = klo + koff;
        #pragma unroll
        for (int r = 0; r < 4; r++) {
            int rel = koff - (qoff + r);
            bool ok = (jj >= 0) && (jj < SEQ) && (rel >= 0) && (rel <= 64);
            s[t][r] = ok ? sacc[t][r] * 0.125f : -1e30f;
        }
    }

    float mrow[4], srow[4];
    #pragma unroll
    for (int r = 0; r < 4; r++)
        mrow[r] = fmaxf(fmaxf(s[0][r], s[1][r]), s[2][r]);
    #pragma unroll
    for (int off = 8; off >= 1; off >>= 1)
        #pragma unroll
        for (int r = 0; r < 4; r++)
            mrow[r] = fmaxf(mrow[r], __shfl_xor(mrow[r], off));
    #pragma unroll
    for (int r = 0; r < 4; r++)
        srow[r] = __expf(s[0][r]-mrow[r]) + __expf(s[1][r]-mrow[r]) + __expf(s[2][r]-mrow[r]);
    #pragma unroll
    for (int off = 8; off >= 1; off >>= 1)
        #pragma unroll
        for (int r = 0; r < 4; r++)
            srow[r] += __shfl_xor(srow[r], off);
    if (cc == 0) {
        #pragma unroll
        for (int r = 0; r < 4; r++) { S.sm[seg][qoff+r] = mrow[r]; S.ss[seg][qoff+r] = srow[r]; }
    }
    __syncthreads();

    float Mr[4], inv[4];
    #pragma unroll
    for (int r = 0; r < 4; r++) {
        float m0 = S.sm[0][qoff+r], m1 = S.sm[1][qoff+r];
        float M = fmaxf(m0, m1);
        float dn = S.ss[0][qoff+r] * __expf(m0 - M) + S.ss[1][qoff+r] * __expf(m1 - M);
        Mr[r] = M; inv[r] = 1.0f / dn;
    }
    #pragma unroll
    for (int t = 0; t < 3; t++)
        #pragma unroll
        for (int r = 0; r < 4; r++)
            S.Pl[qoff+r][seg*48 + t*16 + cc] = __float2bfloat16(__expf(s[t][r]-Mr[r]) * inv[r]);
    __syncthreads();

    // prefetch proj weight fragments (coalesced; hidden under PV)
    bf16x8 owf[8];
    {
        const short* op = (const short*)ow + (size_t)wave * 8 * 512 + lane * 8;
        #pragma unroll
        for (int i = 0; i < 8; i++)
            owf[i] = *(const bf16x8*)(op + i * 512);
    }

    // O = P @ V -> att_lds
    {
        f32x4 oacc[2];
        oacc[0] = (f32x4){0.f,0.f,0.f,0.f}; oacc[1] = (f32x4){0.f,0.f,0.f,0.f};
        #pragma unroll
        for (int ks = 0; ks < 3; ks++) {
            int kk = ks * 32;
            bf16x8 pf = *(const bf16x8*)&S.Pl[qh*16 + lr][kk + hi*8];
            #pragma unroll
            for (int dt = 0; dt < 2; dt++) {
                int d = seg*32 + dt*16 + lr;
                int colb = (kk + hi*8) ^ (((d >> 3) & 7) << 3);
                bf16x8 vf = *(const bf16x8*)&S.Vt[d][colb];
                oacc[dt] = __builtin_amdgcn_mfma_f32_16x16x32_bf16(pf, vf, oacc[dt], 0,0,0);
            }
        }
        #pragma unroll
        for (int dt = 0; dt < 2; dt++) {
            int col = hd*64 + seg*32 + dt*16 + cc;
            #pragma unroll
            for (int r = 0; r < 4; r++)
                att_lds[qoff + r][col] =
                    (short)__bfloat16_as_ushort(__float2bfloat16(oacc[dt][r]));
        }
    }
    __syncthreads();

    // ======== phase 2: proj + residual -> H_lds (wave owns 16 cols) ========
    {
        f32x4 acc[2];
        acc[0] = (f32x4){0.f,0.f,0.f,0.f}; acc[1] = (f32x4){0.f,0.f,0.f,0.f};
        #pragma unroll
        for (int i = 0; i < 8; i++) {
            bf16x8 a0 = *(const bf16x8*)&att_lds[lr][i*32 + hi*8];
            bf16x8 a1 = *(const bf16x8*)&att_lds[16 + lr][i*32 + hi*8];
            acc[0] = __builtin_amdgcn_mfma_f32_16x16x32_bf16(a0, owf[i], acc[0], 0,0,0);
            acc[1] = __builtin_amdgcn_mfma_f32_16x16x32_bf16(a1, owf[i], acc[1], 0,0,0);
        }
        float bv = ob[wave*16 + cc];
        #pragma unroll
        for (int mt = 0; mt < 2; mt++)
            #pragma unroll
            for (int r = 0; r < 4; r++)
                H_lds[mt*16 + quad*4 + r][wave*16 + cc] = hold[mt][r] + acc[mt][r] + bv;
    }

    // prologue: prefetch W1 chunk 0 (coalesced; hidden under barrier + LN2)
    const short* W1s = (const short*)W1;
    const short* W2s = (const short*)W2;
    bf16x8 w1f[8];
    {
        const short* wp = W1s + (size_t)wave * 8 * 512 + lane * 8;
        #pragma unroll
        for (int i = 0; i < 8; i++)
            w1f[i] = *(const bf16x8*)(wp + i * 512);
    }
    __syncthreads();

    // ======== phase 3: LN2(H_lds) -> A bf16 (each wave: 2 rows) ========
    {
        float4 gv = *(const float4*)(g + lane * 4);
        float4 bv = *(const float4*)(bln + lane * 4);
        #pragma unroll
        for (int u = 0; u < 2; u++) {
            float4 xv = *(const float4*)&H_lds[wave*2 + u][lane*4];
            float ss2 = xv.x + xv.y + xv.z + xv.w;
            #pragma unroll
            for (int off = 32; off >= 1; off >>= 1) ss2 += __shfl_xor(ss2, off);
            float mu = ss2 * (1.0f/256.0f);
            float d0 = xv.x-mu, d1 = xv.y-mu, d2 = xv.z-mu, d3 = xv.w-mu;
            float v = d0*d0 + d1*d1 + d2*d2 + d3*d3;
            #pragma unroll
            for (int off = 32; off >= 1; off >>= 1) v += __shfl_xor(v, off);
            float rstd = rsqrtf(v * (1.0f/256.0f) + 1e-5f);
            union { short e[4]; uint2 w2; } o;
            o.e[0] = (short)__bfloat16_as_ushort(__float2bfloat16(d0*rstd*gv.x + bv.x));
            o.e[1] = (short)__bfloat16_as_ushort(__float2bfloat16(d1*rstd*gv.y + bv.y));
            o.e[2] = (short)__bfloat16_as_ushort(__float2bfloat16(d2*rstd*gv.z + bv.z));
            o.e[3] = (short)__bfloat16_as_ushort(__float2bfloat16(d3*rstd*gv.w + bv.w));
            *(uint2*)&U.f.A[wave*2 + u][lane*4] = o.w2;
        }
    }
    __syncthreads();

    // ======== phase 4: FFN, Z dbuf, weights software-pipelined ========
    f32x4 acc2[2];
    acc2[0] = (f32x4){0.f,0.f,0.f,0.f}; acc2[1] = (f32x4){0.f,0.f,0.f,0.f};

    #pragma unroll 1
    for (int kk = 0; kk < 4; kk++) {
        // prefetch W2[kk] fragments (coalesced)
        bf16x8 w2f[8];
        {
            const short* wp = W2s + (size_t)(wave * 32 + kk * 8) * 512 + lane * 8;
            #pragma unroll
            for (int i = 0; i < 8; i++)
                w2f[i] = *(const bf16x8*)(wp + i * 512);
        }

        // FF1 chunk
        f32x4 acc1[2];
        acc1[0] = (f32x4){0.f,0.f,0.f,0.f}; acc1[1] = (f32x4){0.f,0.f,0.f,0.f};
        #pragma unroll
        for (int i = 0; i < 8; i++) {
            bf16x8 af0 = *(const bf16x8*)&U.f.A[lr][i*32 + hi*8];
            bf16x8 af1 = *(const bf16x8*)&U.f.A[16 + lr][i*32 + hi*8];
            acc1[0] = __builtin_amdgcn_mfma_f32_16x16x32_bf16(af0, w1f[i], acc1[0], 0,0,0);
            acc1[1] = __builtin_amdgcn_mfma_f32_16x16x32_bf16(af1, w1f[i], acc1[1], 0,0,0);
        }

        // relu + bias -> Z[kk&1]
        {
            int col = wave*16 + cc;
            float bb = b1[kk*256 + col];
            #pragma unroll
            for (int mt = 0; mt < 2; mt++)
                #pragma unroll
                for (int r = 0; r < 4; r++) {
                    float z = fmaxf(acc1[mt][r] + bb, 0.f);
                    U.f.Z[kk & 1][mt*16 + quad*4 + r][col] =
                        (short)__bfloat16_as_ushort(__float2bfloat16(z));
                }
        }
        __syncthreads();

        // prefetch W1[kk+1] fragments (covered by FF2)
        {
            int nk = (kk < 3) ? kk + 1 : 3;
            const short* wp = W1s + (size_t)(nk * 16 + wave) * 8 * 512 + lane * 8;
            #pragma unroll
            for (int i = 0; i < 8; i++)
                w1f[i] = *(const bf16x8*)(wp + i * 512);
        }

        // FF2 partial
        #pragma unroll
        for (int i = 0; i < 8; i++) {
            bf16x8 zf0 = *(const bf16x8*)&U.f.Z[kk & 1][lr][i*32 + hi*8];
            bf16x8 zf1 = *(const bf16x8*)&U.f.Z[kk & 1][16 + lr][i*32 + hi*8];
            acc2[0] = __builtin_amdgcn_mfma_f32_16x16x32_bf16(zf0, w2f[i], acc2[0], 0,0,0);
            acc2[1] = __builtin_amdgcn_mfma_f32_16x16x32_bf16(zf1, w2f[i], acc2[1], 0,0,0);
        }
        // Z[kk&1] overwritten only at kk+2, after the kk+1 barrier.
    }

    // ======== phase 5: h = H_lds + FF2 + b2 ========
    {
        int col = wave*16 + cc;
        float bb = b2[col];
        #pragma unroll
        for (int mt = 0; mt < 2; mt++)
            #pragma unroll
            for (int r = 0; r < 4; r++) {
                int rowl = mt*16 + quad*4 + r;
                int row = b * SEQ + i0 + rowl;
                h[(size_t)row * HDIM + col] = H_lds[rowl][col] + acc2[mt][r] + bb;
            }
    }
}

// ---------------------------------------------------------------------------
extern "C" void kernel_launch(void* const* d_in, const int* in_sizes, int n_in,
                              void* d_out, int out_size, void* d_ws, size_t ws_size,
                              hipStream_t stream)
{
    const float* x     = (const float*)d_in[0];
    const float* w_in  = (const float*)d_in[1];
    const float* w_out = (const float*)d_in[2];
    const float* b_out = (const float*)d_in[3];
    const float* qkv_w = (const float*)d_in[4];
    const float* qkv_b = (const float*)d_in[5];
    const float* out_w = (const float*)d_in[6];
    const float* out_b = (const float*)d_in[7];
    const float* ln1_g = (const float*)d_in[8];
    const float* ln1_b = (const float*)d_in[9];
    const float* ln2_g = (const float*)d_in[10];
    const float* ln2_b = (const float*)d_in[11];
    const float* ff1_w = (const float*)d_in[12];
    const float* ff1_b = (const float*)d_in[13];
    const float* ff2_w = (const float*)d_in[14];
    const float* ff2_b = (const float*)d_in[15];
    const float* lnf_g = (const float*)d_in[16];
    const float* lnf_b = (const float*)d_in[17];

    char* ws = (char*)d_ws;
    float*          h    = (float*)ws;                        // [0, 8M)
    __hip_bfloat16* qkvd = (__hip_bfloat16*)(ws + 8388608);   // [8M, ~21M)
    __hip_bfloat16* wb   = (__hip_bfloat16*)(ws + 25165824);  // weights bf16 (~5 MB)

    __hip_bfloat16* w_in_b  = wb;
    __hip_bfloat16* w_out_b = wb + 65536;
    __hip_bfloat16* qkv_w_b = wb + 131072;
    __hip_bfloat16* out_w_b = wb + 720896;
    __hip_bfloat16* ff1_w_b = wb + 917504;
    __hip_bfloat16* ff2_w_b = wb + 1703936;

    dim3 blk(256);

    cvt_all<<<1216, blk, 0, stream>>>(w_in, w_out, qkv_w, out_w, ff1_w, ff2_w, wb);

    // h = 16 * (x @ w_in^T) + PE
    embed_pe<<<dim3(4, 128), blk, 0, stream>>>(x, w_in_b, h);

    for (int l = 0; l < 3; l++) {
        // qkv = LN1(h) @ qkv_w^T + qkv_b; NT=128 (measured optimum), 768 blocks = 3/CU
        gemm_ln<5, 128><<<dim3(6, 128), blk, 0, stream>>>(
            h, ln1_g + l*HDIM, ln1_b + l*HDIM,
            qkv_w_b + (size_t)l*768*HDIM, qkv_b + l*768, qkvd, nullptr, 768, HDIM);
        // attention + proj + residual + LN2 + FFN + residual (single kernel)
        attn_ffn<<<dim3(SEQ/32, BATCH), dim3(1024), 0, stream>>>(
            qkvd, out_w_b + (size_t)l*HDIM*HDIM, out_b + l*HDIM, h,
            ln2_g + l*HDIM, ln2_b + l*HDIM,
            ff1_w_b + (size_t)l*FFN_DIM*HDIM, ff1_b + l*FFN_DIM,
            ff2_w_b + (size_t)l*HDIM*FFN_DIM, ff2_b + l*HDIM);
    }

    // out = LNf(h) @ w_out^T + b_out   (fp32)
    gemm_ln<4, 64><<<dim3(4, 128), blk, 0, stream>>>(
        h, lnf_g, lnf_b, w_out_b, b_out, nullptr, (float*)d_out, HDIM, HDIM);
}

// Round 12
// 233.841 us; speedup vs baseline: 1.1077x; 1.0447x over previous
//
#include <hip/hip_runtime.h>
#include <hip/hip_bf16.h>
#include <math.h>

#define SEQ 2048
#define BATCH 4
#define HDIM 256
#define NHEAD 4
#define FFN_DIM 1024
#define MTOT (BATCH*SEQ)   // 8192

typedef __attribute__((ext_vector_type(8))) short bf16x8;
typedef __attribute__((ext_vector_type(4))) float f32x4;

__device__ __forceinline__ bf16x8 cvt8(const float* p)
{
    float4 a = *(const float4*)p;
    float4 b = *(const float4*)(p + 4);
    union { bf16x8 v; __hip_bfloat16 e[8]; } u;
    u.e[0] = __float2bfloat16(a.x); u.e[1] = __float2bfloat16(a.y);
    u.e[2] = __float2bfloat16(a.z); u.e[3] = __float2bfloat16(a.w);
    u.e[4] = __float2bfloat16(b.x); u.e[5] = __float2bfloat16(b.y);
    u.e[6] = __float2bfloat16(b.z); u.e[7] = __float2bfloat16(b.w);
    return u.v;
}

// ---------------------------------------------------------------------------
// Weights f32 -> bf16, re-laid out in MFMA-FRAGMENT TILES:
//   W[N][K] -> tiles [N/16][K/32][lane=0..63][8], where
//   lane = ((k>>3)&3)*16 + (row&15), elem = k&7.
// A fragment load is then ONE coalesced 1KB read: base + tile*512 + lane*8.
// ---------------------------------------------------------------------------
__global__ __launch_bounds__(256)
void cvt_all(const float* __restrict__ w_in, const float* __restrict__ w_out,
             const float* __restrict__ qkv_w, const float* __restrict__ out_w,
             const float* __restrict__ ff1_w, const float* __restrict__ ff2_w,
             __hip_bfloat16* __restrict__ wb)
{
    int i = blockIdx.x * 256 + threadIdx.x;   // grid 1216 -> exact (311296 thr)
    size_t e = (size_t)i * 8;

    const float* srcbase; size_t rbase; int kshift;  // K = 1<<kshift
    if (e < 720896) {
        if (e < 65536)       { srcbase = w_in;  rbase = 0;      kshift = 8; }
        else if (e < 131072) { srcbase = w_out; rbase = 65536;  kshift = 8; }
        else                 { srcbase = qkv_w; rbase = 131072; kshift = 8; }
    } else if (e < 917504)   { srcbase = out_w; rbase = 720896; kshift = 8; }
    else if (e < 1703936)    { srcbase = ff1_w; rbase = 917504; kshift = 8; }
    else                     { srcbase = ff2_w; rbase = 1703936; kshift = 10; }

    size_t local = e - rbase;
    int K = 1 << kshift;
    int row = (int)(local >> kshift);
    int k   = (int)(local & (K - 1));          // multiple of 8

    size_t dst = rbase
               + ((size_t)(row >> 4) * (K >> 5) + (k >> 5)) * 512
               + (size_t)((((k >> 3) & 3) << 4) | (row & 15)) * 8;

    *(bf16x8*)(wb + dst) = cvt8(srcbase + local);
}

// fragment-tile load helper: W swizzled with inner-dim K, n0 16-aligned
__device__ __forceinline__ bf16x8 fragW(const short* W, int n0, int k0, int K, int lane)
{
    return *(const bf16x8*)(W + ((size_t)(n0 >> 4) * (K >> 5) + (k0 >> 5)) * 512 + lane * 8);
}

// ---------------------------------------------------------------------------
// Embed: h = 16 * (x @ w_in^T) + PE.
// ---------------------------------------------------------------------------
__global__ __launch_bounds__(256)
void embed_pe(const float* __restrict__ X, const __hip_bfloat16* __restrict__ W,
              float* __restrict__ hbuf)
{
    int tid = threadIdx.x, wave = tid >> 6, lane = tid & 63;
    int wm = wave >> 1, wn = wave & 1;
    int rowBase = blockIdx.y * 64 + wm * 32;
    int colBase = blockIdx.x * 64 + wn * 32;
    int lr = lane & 15, hi = lane >> 4;

    const float* px0 = X + (size_t)(rowBase + lr) * HDIM + hi * 8;
    const float* px1 = px0 + (size_t)16 * HDIM;
    const short* Wb  = (const short*)W;

    f32x4 acc[2][2];
    acc[0][0] = (f32x4){0.f,0.f,0.f,0.f}; acc[0][1] = (f32x4){0.f,0.f,0.f,0.f};
    acc[1][0] = (f32x4){0.f,0.f,0.f,0.f}; acc[1][1] = (f32x4){0.f,0.f,0.f,0.f};

    #pragma unroll
    for (int k0 = 0; k0 < 256; k0 += 32) {
        bf16x8 a0 = cvt8(px0 + k0);
        bf16x8 a1 = cvt8(px1 + k0);
        bf16x8 b0 = fragW(Wb, colBase,      k0, 256, lane);
        bf16x8 b1 = fragW(Wb, colBase + 16, k0, 256, lane);
        acc[0][0] = __builtin_amdgcn_mfma_f32_16x16x32_bf16(a0, b0, acc[0][0], 0,0,0);
        acc[0][1] = __builtin_amdgcn_mfma_f32_16x16x32_bf16(a0, b1, acc[0][1], 0,0,0);
        acc[1][0] = __builtin_amdgcn_mfma_f32_16x16x32_bf16(a1, b0, acc[1][0], 0,0,0);
        acc[1][1] = __builtin_amdgcn_mfma_f32_16x16x32_bf16(a1, b1, acc[1][1], 0,0,0);
    }

    int cc = lane & 15, quad = lane >> 4;
    #pragma unroll
    for (int mt = 0; mt < 2; mt++)
        #pragma unroll
        for (int nt = 0; nt < 2; nt++) {
            int col = colBase + nt*16 + cc;
            int i2 = col & ~1;
            float freq = __expf((float)i2 * (-9.210340371976184f / 256.0f));
            #pragma unroll
            for (int r = 0; r < 4; r++) {
                int row = rowBase + mt*16 + quad*4 + r;
                float arg = (float)(row & (SEQ-1)) * freq;
                float pe = (col & 1) ? __cosf(arg) : __sinf(arg);
                hbuf[(size_t)row*HDIM + col] = 16.0f*acc[mt][nt][r] + pe;
            }
        }
}

// ---------------------------------------------------------------------------
// LN-fused GEMM, 64-row tile. Weights in fragment-tile layout.
// MODE 5: head-split dense qkv write; Q/K sections fragment-tiled, V dense.
// ---------------------------------------------------------------------------
template<int MODE, int NT>
__global__ __launch_bounds__(256)
void gemm_ln(const float* __restrict__ h,
             const float* __restrict__ g, const float* __restrict__ bln,
             const __hip_bfloat16* __restrict__ W,
             const float* __restrict__ bias,
             __hip_bfloat16* __restrict__ obf, float* __restrict__ of32,
             int N, int ldw)
{
    constexpr int NTW = NT / 32;
    __shared__ __align__(16) short A_lds[64][264];

    int tid = threadIdx.x, wave = tid >> 6, lane = tid & 63;
    int wm = wave >> 1, wn = wave & 1;
    int rowBase = blockIdx.y * 64;
    int colBase = blockIdx.x * NT + wn * (NT / 2);

    {
        float4 gv = *(const float4*)(g + lane * 4);
        float4 bv = *(const float4*)(bln + lane * 4);
        #pragma unroll
        for (int rr = 0; rr < 16; rr += 4) {
            float4 xv[4];
            #pragma unroll
            for (int u = 0; u < 4; u++)
                xv[u] = *(const float4*)(h + (size_t)(rowBase + wave*16 + rr + u)*HDIM + lane*4);
            #pragma unroll
            for (int u = 0; u < 4; u++) {
                float s = xv[u].x + xv[u].y + xv[u].z + xv[u].w;
                #pragma unroll
                for (int off = 32; off >= 1; off >>= 1) s += __shfl_xor(s, off);
                float mu = s * (1.0f/256.0f);
                float d0 = xv[u].x-mu, d1 = xv[u].y-mu, d2 = xv[u].z-mu, d3 = xv[u].w-mu;
                float v = d0*d0 + d1*d1 + d2*d2 + d3*d3;
                #pragma unroll
                for (int off = 32; off >= 1; off >>= 1) v += __shfl_xor(v, off);
                float rstd = rsqrtf(v * (1.0f/256.0f) + 1e-5f);
                union { short e[4]; uint2 w2; } o;
                o.e[0] = (short)__bfloat16_as_ushort(__float2bfloat16(d0*rstd*gv.x + bv.x));
                o.e[1] = (short)__bfloat16_as_ushort(__float2bfloat16(d1*rstd*gv.y + bv.y));
                o.e[2] = (short)__bfloat16_as_ushort(__float2bfloat16(d2*rstd*gv.z + bv.z));
                o.e[3] = (short)__bfloat16_as_ushort(__float2bfloat16(d3*rstd*gv.w + bv.w));
                *(uint2*)&A_lds[wave*16 + rr + u][lane*4] = o.w2;
            }
        }
    }
    __syncthreads();

    int lr = lane & 15, hi = lane >> 4;
    f32x4 acc[2][NTW];
    #pragma unroll
    for (int mt = 0; mt < 2; mt++)
        #pragma unroll
        for (int nt = 0; nt < NTW; nt++)
            acc[mt][nt] = (f32x4){0.f,0.f,0.f,0.f};

    const short* Ws = (const short*)W;
    #pragma unroll
    for (int k0 = 0; k0 < 256; k0 += 32) {
        bf16x8 af[2], bfr[NTW];
        #pragma unroll
        for (int mt = 0; mt < 2; mt++)
            af[mt] = *(const bf16x8*)&A_lds[wm*32 + mt*16 + lr][k0 + hi*8];
        #pragma unroll
        for (int nt = 0; nt < NTW; nt++)
            bfr[nt] = fragW(Ws, colBase + nt*16, k0, 256, lane);
        #pragma unroll
        for (int mt = 0; mt < 2; mt++)
            #pragma unroll
            for (int nt = 0; nt < NTW; nt++)
                acc[mt][nt] = __builtin_amdgcn_mfma_f32_16x16x32_bf16(af[mt], bfr[nt], acc[mt][nt], 0,0,0);
    }

    int cc = lane & 15, quad = lane >> 4;
    #pragma unroll
    for (int mt = 0; mt < 2; mt++)
        #pragma unroll
        for (int nt = 0; nt < NTW; nt++) {
            int col = colBase + nt*16 + cc;
            float bv = bias[col];
            #pragma unroll
            for (int r = 0; r < 4; r++) {
                int row = rowBase + wm*32 + mt*16 + quad*4 + r;
                float c = acc[mt][nt][r] + bv;
                if (MODE == 4) { of32[(size_t)row*N + col] = c; }
                else { // MODE 5
                    int sec = col >> 8, hd = (col >> 6) & 3, d = col & 63;
                    int srow = row & (SEQ - 1);
                    size_t base = (size_t)sec * 2097152
                                + (size_t)(((row >> 11) << 2) | hd) * 131072;
                    size_t idx;
                    if (sec < 2)   // Q/K: tiles [s/16][d/32]
                        idx = base + (size_t)(srow >> 4) * 1024 + (size_t)(d >> 5) * 512
                            + (size_t)((((d >> 3) & 3) << 4) | (srow & 15)) * 8 + (d & 7);
                    else           // V: dense row-major [s][64]
                        idx = base + (size_t)srow * 64 + d;
                    obf[idx] = __float2bfloat16(c);
                }
            }
        }
}

// ---------------------------------------------------------------------------
// FULLY FUSED layer tail, 1024 threads / 16 waves (round-6 form).
// LAST=1 additionally fuses the FINAL LNf + out-GEMM (row-local): no h write,
// no separate final kernel.
// ---------------------------------------------------------------------------
struct AttnLDS {
    __align__(16) __hip_bfloat16 Vt[64][128];
    __align__(16) __hip_bfloat16 Pl[32][96];
    float sm[2][32], ss[2][32];
};

template<int LAST>
__global__ __launch_bounds__(1024)
void attn_ffn(const __hip_bfloat16* __restrict__ qkvd,
              const __hip_bfloat16* __restrict__ ow,   // fragment-tiled [256][256]
              const float* __restrict__ ob,
              float* __restrict__ h,
              const float* __restrict__ g, const float* __restrict__ bln,
              const __hip_bfloat16* __restrict__ W1, const float* __restrict__ b1,
              const __hip_bfloat16* __restrict__ W2, const float* __restrict__ b2,
              const float* __restrict__ gf, const float* __restrict__ bf,
              const __hip_bfloat16* __restrict__ Wout, const float* __restrict__ bout,
              float* __restrict__ outp)
{
    __shared__ union SMem {
        AttnLDS asl[4];                                   // 92160 B (attention)
        struct {
            __align__(16) short A[32][264];               // LN out (bf16)
            __align__(16) short Z[2][32][264];            // FFN hidden, dbuf
        } f;                                              // 50688 B (FFN)
    } U;
    __shared__ __align__(16) short att_lds[32][264];
    __shared__ __align__(16) float H_lds[32][260];

    int tid  = threadIdx.x;
    int wave = tid >> 6, lane = tid & 63;
    int grp  = wave >> 2, w4 = wave & 3, ltid = tid & 255;
    int b    = blockIdx.y, i0 = blockIdx.x * 32;
    int klo  = i0 - 32;

    int lr = lane & 15, hi = lane >> 4;
    int cc = lane & 15, quad = lane >> 4;

    int hd = grp;
    AttnLDS& S = U.asl[grp];
    const short* Qd = (const short*)qkvd + (size_t)(b * 4 + hd) * 131072;
    const short* Kd = Qd + 2097152;
    const short* Vd = Qd + 4194304;
    int qh = w4 & 1, seg = w4 >> 1;
    int qoff = qh * 16 + quad * 4;

    // ======== ENTRY PREFETCH ========
    int vm = ltid & 7, vrl = ltid >> 3, vdp = vm * 8;
    bf16x8 vr[3];
    #pragma unroll
    for (int rr = 0; rr < 3; rr++) {
        int j = klo + rr * 32 + vrl;
        j = j < 0 ? 0 : (j > SEQ - 1 ? SEQ - 1 : j);
        vr[rr] = *(const bf16x8*)(Vd + (size_t)j * 64 + vdp);
    }
    bf16x8 qf[2];
    #pragma unroll
    for (int ds = 0; ds < 2; ds++)
        qf[ds] = *(const bf16x8*)(Qd + (size_t)((i0 >> 4) + qh) * 1024 + ds * 512 + lane * 8);
    bf16x8 kf[3][2];
    #pragma unroll
    for (int t = 0; t < 3; t++) {
        int jt = (klo + seg * 48 + t * 16) >> 4;
        jt = jt < 0 ? 0 : (jt > 127 ? 127 : jt);
        kf[t][0] = *(const bf16x8*)(Kd + (size_t)jt * 1024 + lane * 8);
        kf[t][1] = *(const bf16x8*)(Kd + (size_t)jt * 1024 + 512 + lane * 8);
    }
    float hold[2][4];
    {
        const float* hp = h + (size_t)(b * SEQ + i0) * HDIM + wave * 16 + cc;
        #pragma unroll
        for (int mt = 0; mt < 2; mt++)
            #pragma unroll
            for (int r = 0; r < 4; r++)
                hold[mt][r] = hp[(size_t)(mt*16 + quad*4 + r) * HDIM];
    }

    // ======== phase 1: attention ========
    { // scatter V^T
        union { bf16x8 v; short e[8]; } u;
        #pragma unroll
        for (int rr = 0; rr < 3; rr++) {
            int row = rr * 32 + vrl;
            int colp = row ^ (vm << 3);
            u.v = vr[rr];
            #pragma unroll
            for (int jj = 0; jj < 8; jj++)
                *(short*)&S.Vt[vdp + jj][colp] = u.e[jj];
        }
    }

    f32x4 sacc[3];
    #pragma unroll
    for (int t = 0; t < 3; t++) {
        f32x4 a = (f32x4){0.f,0.f,0.f,0.f};
        a = __builtin_amdgcn_mfma_f32_16x16x32_bf16(qf[0], kf[t][0], a, 0,0,0);
        a = __builtin_amdgcn_mfma_f32_16x16x32_bf16(qf[1], kf[t][1], a, 0,0,0);
        sacc[t] = a;
    }

    float s[3][4];
    #pragma unroll
    for (int t = 0; t < 3; t++) {
        int koff = seg * 48 + t * 16 + cc;
        int jj = klo + koff;
        #pragma unroll
        for (int r = 0; r < 4; r++) {
            int rel = koff - (qoff + r);
            bool ok = (jj >= 0) && (jj < SEQ) && (rel >= 0) && (rel <= 64);
            s[t][r] = ok ? sacc[t][r] * 0.125f : -1e30f;
        }
    }

    float mrow[4], srow[4];
    #pragma unroll
    for (int r = 0; r < 4; r++)
        mrow[r] = fmaxf(fmaxf(s[0][r], s[1][r]), s[2][r]);
    #pragma unroll
    for (int off = 8; off >= 1; off >>= 1)
        #pragma unroll
        for (int r = 0; r < 4; r++)
            mrow[r] = fmaxf(mrow[r], __shfl_xor(mrow[r], off));
    #pragma unroll
    for (int r = 0; r < 4; r++)
        srow[r] = __expf(s[0][r]-mrow[r]) + __expf(s[1][r]-mrow[r]) + __expf(s[2][r]-mrow[r]);
    #pragma unroll
    for (int off = 8; off >= 1; off >>= 1)
        #pragma unroll
        for (int r = 0; r < 4; r++)
            srow[r] += __shfl_xor(srow[r], off);
    if (cc == 0) {
        #pragma unroll
        for (int r = 0; r < 4; r++) { S.sm[seg][qoff+r] = mrow[r]; S.ss[seg][qoff+r] = srow[r]; }
    }
    __syncthreads();

    float Mr[4], inv[4];
    #pragma unroll
    for (int r = 0; r < 4; r++) {
        float m0 = S.sm[0][qoff+r], m1 = S.sm[1][qoff+r];
        float M = fmaxf(m0, m1);
        float dn = S.ss[0][qoff+r] * __expf(m0 - M) + S.ss[1][qoff+r] * __expf(m1 - M);
        Mr[r] = M; inv[r] = 1.0f / dn;
    }
    #pragma unroll
    for (int t = 0; t < 3; t++)
        #pragma unroll
        for (int r = 0; r < 4; r++)
            S.Pl[qoff+r][seg*48 + t*16 + cc] = __float2bfloat16(__expf(s[t][r]-Mr[r]) * inv[r]);
    __syncthreads();

    // prefetch proj weight fragments (coalesced; hidden under PV)
    bf16x8 owf[8];
    {
        const short* op = (const short*)ow + (size_t)wave * 8 * 512 + lane * 8;
        #pragma unroll
        for (int i = 0; i < 8; i++)
            owf[i] = *(const bf16x8*)(op + i * 512);
    }

    // O = P @ V -> att_lds
    {
        f32x4 oacc[2];
        oacc[0] = (f32x4){0.f,0.f,0.f,0.f}; oacc[1] = (f32x4){0.f,0.f,0.f,0.f};
        #pragma unroll
        for (int ks = 0; ks < 3; ks++) {
            int kk = ks * 32;
            bf16x8 pf = *(const bf16x8*)&S.Pl[qh*16 + lr][kk + hi*8];
            #pragma unroll
            for (int dt = 0; dt < 2; dt++) {
                int d = seg*32 + dt*16 + lr;
                int colb = (kk + hi*8) ^ (((d >> 3) & 7) << 3);
                bf16x8 vf = *(const bf16x8*)&S.Vt[d][colb];
                oacc[dt] = __builtin_amdgcn_mfma_f32_16x16x32_bf16(pf, vf, oacc[dt], 0,0,0);
            }
        }
        #pragma unroll
        for (int dt = 0; dt < 2; dt++) {
            int col = hd*64 + seg*32 + dt*16 + cc;
            #pragma unroll
            for (int r = 0; r < 4; r++)
                att_lds[qoff + r][col] =
                    (short)__bfloat16_as_ushort(__float2bfloat16(oacc[dt][r]));
        }
    }
    __syncthreads();

    // ======== phase 2: proj + residual -> H_lds (wave owns 16 cols) ========
    {
        f32x4 acc[2];
        acc[0] = (f32x4){0.f,0.f,0.f,0.f}; acc[1] = (f32x4){0.f,0.f,0.f,0.f};
        #pragma unroll
        for (int i = 0; i < 8; i++) {
            bf16x8 a0 = *(const bf16x8*)&att_lds[lr][i*32 + hi*8];
            bf16x8 a1 = *(const bf16x8*)&att_lds[16 + lr][i*32 + hi*8];
            acc[0] = __builtin_amdgcn_mfma_f32_16x16x32_bf16(a0, owf[i], acc[0], 0,0,0);
            acc[1] = __builtin_amdgcn_mfma_f32_16x16x32_bf16(a1, owf[i], acc[1], 0,0,0);
        }
        float bv = ob[wave*16 + cc];
        #pragma unroll
        for (int mt = 0; mt < 2; mt++)
            #pragma unroll
            for (int r = 0; r < 4; r++)
                H_lds[mt*16 + quad*4 + r][wave*16 + cc] = hold[mt][r] + acc[mt][r] + bv;
    }

    // prologue: prefetch W1 chunk 0 (coalesced; hidden under barrier + LN2)
    const short* W1s = (const short*)W1;
    const short* W2s = (const short*)W2;
    bf16x8 w1f[8];
    {
        const short* wp = W1s + (size_t)wave * 8 * 512 + lane * 8;
        #pragma unroll
        for (int i = 0; i < 8; i++)
            w1f[i] = *(const bf16x8*)(wp + i * 512);
    }
    __syncthreads();

    // ======== phase 3: LN2(H_lds) -> A bf16 (each wave: 2 rows) ========
    {
        float4 gv = *(const float4*)(g + lane * 4);
        float4 bv = *(const float4*)(bln + lane * 4);
        #pragma unroll
        for (int u = 0; u < 2; u++) {
            float4 xv = *(const float4*)&H_lds[wave*2 + u][lane*4];
            float ss2 = xv.x + xv.y + xv.z + xv.w;
            #pragma unroll
            for (int off = 32; off >= 1; off >>= 1) ss2 += __shfl_xor(ss2, off);
            float mu = ss2 * (1.0f/256.0f);
            float d0 = xv.x-mu, d1 = xv.y-mu, d2 = xv.z-mu, d3 = xv.w-mu;
            float v = d0*d0 + d1*d1 + d2*d2 + d3*d3;
            #pragma unroll
            for (int off = 32; off >= 1; off >>= 1) v += __shfl_xor(v, off);
            float rstd = rsqrtf(v * (1.0f/256.0f) + 1e-5f);
            union { short e[4]; uint2 w2; } o;
            o.e[0] = (short)__bfloat16_as_ushort(__float2bfloat16(d0*rstd*gv.x + bv.x));
            o.e[1] = (short)__bfloat16_as_ushort(__float2bfloat16(d1*rstd*gv.y + bv.y));
            o.e[2] = (short)__bfloat16_as_ushort(__float2bfloat16(d2*rstd*gv.z + bv.z));
            o.e[3] = (short)__bfloat16_as_ushort(__float2bfloat16(d3*rstd*gv.w + bv.w));
            *(uint2*)&U.f.A[wave*2 + u][lane*4] = o.w2;
        }
    }
    __syncthreads();

    // ======== phase 4: FFN, Z dbuf, weights software-pipelined ========
    f32x4 acc2[2];
    acc2[0] = (f32x4){0.f,0.f,0.f,0.f}; acc2[1] = (f32x4){0.f,0.f,0.f,0.f};

    #pragma unroll 1
    for (int kk = 0; kk < 4; kk++) {
        // prefetch W2[kk] fragments (coalesced)
        bf16x8 w2f[8];
        {
            const short* wp = W2s + (size_t)(wave * 32 + kk * 8) * 512 + lane * 8;
            #pragma unroll
            for (int i = 0; i < 8; i++)
                w2f[i] = *(const bf16x8*)(wp + i * 512);
        }

        // FF1 chunk
        f32x4 acc1[2];
        acc1[0] = (f32x4){0.f,0.f,0.f,0.f}; acc1[1] = (f32x4){0.f,0.f,0.f,0.f};
        #pragma unroll
        for (int i = 0; i < 8; i++) {
            bf16x8 af0 = *(const bf16x8*)&U.f.A[lr][i*32 + hi*8];
            bf16x8 af1 = *(const bf16x8*)&U.f.A[16 + lr][i*32 + hi*8];
            acc1[0] = __builtin_amdgcn_mfma_f32_16x16x32_bf16(af0, w1f[i], acc1[0], 0,0,0);
            acc1[1] = __builtin_amdgcn_mfma_f32_16x16x32_bf16(af1, w1f[i], acc1[1], 0,0,0);
        }

        // relu + bias -> Z[kk&1]
        {
            int col = wave*16 + cc;
            float bb = b1[kk*256 + col];
            #pragma unroll
            for (int mt = 0; mt < 2; mt++)
                #pragma unroll
                for (int r = 0; r < 4; r++) {
                    float z = fmaxf(acc1[mt][r] + bb, 0.f);
                    U.f.Z[kk & 1][mt*16 + quad*4 + r][col] =
                        (short)__bfloat16_as_ushort(__float2bfloat16(z));
                }
        }
        __syncthreads();

        // prefetch W1[kk+1] fragments (covered by FF2)
        {
            int nk = (kk < 3) ? kk + 1 : 3;
            const short* wp = W1s + (size_t)(nk * 16 + wave) * 8 * 512 + lane * 8;
            #pragma unroll
            for (int i = 0; i < 8; i++)
                w1f[i] = *(const bf16x8*)(wp + i * 512);
        }

        // FF2 partial
        #pragma unroll
        for (int i = 0; i < 8; i++) {
            bf16x8 zf0 = *(const bf16x8*)&U.f.Z[kk & 1][lr][i*32 + hi*8];
            bf16x8 zf1 = *(const bf16x8*)&U.f.Z[kk & 1][16 + lr][i*32 + hi*8];
            acc2[0] = __builtin_amdgcn_mfma_f32_16x16x32_bf16(zf0, w2f[i], acc2[0], 0,0,0);
            acc2[1] = __builtin_amdgcn_mfma_f32_16x16x32_bf16(zf1, w2f[i], acc2[1], 0,0,0);
        }
        // Z[kk&1] overwritten only at kk+2, after the kk+1 barrier.
    }

    if (!LAST) {
        // ======== phase 5: h = H_lds + FF2 + b2 ========
        int col = wave*16 + cc;
        float bb = b2[col];
        #pragma unroll
        for (int mt = 0; mt < 2; mt++)
            #pragma unroll
            for (int r = 0; r < 4; r++) {
                int rowl = mt*16 + quad*4 + r;
                int row = b * SEQ + i0 + rowl;
                h[(size_t)row * HDIM + col] = H_lds[rowl][col] + acc2[mt][r] + bb;
            }
    } else {
        // ======== phase 5': H_lds += FF2 + b2 (final h, LDS only) ========
        {
            int col = wave*16 + cc;
            float bb = b2[col];
            #pragma unroll
            for (int mt = 0; mt < 2; mt++)
                #pragma unroll
                for (int r = 0; r < 4; r++) {
                    int rowl = mt*16 + quad*4 + r;
                    H_lds[rowl][col] = H_lds[rowl][col] + acc2[mt][r] + bb;
                }
        }
        __syncthreads();

        // ======== phase 6: LNf(H_lds) -> A bf16 (each wave: 2 rows) ========
        {
            float4 gv = *(const float4*)(gf + lane * 4);
            float4 bv = *(const float4*)(bf + lane * 4);
            #pragma unroll
            for (int u = 0; u < 2; u++) {
                float4 xv = *(const float4*)&H_lds[wave*2 + u][lane*4];
                float ss2 = xv.x + xv.y + xv.z + xv.w;
                #pragma unroll
                for (int off = 32; off >= 1; off >>= 1) ss2 += __shfl_xor(ss2, off);
                float mu = ss2 * (1.0f/256.0f);
                float d0 = xv.x-mu, d1 = xv.y-mu, d2 = xv.z-mu, d3 = xv.w-mu;
                float v = d0*d0 + d1*d1 + d2*d2 + d3*d3;
                #pragma unroll
                for (int off = 32; off >= 1; off >>= 1) v += __shfl_xor(v, off);
                float rstd = rsqrtf(v * (1.0f/256.0f) + 1e-5f);
                union { short e[4]; uint2 w2; } o;
                o.e[0] = (short)__bfloat16_as_ushort(__float2bfloat16(d0*rstd*gv.x + bv.x));
                o.e[1] = (short)__bfloat16_as_ushort(__float2bfloat16(d1*rstd*gv.y + bv.y));
                o.e[2] = (short)__bfloat16_as_ushort(__float2bfloat16(d2*rstd*gv.z + bv.z));
                o.e[3] = (short)__bfloat16_as_ushort(__float2bfloat16(d3*rstd*gv.w + bv.w));
                *(uint2*)&U.f.A[wave*2 + u][lane*4] = o.w2;
            }
        }
        __syncthreads();

        // ======== phase 7: out = A @ w_out^T + b_out (wave owns 16 cols) ====
        {
            bf16x8 wf[8];
            const short* wp = (const short*)Wout + (size_t)wave * 8 * 512 + lane * 8;
            #pragma unroll
            for (int i = 0; i < 8; i++)
                wf[i] = *(const bf16x8*)(wp + i * 512);

            f32x4 oa[2];
            oa[0] = (f32x4){0.f,0.f,0.f,0.f}; oa[1] = (f32x4){0.f,0.f,0.f,0.f};
            #pragma unroll
            for (int i = 0; i < 8; i++) {
                bf16x8 a0 = *(const bf16x8*)&U.f.A[lr][i*32 + hi*8];
                bf16x8 a1 = *(const bf16x8*)&U.f.A[16 + lr][i*32 + hi*8];
                oa[0] = __builtin_amdgcn_mfma_f32_16x16x32_bf16(a0, wf[i], oa[0], 0,0,0);
                oa[1] = __builtin_amdgcn_mfma_f32_16x16x32_bf16(a1, wf[i], oa[1], 0,0,0);
            }
            int col = wave*16 + cc;
            float bb = bout[col];
            #pragma unroll
            for (int mt = 0; mt < 2; mt++)
                #pragma unroll
                for (int r = 0; r < 4; r++) {
                    int row = b * SEQ + i0 + mt*16 + quad*4 + r;
                    outp[(size_t)row * HDIM + col] = oa[mt][r] + bb;
                }
        }
    }
}

// ---------------------------------------------------------------------------
extern "C" void kernel_launch(void* const* d_in, const int* in_sizes, int n_in,
                              void* d_out, int out_size, void* d_ws, size_t ws_size,
                              hipStream_t stream)
{
    const float* x     = (const float*)d_in[0];
    const float* w_in  = (const float*)d_in[1];
    const float* w_out = (const float*)d_in[2];
    const float* b_out = (const float*)d_in[3];
    const float* qkv_w = (const float*)d_in[4];
    const float* qkv_b = (const float*)d_in[5];
    const float* out_w = (const float*)d_in[6];
    const float* out_b = (const float*)d_in[7];
    const float* ln1_g = (const float*)d_in[8];
    const float* ln1_b = (const float*)d_in[9];
    const float* ln2_g = (const float*)d_in[10];
    const float* ln2_b = (const float*)d_in[11];
    const float* ff1_w = (const float*)d_in[12];
    const float* ff1_b = (const float*)d_in[13];
    const float* ff2_w = (const float*)d_in[14];
    const float* ff2_b = (const float*)d_in[15];
    const float* lnf_g = (const float*)d_in[16];
    const float* lnf_b = (const float*)d_in[17];

    char* ws = (char*)d_ws;
    float*          h    = (float*)ws;                        // [0, 8M)
    __hip_bfloat16* qkvd = (__hip_bfloat16*)(ws + 8388608);   // [8M, ~21M)
    __hip_bfloat16* wb   = (__hip_bfloat16*)(ws + 25165824);  // weights bf16 (~5 MB)

    __hip_bfloat16* w_in_b  = wb;
    __hip_bfloat16* w_out_b = wb + 65536;
    __hip_bfloat16* qkv_w_b = wb + 131072;
    __hip_bfloat16* out_w_b = wb + 720896;
    __hip_bfloat16* ff1_w_b = wb + 917504;
    __hip_bfloat16* ff2_w_b = wb + 1703936;

    dim3 blk(256);

    cvt_all<<<1216, blk, 0, stream>>>(w_in, w_out, qkv_w, out_w, ff1_w, ff2_w, wb);

    // h = 16 * (x @ w_in^T) + PE
    embed_pe<<<dim3(4, 128), blk, 0, stream>>>(x, w_in_b, h);

    for (int l = 0; l < 3; l++) {
        // qkv = LN1(h) @ qkv_w^T + qkv_b; NT=128 (measured optimum), 768 blocks = 3/CU
        gemm_ln<5, 128><<<dim3(6, 128), blk, 0, stream>>>(
            h, ln1_g + l*HDIM, ln1_b + l*HDIM,
            qkv_w_b + (size_t)l*768*HDIM, qkv_b + l*768, qkvd, nullptr, 768, HDIM);
        // attention + proj + residual + LN2 + FFN + residual;
        // layer 2 additionally fuses LNf + out-GEMM (writes d_out directly)
        if (l < 2)
            attn_ffn<0><<<dim3(SEQ/32, BATCH), dim3(1024), 0, stream>>>(
                qkvd, out_w_b + (size_t)l*HDIM*HDIM, out_b + l*HDIM, h,
                ln2_g + l*HDIM, ln2_b + l*HDIM,
                ff1_w_b + (size_t)l*FFN_DIM*HDIM, ff1_b + l*FFN_DIM,
                ff2_w_b + (size_t)l*HDIM*FFN_DIM, ff2_b + l*HDIM,
                nullptr, nullptr, nullptr, nullptr, nullptr);
        else
            attn_ffn<1><<<dim3(SEQ/32, BATCH), dim3(1024), 0, stream>>>(
                qkvd, out_w_b + (size_t)l*HDIM*HDIM, out_b + l*HDIM, h,
                ln2_g + l*HDIM, ln2_b + l*HDIM,
                ff1_w_b + (size_t)l*FFN_DIM*HDIM, ff1_b + l*FFN_DIM,
                ff2_w_b + (size_t)l*HDIM*FFN_DIM, ff2_b + l*HDIM,
                lnf_g, lnf_b, w_out_b, b_out, (float*)d_out);
    }
}

// Round 13
// 224.139 us; speedup vs baseline: 1.1556x; 1.0433x over previous
//
#include <hip/hip_runtime.h>
#include <hip/hip_bf16.h>
#include <math.h>

#define SEQ 2048
#define BATCH 4
#define HDIM 256
#define NHEAD 4
#define FFN_DIM 1024
#define MTOT (BATCH*SEQ)   // 8192

typedef __attribute__((ext_vector_type(8))) short bf16x8;
typedef __attribute__((ext_vector_type(4))) float f32x4;

__device__ __forceinline__ bf16x8 cvt8(const float* p)
{
    float4 a = *(const float4*)p;
    float4 b = *(const float4*)(p + 4);
    union { bf16x8 v; __hip_bfloat16 e[8]; } u;
    u.e[0] = __float2bfloat16(a.x); u.e[1] = __float2bfloat16(a.y);
    u.e[2] = __float2bfloat16(a.z); u.e[3] = __float2bfloat16(a.w);
    u.e[4] = __float2bfloat16(b.x); u.e[5] = __float2bfloat16(b.y);
    u.e[6] = __float2bfloat16(b.z); u.e[7] = __float2bfloat16(b.w);
    return u.v;
}

// ---------------------------------------------------------------------------
// Weights f32 -> bf16, re-laid out in MFMA-FRAGMENT TILES:
//   W[N][K] -> tiles [N/16][K/32][lane=0..63][8], where
//   lane = ((k>>3)&3)*16 + (row&15), elem = k&7.
// ---------------------------------------------------------------------------
__global__ __launch_bounds__(256)
void cvt_all(const float* __restrict__ w_in, const float* __restrict__ w_out,
             const float* __restrict__ qkv_w, const float* __restrict__ out_w,
             const float* __restrict__ ff1_w, const float* __restrict__ ff2_w,
             __hip_bfloat16* __restrict__ wb)
{
    int i = blockIdx.x * 256 + threadIdx.x;   // grid 1216 -> exact (311296 thr)
    size_t e = (size_t)i * 8;

    const float* srcbase; size_t rbase; int kshift;  // K = 1<<kshift
    if (e < 720896) {
        if (e < 65536)       { srcbase = w_in;  rbase = 0;      kshift = 8; }
        else if (e < 131072) { srcbase = w_out; rbase = 65536;  kshift = 8; }
        else                 { srcbase = qkv_w; rbase = 131072; kshift = 8; }
    } else if (e < 917504)   { srcbase = out_w; rbase = 720896; kshift = 8; }
    else if (e < 1703936)    { srcbase = ff1_w; rbase = 917504; kshift = 8; }
    else                     { srcbase = ff2_w; rbase = 1703936; kshift = 10; }

    size_t local = e - rbase;
    int K = 1 << kshift;
    int row = (int)(local >> kshift);
    int k   = (int)(local & (K - 1));          // multiple of 8

    size_t dst = rbase
               + ((size_t)(row >> 4) * (K >> 5) + (k >> 5)) * 512
               + (size_t)((((k >> 3) & 3) << 4) | (row & 15)) * 8;

    *(bf16x8*)(wb + dst) = cvt8(srcbase + local);
}

// fragment-tile load helper: W swizzled with inner-dim K, n0 16-aligned
__device__ __forceinline__ bf16x8 fragW(const short* W, int n0, int k0, int K, int lane)
{
    return *(const bf16x8*)(W + ((size_t)(n0 >> 4) * (K >> 5) + (k0 >> 5)) * 512 + lane * 8);
}

// MODE-5 head-split scatter index (Q/K fragment-tiled, V dense)
__device__ __forceinline__ size_t qkv_idx(int row, int col)
{
    int sec = col >> 8, hd = (col >> 6) & 3, d = col & 63;
    int srow = row & (SEQ - 1);
    size_t base = (size_t)sec * 2097152
                + (size_t)(((row >> 11) << 2) | hd) * 131072;
    if (sec < 2)
        return base + (size_t)(srow >> 4) * 1024 + (size_t)(d >> 5) * 512
             + (size_t)((((d >> 3) & 3) << 4) | (srow & 15)) * 8 + (d & 7);
    return base + (size_t)srow * 64 + d;
}

// ---------------------------------------------------------------------------
// Embed: h = 16 * (x @ w_in^T) + PE.
// ---------------------------------------------------------------------------
__global__ __launch_bounds__(256)
void embed_pe(const float* __restrict__ X, const __hip_bfloat16* __restrict__ W,
              float* __restrict__ hbuf)
{
    int tid = threadIdx.x, wave = tid >> 6, lane = tid & 63;
    int wm = wave >> 1, wn = wave & 1;
    int rowBase = blockIdx.y * 64 + wm * 32;
    int colBase = blockIdx.x * 64 + wn * 32;
    int lr = lane & 15, hi = lane >> 4;

    const float* px0 = X + (size_t)(rowBase + lr) * HDIM + hi * 8;
    const float* px1 = px0 + (size_t)16 * HDIM;
    const short* Wb  = (const short*)W;

    f32x4 acc[2][2];
    acc[0][0] = (f32x4){0.f,0.f,0.f,0.f}; acc[0][1] = (f32x4){0.f,0.f,0.f,0.f};
    acc[1][0] = (f32x4){0.f,0.f,0.f,0.f}; acc[1][1] = (f32x4){0.f,0.f,0.f,0.f};

    #pragma unroll
    for (int k0 = 0; k0 < 256; k0 += 32) {
        bf16x8 a0 = cvt8(px0 + k0);
        bf16x8 a1 = cvt8(px1 + k0);
        bf16x8 b0 = fragW(Wb, colBase,      k0, 256, lane);
        bf16x8 b1 = fragW(Wb, colBase + 16, k0, 256, lane);
        acc[0][0] = __builtin_amdgcn_mfma_f32_16x16x32_bf16(a0, b0, acc[0][0], 0,0,0);
        acc[0][1] = __builtin_amdgcn_mfma_f32_16x16x32_bf16(a0, b1, acc[0][1], 0,0,0);
        acc[1][0] = __builtin_amdgcn_mfma_f32_16x16x32_bf16(a1, b0, acc[1][0], 0,0,0);
        acc[1][1] = __builtin_amdgcn_mfma_f32_16x16x32_bf16(a1, b1, acc[1][1], 0,0,0);
    }

    int cc = lane & 15, quad = lane >> 4;
    #pragma unroll
    for (int mt = 0; mt < 2; mt++)
        #pragma unroll
        for (int nt = 0; nt < 2; nt++) {
            int col = colBase + nt*16 + cc;
            int i2 = col & ~1;
            float freq = __expf((float)i2 * (-9.210340371976184f / 256.0f));
            #pragma unroll
            for (int r = 0; r < 4; r++) {
                int row = rowBase + mt*16 + quad*4 + r;
                float arg = (float)(row & (SEQ-1)) * freq;
                float pe = (col & 1) ? __cosf(arg) : __sinf(arg);
                hbuf[(size_t)row*HDIM + col] = 16.0f*acc[mt][nt][r] + pe;
            }
        }
}

// ---------------------------------------------------------------------------
// LN-fused GEMM, 64-row tile, MODE-5 qkv scatter (layer 0 only).
// ---------------------------------------------------------------------------
template<int NT>
__global__ __launch_bounds__(256)
void gemm_ln(const float* __restrict__ h,
             const float* __restrict__ g, const float* __restrict__ bln,
             const __hip_bfloat16* __restrict__ W,
             const float* __restrict__ bias,
             __hip_bfloat16* __restrict__ obf)
{
    constexpr int NTW = NT / 32;
    __shared__ __align__(16) short A_lds[64][264];

    int tid = threadIdx.x, wave = tid >> 6, lane = tid & 63;
    int wm = wave >> 1, wn = wave & 1;
    int rowBase = blockIdx.y * 64;
    int colBase = blockIdx.x * NT + wn * (NT / 2);

    {
        float4 gv = *(const float4*)(g + lane * 4);
        float4 bv = *(const float4*)(bln + lane * 4);
        #pragma unroll
        for (int rr = 0; rr < 16; rr += 4) {
            float4 xv[4];
            #pragma unroll
            for (int u = 0; u < 4; u++)
                xv[u] = *(const float4*)(h + (size_t)(rowBase + wave*16 + rr + u)*HDIM + lane*4);
            #pragma unroll
            for (int u = 0; u < 4; u++) {
                float s = xv[u].x + xv[u].y + xv[u].z + xv[u].w;
                #pragma unroll
                for (int off = 32; off >= 1; off >>= 1) s += __shfl_xor(s, off);
                float mu = s * (1.0f/256.0f);
                float d0 = xv[u].x-mu, d1 = xv[u].y-mu, d2 = xv[u].z-mu, d3 = xv[u].w-mu;
                float v = d0*d0 + d1*d1 + d2*d2 + d3*d3;
                #pragma unroll
                for (int off = 32; off >= 1; off >>= 1) v += __shfl_xor(v, off);
                float rstd = rsqrtf(v * (1.0f/256.0f) + 1e-5f);
                union { short e[4]; uint2 w2; } o;
                o.e[0] = (short)__bfloat16_as_ushort(__float2bfloat16(d0*rstd*gv.x + bv.x));
                o.e[1] = (short)__bfloat16_as_ushort(__float2bfloat16(d1*rstd*gv.y + bv.y));
                o.e[2] = (short)__bfloat16_as_ushort(__float2bfloat16(d2*rstd*gv.z + bv.z));
                o.e[3] = (short)__bfloat16_as_ushort(__float2bfloat16(d3*rstd*gv.w + bv.w));
                *(uint2*)&A_lds[wave*16 + rr + u][lane*4] = o.w2;
            }
        }
    }
    __syncthreads();

    int lr = lane & 15, hi = lane >> 4;
    f32x4 acc[2][NTW];
    #pragma unroll
    for (int mt = 0; mt < 2; mt++)
        #pragma unroll
        for (int nt = 0; nt < NTW; nt++)
            acc[mt][nt] = (f32x4){0.f,0.f,0.f,0.f};

    const short* Ws = (const short*)W;
    #pragma unroll
    for (int k0 = 0; k0 < 256; k0 += 32) {
        bf16x8 af[2], bfr[NTW];
        #pragma unroll
        for (int mt = 0; mt < 2; mt++)
            af[mt] = *(const bf16x8*)&A_lds[wm*32 + mt*16 + lr][k0 + hi*8];
        #pragma unroll
        for (int nt = 0; nt < NTW; nt++)
            bfr[nt] = fragW(Ws, colBase + nt*16, k0, 256, lane);
        #pragma unroll
        for (int mt = 0; mt < 2; mt++)
            #pragma unroll
            for (int nt = 0; nt < NTW; nt++)
                acc[mt][nt] = __builtin_amdgcn_mfma_f32_16x16x32_bf16(af[mt], bfr[nt], acc[mt][nt], 0,0,0);
    }

    int cc = lane & 15, quad = lane >> 4;
    #pragma unroll
    for (int mt = 0; mt < 2; mt++)
        #pragma unroll
        for (int nt = 0; nt < NTW; nt++) {
            int col = colBase + nt*16 + cc;
            float bv = bias[col];
            #pragma unroll
            for (int r = 0; r < 4; r++) {
                int row = rowBase + wm*32 + mt*16 + quad*4 + r;
                float c = acc[mt][nt][r] + bv;
                obf[qkv_idx(row, col)] = __float2bfloat16(c);
            }
        }
}

// ---------------------------------------------------------------------------
// FULLY FUSED layer tail, 1024 threads / 16 waves.
// TAIL=1: also computes NEXT layer's qkv (LN1 + 32x768 GEMM, scatter to
//         qkv_out, a DIFFERENT buffer than qkvd -> no cross-block race).
// TAIL=2: fuses final LNf + out-GEMM (writes d_out directly).
// ---------------------------------------------------------------------------
struct AttnLDS {
    __align__(16) __hip_bfloat16 Vt[64][128];
    __align__(16) __hip_bfloat16 Pl[32][96];
    float sm[2][32], ss[2][32];
};

template<int TAIL>
__global__ __launch_bounds__(1024)
void attn_ffn(const __hip_bfloat16* __restrict__ qkvd,
              const __hip_bfloat16* __restrict__ ow,   // fragment-tiled [256][256]
              const float* __restrict__ ob,
              float* __restrict__ h,
              const float* __restrict__ g, const float* __restrict__ bln,
              const __hip_bfloat16* __restrict__ W1, const float* __restrict__ b1,
              const __hip_bfloat16* __restrict__ W2, const float* __restrict__ b2,
              const float* __restrict__ gt, const float* __restrict__ bt,
              const __hip_bfloat16* __restrict__ Wt, const float* __restrict__ btb,
              float* __restrict__ outp, __hip_bfloat16* __restrict__ qkv_out)
{
    __shared__ union SMem {
        AttnLDS asl[4];                                   // 92160 B (attention)
        struct {
            __align__(16) short A[32][264];               // LN out (bf16)
            __align__(16) short Z[2][32][264];            // FFN hidden, dbuf
        } f;                                              // 50688 B (FFN)
    } U;
    __shared__ __align__(16) short att_lds[32][264];
    __shared__ __align__(16) float H_lds[32][260];

    int tid  = threadIdx.x;
    int wave = tid >> 6, lane = tid & 63;
    int grp  = wave >> 2, w4 = wave & 3, ltid = tid & 255;
    int b    = blockIdx.y, i0 = blockIdx.x * 32;
    int klo  = i0 - 32;

    int lr = lane & 15, hi = lane >> 4;
    int cc = lane & 15, quad = lane >> 4;

    int hd = grp;
    AttnLDS& S = U.asl[grp];
    const short* Qd = (const short*)qkvd + (size_t)(b * 4 + hd) * 131072;
    const short* Kd = Qd + 2097152;
    const short* Vd = Qd + 4194304;
    int qh = w4 & 1, seg = w4 >> 1;
    int qoff = qh * 16 + quad * 4;

    // ======== ENTRY PREFETCH ========
    int vm = ltid & 7, vrl = ltid >> 3, vdp = vm * 8;
    bf16x8 vr[3];
    #pragma unroll
    for (int rr = 0; rr < 3; rr++) {
        int j = klo + rr * 32 + vrl;
        j = j < 0 ? 0 : (j > SEQ - 1 ? SEQ - 1 : j);
        vr[rr] = *(const bf16x8*)(Vd + (size_t)j * 64 + vdp);
    }
    bf16x8 qf[2];
    #pragma unroll
    for (int ds = 0; ds < 2; ds++)
        qf[ds] = *(const bf16x8*)(Qd + (size_t)((i0 >> 4) + qh) * 1024 + ds * 512 + lane * 8);
    bf16x8 kf[3][2];
    #pragma unroll
    for (int t = 0; t < 3; t++) {
        int jt = (klo + seg * 48 + t * 16) >> 4;
        jt = jt < 0 ? 0 : (jt > 127 ? 127 : jt);
        kf[t][0] = *(const bf16x8*)(Kd + (size_t)jt * 1024 + lane * 8);
        kf[t][1] = *(const bf16x8*)(Kd + (size_t)jt * 1024 + 512 + lane * 8);
    }
    float hold[2][4];
    {
        const float* hp = h + (size_t)(b * SEQ + i0) * HDIM + wave * 16 + cc;
        #pragma unroll
        for (int mt = 0; mt < 2; mt++)
            #pragma unroll
            for (int r = 0; r < 4; r++)
                hold[mt][r] = hp[(size_t)(mt*16 + quad*4 + r) * HDIM];
    }

    // ======== phase 1: attention ========
    { // scatter V^T
        union { bf16x8 v; short e[8]; } u;
        #pragma unroll
        for (int rr = 0; rr < 3; rr++) {
            int row = rr * 32 + vrl;
            int colp = row ^ (vm << 3);
            u.v = vr[rr];
            #pragma unroll
            for (int jj = 0; jj < 8; jj++)
                *(short*)&S.Vt[vdp + jj][colp] = u.e[jj];
        }
    }

    f32x4 sacc[3];
    #pragma unroll
    for (int t = 0; t < 3; t++) {
        f32x4 a = (f32x4){0.f,0.f,0.f,0.f};
        a = __builtin_amdgcn_mfma_f32_16x16x32_bf16(qf[0], kf[t][0], a, 0,0,0);
        a = __builtin_amdgcn_mfma_f32_16x16x32_bf16(qf[1], kf[t][1], a, 0,0,0);
        sacc[t] = a;
    }

    float s[3][4];
    #pragma unroll
    for (int t = 0; t < 3; t++) {
        int koff = seg * 48 + t * 16 + cc;
        int jj = klo + koff;
        #pragma unroll
        for (int r = 0; r < 4; r++) {
            int rel = koff - (qoff + r);
            bool ok = (jj >= 0) && (jj < SEQ) && (rel >= 0) && (rel <= 64);
            s[t][r] = ok ? sacc[t][r] * 0.125f : -1e30f;
        }
    }

    float mrow[4], srow[4];
    #pragma unroll
    for (int r = 0; r < 4; r++)
        mrow[r] = fmaxf(fmaxf(s[0][r], s[1][r]), s[2][r]);
    #pragma unroll
    for (int off = 8; off >= 1; off >>= 1)
        #pragma unroll
        for (int r = 0; r < 4; r++)
            mrow[r] = fmaxf(mrow[r], __shfl_xor(mrow[r], off));
    #pragma unroll
    for (int r = 0; r < 4; r++)
        srow[r] = __expf(s[0][r]-mrow[r]) + __expf(s[1][r]-mrow[r]) + __expf(s[2][r]-mrow[r]);
    #pragma unroll
    for (int off = 8; off >= 1; off >>= 1)
        #pragma unroll
        for (int r = 0; r < 4; r++)
            srow[r] += __shfl_xor(srow[r], off);
    if (cc == 0) {
        #pragma unroll
        for (int r = 0; r < 4; r++) { S.sm[seg][qoff+r] = mrow[r]; S.ss[seg][qoff+r] = srow[r]; }
    }
    __syncthreads();

    float Mr[4], inv[4];
    #pragma unroll
    for (int r = 0; r < 4; r++) {
        float m0 = S.sm[0][qoff+r], m1 = S.sm[1][qoff+r];
        float M = fmaxf(m0, m1);
        float dn = S.ss[0][qoff+r] * __expf(m0 - M) + S.ss[1][qoff+r] * __expf(m1 - M);
        Mr[r] = M; inv[r] = 1.0f / dn;
    }
    #pragma unroll
    for (int t = 0; t < 3; t++)
        #pragma unroll
        for (int r = 0; r < 4; r++)
            S.Pl[qoff+r][seg*48 + t*16 + cc] = __float2bfloat16(__expf(s[t][r]-Mr[r]) * inv[r]);
    __syncthreads();

    // prefetch proj weight fragments (coalesced; hidden under PV)
    bf16x8 owf[8];
    {
        const short* op = (const short*)ow + (size_t)wave * 8 * 512 + lane * 8;
        #pragma unroll
        for (int i = 0; i < 8; i++)
            owf[i] = *(const bf16x8*)(op + i * 512);
    }

    // O = P @ V -> att_lds
    {
        f32x4 oacc[2];
        oacc[0] = (f32x4){0.f,0.f,0.f,0.f}; oacc[1] = (f32x4){0.f,0.f,0.f,0.f};
        #pragma unroll
        for (int ks = 0; ks < 3; ks++) {
            int kk = ks * 32;
            bf16x8 pf = *(const bf16x8*)&S.Pl[qh*16 + lr][kk + hi*8];
            #pragma unroll
            for (int dt = 0; dt < 2; dt++) {
                int d = seg*32 + dt*16 + lr;
                int colb = (kk + hi*8) ^ (((d >> 3) & 7) << 3);
                bf16x8 vf = *(const bf16x8*)&S.Vt[d][colb];
                oacc[dt] = __builtin_amdgcn_mfma_f32_16x16x32_bf16(pf, vf, oacc[dt], 0,0,0);
            }
        }
        #pragma unroll
        for (int dt = 0; dt < 2; dt++) {
            int col = hd*64 + seg*32 + dt*16 + cc;
            #pragma unroll
            for (int r = 0; r < 4; r++)
                att_lds[qoff + r][col] =
                    (short)__bfloat16_as_ushort(__float2bfloat16(oacc[dt][r]));
        }
    }
    __syncthreads();

    // ======== phase 2: proj + residual -> H_lds (wave owns 16 cols) ========
    {
        f32x4 acc[2];
        acc[0] = (f32x4){0.f,0.f,0.f,0.f}; acc[1] = (f32x4){0.f,0.f,0.f,0.f};
        #pragma unroll
        for (int i = 0; i < 8; i++) {
            bf16x8 a0 = *(const bf16x8*)&att_lds[lr][i*32 + hi*8];
            bf16x8 a1 = *(const bf16x8*)&att_lds[16 + lr][i*32 + hi*8];
            acc[0] = __builtin_amdgcn_mfma_f32_16x16x32_bf16(a0, owf[i], acc[0], 0,0,0);
            acc[1] = __builtin_amdgcn_mfma_f32_16x16x32_bf16(a1, owf[i], acc[1], 0,0,0);
        }
        float bv = ob[wave*16 + cc];
        #pragma unroll
        for (int mt = 0; mt < 2; mt++)
            #pragma unroll
            for (int r = 0; r < 4; r++)
                H_lds[mt*16 + quad*4 + r][wave*16 + cc] = hold[mt][r] + acc[mt][r] + bv;
    }

    // prologue: prefetch W1 chunk 0 (coalesced; hidden under barrier + LN2)
    const short* W1s = (const short*)W1;
    const short* W2s = (const short*)W2;
    bf16x8 w1f[8];
    {
        const short* wp = W1s + (size_t)wave * 8 * 512 + lane * 8;
        #pragma unroll
        for (int i = 0; i < 8; i++)
            w1f[i] = *(const bf16x8*)(wp + i * 512);
    }
    __syncthreads();

    // ======== phase 3: LN2(H_lds) -> A bf16 (each wave: 2 rows) ========
    {
        float4 gv = *(const float4*)(g + lane * 4);
        float4 bv = *(const float4*)(bln + lane * 4);
        #pragma unroll
        for (int u = 0; u < 2; u++) {
            float4 xv = *(const float4*)&H_lds[wave*2 + u][lane*4];
            float ss2 = xv.x + xv.y + xv.z + xv.w;
            #pragma unroll
            for (int off = 32; off >= 1; off >>= 1) ss2 += __shfl_xor(ss2, off);
            float mu = ss2 * (1.0f/256.0f);
            float d0 = xv.x-mu, d1 = xv.y-mu, d2 = xv.z-mu, d3 = xv.w-mu;
            float v = d0*d0 + d1*d1 + d2*d2 + d3*d3;
            #pragma unroll
            for (int off = 32; off >= 1; off >>= 1) v += __shfl_xor(v, off);
            float rstd = rsqrtf(v * (1.0f/256.0f) + 1e-5f);
            union { short e[4]; uint2 w2; } o;
            o.e[0] = (short)__bfloat16_as_ushort(__float2bfloat16(d0*rstd*gv.x + bv.x));
            o.e[1] = (short)__bfloat16_as_ushort(__float2bfloat16(d1*rstd*gv.y + bv.y));
            o.e[2] = (short)__bfloat16_as_ushort(__float2bfloat16(d2*rstd*gv.z + bv.z));
            o.e[3] = (short)__bfloat16_as_ushort(__float2bfloat16(d3*rstd*gv.w + bv.w));
            *(uint2*)&U.f.A[wave*2 + u][lane*4] = o.w2;
        }
    }
    __syncthreads();

    // ======== phase 4: FFN, Z dbuf, weights software-pipelined ========
    f32x4 acc2[2];
    acc2[0] = (f32x4){0.f,0.f,0.f,0.f}; acc2[1] = (f32x4){0.f,0.f,0.f,0.f};

    #pragma unroll 1
    for (int kk = 0; kk < 4; kk++) {
        bf16x8 w2f[8];
        {
            const short* wp = W2s + (size_t)(wave * 32 + kk * 8) * 512 + lane * 8;
            #pragma unroll
            for (int i = 0; i < 8; i++)
                w2f[i] = *(const bf16x8*)(wp + i * 512);
        }

        f32x4 acc1[2];
        acc1[0] = (f32x4){0.f,0.f,0.f,0.f}; acc1[1] = (f32x4){0.f,0.f,0.f,0.f};
        #pragma unroll
        for (int i = 0; i < 8; i++) {
            bf16x8 af0 = *(const bf16x8*)&U.f.A[lr][i*32 + hi*8];
            bf16x8 af1 = *(const bf16x8*)&U.f.A[16 + lr][i*32 + hi*8];
            acc1[0] = __builtin_amdgcn_mfma_f32_16x16x32_bf16(af0, w1f[i], acc1[0], 0,0,0);
            acc1[1] = __builtin_amdgcn_mfma_f32_16x16x32_bf16(af1, w1f[i], acc1[1], 0,0,0);
        }

        {
            int col = wave*16 + cc;
            float bb = b1[kk*256 + col];
            #pragma unroll
            for (int mt = 0; mt < 2; mt++)
                #pragma unroll
                for (int r = 0; r < 4; r++) {
                    float z = fmaxf(acc1[mt][r] + bb, 0.f);
                    U.f.Z[kk & 1][mt*16 + quad*4 + r][col] =
                        (short)__bfloat16_as_ushort(__float2bfloat16(z));
                }
        }
        __syncthreads();

        {
            int nk = (kk < 3) ? kk + 1 : 3;
            const short* wp = W1s + (size_t)(nk * 16 + wave) * 8 * 512 + lane * 8;
            #pragma unroll
            for (int i = 0; i < 8; i++)
                w1f[i] = *(const bf16x8*)(wp + i * 512);
        }

        #pragma unroll
        for (int i = 0; i < 8; i++) {
            bf16x8 zf0 = *(const bf16x8*)&U.f.Z[kk & 1][lr][i*32 + hi*8];
            bf16x8 zf1 = *(const bf16x8*)&U.f.Z[kk & 1][16 + lr][i*32 + hi*8];
            acc2[0] = __builtin_amdgcn_mfma_f32_16x16x32_bf16(zf0, w2f[i], acc2[0], 0,0,0);
            acc2[1] = __builtin_amdgcn_mfma_f32_16x16x32_bf16(zf1, w2f[i], acc2[1], 0,0,0);
        }
        // Z[kk&1] overwritten only at kk+2, after the kk+1 barrier.
    }

    // ======== tail ========
    // H_lds += FF2 + b2 (final h for this layer); TAIL=1 also writes h global.
    {
        int col = wave*16 + cc;
        float bb = b2[col];
        #pragma unroll
        for (int mt = 0; mt < 2; mt++)
            #pragma unroll
            for (int r = 0; r < 4; r++) {
                int rowl = mt*16 + quad*4 + r;
                float v = H_lds[rowl][col] + acc2[mt][r] + bb;
                H_lds[rowl][col] = v;
                if (TAIL == 1) {
                    int row = b * SEQ + i0 + rowl;
                    h[(size_t)row * HDIM + col] = v;
                }
            }
    }
    __syncthreads();

    // tail LN (LN1 of next layer, or LNf) -> U.f.A
    {
        float4 gv = *(const float4*)(gt + lane * 4);
        float4 bv = *(const float4*)(bt + lane * 4);
        #pragma unroll
        for (int u = 0; u < 2; u++) {
            float4 xv = *(const float4*)&H_lds[wave*2 + u][lane*4];
            float ss2 = xv.x + xv.y + xv.z + xv.w;
            #pragma unroll
            for (int off = 32; off >= 1; off >>= 1) ss2 += __shfl_xor(ss2, off);
            float mu = ss2 * (1.0f/256.0f);
            float d0 = xv.x-mu, d1 = xv.y-mu, d2 = xv.z-mu, d3 = xv.w-mu;
            float v = d0*d0 + d1*d1 + d2*d2 + d3*d3;
            #pragma unroll
            for (int off = 32; off >= 1; off >>= 1) v += __shfl_xor(v, off);
            float rstd = rsqrtf(v * (1.0f/256.0f) + 1e-5f);
            union { short e[4]; uint2 w2; } o;
            o.e[0] = (short)__bfloat16_as_ushort(__float2bfloat16(d0*rstd*gv.x + bv.x));
            o.e[1] = (short)__bfloat16_as_ushort(__float2bfloat16(d1*rstd*gv.y + bv.y));
            o.e[2] = (short)__bfloat16_as_ushort(__float2bfloat16(d2*rstd*gv.z + bv.z));
            o.e[3] = (short)__bfloat16_as_ushort(__float2bfloat16(d3*rstd*gv.w + bv.w));
            *(uint2*)&U.f.A[wave*2 + u][lane*4] = o.w2;
        }
    }
    __syncthreads();

    if (TAIL == 2) {
        // out = A @ w_out^T + b_out (wave owns 16 cols)
        bf16x8 wf[8];
        const short* wp = (const short*)Wt + (size_t)wave * 8 * 512 + lane * 8;
        #pragma unroll
        for (int i = 0; i < 8; i++)
            wf[i] = *(const bf16x8*)(wp + i * 512);

        f32x4 oa[2];
        oa[0] = (f32x4){0.f,0.f,0.f,0.f}; oa[1] = (f32x4){0.f,0.f,0.f,0.f};
        #pragma unroll
        for (int i = 0; i < 8; i++) {
            bf16x8 a0 = *(const bf16x8*)&U.f.A[lr][i*32 + hi*8];
            bf16x8 a1 = *(const bf16x8*)&U.f.A[16 + lr][i*32 + hi*8];
            oa[0] = __builtin_amdgcn_mfma_f32_16x16x32_bf16(a0, wf[i], oa[0], 0,0,0);
            oa[1] = __builtin_amdgcn_mfma_f32_16x16x32_bf16(a1, wf[i], oa[1], 0,0,0);
        }
        int col = wave*16 + cc;
        float bb = btb[col];
        #pragma unroll
        for (int mt = 0; mt < 2; mt++)
            #pragma unroll
            for (int r = 0; r < 4; r++) {
                int row = b * SEQ + i0 + mt*16 + quad*4 + r;
                outp[(size_t)row * HDIM + col] = oa[mt][r] + bb;
            }
    } else {
        // TAIL == 1: next layer's qkv = A @ Wt^T + btb; wave owns 48 cols
        const short* Wts = (const short*)Wt;
        f32x4 qa[2][3];
        #pragma unroll
        for (int mt = 0; mt < 2; mt++)
            #pragma unroll
            for (int nt = 0; nt < 3; nt++)
                qa[mt][nt] = (f32x4){0.f,0.f,0.f,0.f};

        #pragma unroll
        for (int k0 = 0; k0 < 256; k0 += 32) {
            bf16x8 a0 = *(const bf16x8*)&U.f.A[lr][k0 + hi*8];
            bf16x8 a1 = *(const bf16x8*)&U.f.A[16 + lr][k0 + hi*8];
            #pragma unroll
            for (int nt = 0; nt < 3; nt++) {
                bf16x8 wf = fragW(Wts, wave*48 + nt*16, k0, 256, lane);
                qa[0][nt] = __builtin_amdgcn_mfma_f32_16x16x32_bf16(a0, wf, qa[0][nt], 0,0,0);
                qa[1][nt] = __builtin_amdgcn_mfma_f32_16x16x32_bf16(a1, wf, qa[1][nt], 0,0,0);
            }
        }
        #pragma unroll
        for (int nt = 0; nt < 3; nt++) {
            int col = wave*48 + nt*16 + cc;
            float bv = btb[col];
            #pragma unroll
            for (int mt = 0; mt < 2; mt++)
                #pragma unroll
                for (int r = 0; r < 4; r++) {
                    int row = b * SEQ + i0 + mt*16 + quad*4 + r;
                    float c = qa[mt][nt][r] + bv;
                    qkv_out[qkv_idx(row, col)] = __float2bfloat16(c);
                }
        }
    }
}

// ---------------------------------------------------------------------------
extern "C" void kernel_launch(void* const* d_in, const int* in_sizes, int n_in,
                              void* d_out, int out_size, void* d_ws, size_t ws_size,
                              hipStream_t stream)
{
    const float* x     = (const float*)d_in[0];
    const float* w_in  = (const float*)d_in[1];
    const float* w_out = (const float*)d_in[2];
    const float* b_out = (const float*)d_in[3];
    const float* qkv_w = (const float*)d_in[4];
    const float* qkv_b = (const float*)d_in[5];
    const float* out_w = (const float*)d_in[6];
    const float* out_b = (const float*)d_in[7];
    const float* ln1_g = (const float*)d_in[8];
    const float* ln1_b = (const float*)d_in[9];
    const float* ln2_g = (const float*)d_in[10];
    const float* ln2_b = (const float*)d_in[11];
    const float* ff1_w = (const float*)d_in[12];
    const float* ff1_b = (const float*)d_in[13];
    const float* ff2_w = (const float*)d_in[14];
    const float* ff2_b = (const float*)d_in[15];
    const float* lnf_g = (const float*)d_in[16];
    const float* lnf_b = (const float*)d_in[17];

    char* ws = (char*)d_ws;
    float*          h     = (float*)ws;                        // [0, 8M)
    __hip_bfloat16* qkvd0 = (__hip_bfloat16*)(ws + 8388608);   // 12.6 MB
    __hip_bfloat16* qkvd1 = (__hip_bfloat16*)(ws + 20971520);  // 12.6 MB
    __hip_bfloat16* wb    = (__hip_bfloat16*)(ws + 33554432);  // weights bf16 (~5 MB)

    __hip_bfloat16* w_in_b  = wb;
    __hip_bfloat16* w_out_b = wb + 65536;
    __hip_bfloat16* qkv_w_b = wb + 131072;
    __hip_bfloat16* out_w_b = wb + 720896;
    __hip_bfloat16* ff1_w_b = wb + 917504;
    __hip_bfloat16* ff2_w_b = wb + 1703936;

    dim3 blk(256);

    cvt_all<<<1216, blk, 0, stream>>>(w_in, w_out, qkv_w, out_w, ff1_w, ff2_w, wb);

    // h = 16 * (x @ w_in^T) + PE
    embed_pe<<<dim3(4, 128), blk, 0, stream>>>(x, w_in_b, h);

    // layer-0 qkv (standalone); NT=128, 768 blocks = 3/CU (measured optimum)
    gemm_ln<128><<<dim3(6, 128), blk, 0, stream>>>(
        h, ln1_g, ln1_b, qkv_w_b, qkv_b, qkvd0);

    // layer 0: reads qkvd0, tail computes layer-1 qkv into qkvd1
    attn_ffn<1><<<dim3(SEQ/32, BATCH), dim3(1024), 0, stream>>>(
        qkvd0, out_w_b, out_b, h,
        ln2_g, ln2_b, ff1_w_b, ff1_b, ff2_w_b, ff2_b,
        ln1_g + HDIM, ln1_b + HDIM,
        qkv_w_b + (size_t)768*HDIM, qkv_b + 768, nullptr, qkvd1);

    // layer 1: reads qkvd1, tail computes layer-2 qkv into qkvd0
    attn_ffn<1><<<dim3(SEQ/32, BATCH), dim3(1024), 0, stream>>>(
        qkvd1, out_w_b + (size_t)HDIM*HDIM, out_b + HDIM, h,
        ln2_g + HDIM, ln2_b + HDIM,
        ff1_w_b + (size_t)FFN_DIM*HDIM, ff1_b + FFN_DIM,
        ff2_w_b + (size_t)HDIM*FFN_DIM, ff2_b + HDIM,
        ln1_g + 2*HDIM, ln1_b + 2*HDIM,
        qkv_w_b + (size_t)2*768*HDIM, qkv_b + 2*768, nullptr, qkvd0);

    // layer 2: reads qkvd0, tail fuses LNf + out-GEMM (writes d_out)
    attn_ffn<2><<<dim3(SEQ/32, BATCH), dim3(1024), 0, stream>>>(
        qkvd0, out_w_b + (size_t)2*HDIM*HDIM, out_b + 2*HDIM, h,
        ln2_g + 2*HDIM, ln2_b + 2*HDIM,
        ff1_w_b + (size_t)2*FFN_DIM*HDIM, ff1_b + 2*FFN_DIM,
        ff2_w_b + (size_t)2*HDIM*FFN_DIM, ff2_b + 2*HDIM,
        lnf_g, lnf_b, w_out_b, b_out, (float*)d_out, nullptr);
}